// Round 5
// baseline (3498.483 us; speedup 1.0000x reference)
//
#include <hip/hip_runtime.h>
#include <cstdint>
#include <cstddef>

// Informer ProbSparse decoder layer. GEMMs via split-bf16 MFMA emulation.
// B=4 L=1024 Dm=1024 H=16 Dh=64 U=U_part=35 FF=4096.
#define B_     4
#define L_     1024
#define DM_    1024
#define H_     16
#define DH_    64
#define U_     35
#define FF_    4096
#define MROWS_ 4096          // B_*L_
#define IDXN_  35840         // L_*U_ random draws per attention

typedef __attribute__((ext_vector_type(8))) short bf16x8;
typedef __attribute__((ext_vector_type(4))) float f32x4;

// ---------------- Threefry-2x32-20 (exact JAX semantics) ----------------
__host__ __device__ inline void tf2x32(uint32_t k0, uint32_t k1,
                                       uint32_t x0, uint32_t x1,
                                       uint32_t& y0, uint32_t& y1) {
  const uint32_t ks2 = k0 ^ k1 ^ 0x1BD11BDAu;
  uint32_t v0 = x0 + k0, v1 = x1 + k1;
#define ROTL_(x,d) (((x)<<(d))|((x)>>(32-(d))))
#define RND_(r) { v0 += v1; v1 = ROTL_(v1,(r)); v1 ^= v0; }
  RND_(13) RND_(15) RND_(26) RND_(6)   v0 += k1;  v1 += ks2 + 1u;
  RND_(17) RND_(29) RND_(16) RND_(24)  v0 += ks2; v1 += k0  + 2u;
  RND_(13) RND_(15) RND_(26) RND_(6)   v0 += k0;  v1 += k1  + 3u;
  RND_(17) RND_(29) RND_(16) RND_(24)  v0 += k1;  v1 += ks2 + 4u;
  RND_(13) RND_(15) RND_(26) RND_(6)   v0 += ks2; v1 += k0  + 5u;
#undef RND_
#undef ROTL_
  y0 = v0; y1 = v1;
}

// JAX partitionable threefry random_bits, 32-bit: bits[i] = y0 ^ y1 (XOR fold).
__global__ void idx_kernel(uint32_t k0, uint32_t k1, int* __restrict__ idx) {
  const int i = blockIdx.x * 256 + threadIdx.x;
  if (i >= IDXN_) return;
  uint32_t y0, y1;
  tf2x32(k0, k1, 0u, (uint32_t)i, y0, y1);
  idx[i] = (int)((y0 ^ y1) & 1023u);
}

// ---------------- split-bf16 MFMA GEMM ------------------------------------
struct Gemm3 {
  const float* A[3];
  const float* B[3];
  const float* bias[3];
  float*       C[3];
};

__device__ __forceinline__ uint32_t f32bits(float x) {
  union { float f; uint32_t u; } c; c.f = x; return c.u;
}
__device__ __forceinline__ float bitsf32(uint32_t u) {
  union { uint32_t u; float f; } c; c.u = u; return c.f;
}
__device__ __forceinline__ uint32_t bf16rne(float x) {
  const uint32_t u = f32bits(x);
  return (u + 0x7FFFu + ((u >> 16) & 1u)) >> 16;
}

__device__ __forceinline__ void load_a16(const float* p, float (&v)[16]) {
  const float4* q = (const float4*)p;
  float4 x0 = q[0], x1 = q[1], x2 = q[2], x3 = q[3];
  v[0]=x0.x; v[1]=x0.y; v[2]=x0.z; v[3]=x0.w;
  v[4]=x1.x; v[5]=x1.y; v[6]=x1.z; v[7]=x1.w;
  v[8]=x2.x; v[9]=x2.y; v[10]=x2.z; v[11]=x2.w;
  v[12]=x3.x; v[13]=x3.y; v[14]=x3.z; v[15]=x3.w;
}
__device__ __forceinline__ void load_b16(const float* p, int N, float (&v)[16]) {
#pragma unroll
  for (int j = 0; j < 16; ++j) v[j] = p[(size_t)j * N];
}

template<int WAYS>
__device__ __forceinline__ void split_write(const float (&v)[16], int sr, int skh,
                                            uint32_t* H, uint32_t* Mi, uint32_t* L)
{
  uint32_t hp[8], lp[8], mp[8];
#pragma unroll
  for (int e = 0; e < 8; ++e) {
    const float a0 = v[2*e], a1 = v[2*e+1];
    const uint32_t h0 = f32bits(a0) & 0xFFFF0000u;
    const uint32_t h1 = f32bits(a1) & 0xFFFF0000u;
    hp[e] = (h0 >> 16) | h1;
    float r0 = a0 - bitsf32(h0);
    float r1 = a1 - bitsf32(h1);
    if (WAYS == 3) {
      const uint32_t m0 = f32bits(r0) & 0xFFFF0000u;
      const uint32_t m1 = f32bits(r1) & 0xFFFF0000u;
      mp[e] = (m0 >> 16) | m1;
      r0 -= bitsf32(m0); r1 -= bitsf32(m1);
    }
    lp[e] = bf16rne(r0) | (bf16rne(r1) << 16);
  }
  const int q  = (sr >> 1) & 3;
  const int b0 = sr * 64 + (((skh * 2 + 0) ^ q) << 4);
  const int b1 = sr * 64 + (((skh * 2 + 1) ^ q) << 4);
  *(uint4*)((char*)H + b0) = make_uint4(hp[0], hp[1], hp[2], hp[3]);
  *(uint4*)((char*)H + b1) = make_uint4(hp[4], hp[5], hp[6], hp[7]);
  if (WAYS == 3) {
    *(uint4*)((char*)Mi + b0) = make_uint4(mp[0], mp[1], mp[2], mp[3]);
    *(uint4*)((char*)Mi + b1) = make_uint4(mp[4], mp[5], mp[6], mp[7]);
  }
  *(uint4*)((char*)L + b0) = make_uint4(lp[0], lp[1], lp[2], lp[3]);
  *(uint4*)((char*)L + b1) = make_uint4(lp[4], lp[5], lp[6], lp[7]);
}

template<int WAYS, bool RELU, bool LOAD_EARLY>
__global__ __launch_bounds__(256, 2) void gemm_mfma(Gemm3 g, int K, int N)
{
  constexpr int NB = (WAYS == 3) ? 2048 : 4;
  __shared__ uint32_t AhL[2048], BhL[2048], AlL[2048], BlL[2048];
  __shared__ uint32_t AmL[NB], BmL[NB];

  const int z = blockIdx.z;
  const float* __restrict__ A    = g.A[z];
  const float* __restrict__ B    = g.B[z];
  const float* __restrict__ bias = g.bias[z];
  float* __restrict__       C    = g.C[z];
  const int bm = blockIdx.y * 128, bn = blockIdx.x * 128;

  const int t   = threadIdx.x;
  const int sr  = t >> 1, skh = t & 1;
  const int lane = t & 63, wid = t >> 6;
  const int wr = wid >> 1, wc = wid & 1;
  const int kg = lane >> 4, l15 = lane & 15;

  int aoff[4], boff[4];
#pragma unroll
  for (int m = 0; m < 4; ++m) {
    const int row = wr * 64 + m * 16 + l15;
    aoff[m] = row * 64 + ((kg ^ ((row >> 1) & 3)) << 4);
    const int col = wc * 64 + m * 16 + l15;
    boff[m] = col * 64 + ((kg ^ ((col >> 1) & 3)) << 4);
  }

  f32x4 acc[4][4];
#pragma unroll
  for (int m = 0; m < 4; ++m)
#pragma unroll
    for (int n = 0; n < 4; ++n) acc[m][n] = (f32x4){0.f, 0.f, 0.f, 0.f};

  float va[16], vb[16];
  load_a16(A + (size_t)(bm + sr) * K + skh * 16, va);
  load_b16(B + (size_t)(skh * 16) * N + bn + sr, N, vb);

  for (int kk = 0; kk < K; kk += 32) {
    __syncthreads();
    split_write<WAYS>(va, sr, skh, AhL, AmL, AlL);
    split_write<WAYS>(vb, sr, skh, BhL, BmL, BlL);
    __syncthreads();
    const bool more = (kk + 32 < K);
    if (LOAD_EARLY && more) {
      load_a16(A + (size_t)(bm + sr) * K + kk + 32 + skh * 16, va);
      load_b16(B + (size_t)(kk + 32 + skh * 16) * N + bn + sr, N, vb);
    }
    bf16x8 ah[4], al[4], bh[4], bl[4], am[4], bmf[4];
#pragma unroll
    for (int m = 0; m < 4; ++m) {
      ah[m] = *(const bf16x8*)((const char*)AhL + aoff[m]);
      al[m] = *(const bf16x8*)((const char*)AlL + aoff[m]);
      bh[m] = *(const bf16x8*)((const char*)BhL + boff[m]);
      bl[m] = *(const bf16x8*)((const char*)BlL + boff[m]);
      if (WAYS == 3) {
        am[m]  = *(const bf16x8*)((const char*)AmL + aoff[m]);
        bmf[m] = *(const bf16x8*)((const char*)BmL + boff[m]);
      }
    }
#pragma unroll
    for (int m = 0; m < 4; ++m)
#pragma unroll
      for (int n = 0; n < 4; ++n) {
        acc[m][n] = __builtin_amdgcn_mfma_f32_16x16x32_bf16(ah[m], bh[n], acc[m][n], 0, 0, 0);
        if (WAYS == 3) {
          acc[m][n] = __builtin_amdgcn_mfma_f32_16x16x32_bf16(ah[m], bmf[n], acc[m][n], 0, 0, 0);
          acc[m][n] = __builtin_amdgcn_mfma_f32_16x16x32_bf16(am[m], bh[n],  acc[m][n], 0, 0, 0);
          acc[m][n] = __builtin_amdgcn_mfma_f32_16x16x32_bf16(am[m], bmf[n], acc[m][n], 0, 0, 0);
        }
        acc[m][n] = __builtin_amdgcn_mfma_f32_16x16x32_bf16(ah[m], bl[n], acc[m][n], 0, 0, 0);
        acc[m][n] = __builtin_amdgcn_mfma_f32_16x16x32_bf16(al[m], bh[n], acc[m][n], 0, 0, 0);
      }
    if (!LOAD_EARLY && more) {
      load_a16(A + (size_t)(bm + sr) * K + kk + 32 + skh * 16, va);
      load_b16(B + (size_t)(kk + 32 + skh * 16) * N + bn + sr, N, vb);
    }
  }

#pragma unroll
  for (int m = 0; m < 4; ++m) {
    const int row0 = bm + wr * 64 + m * 16 + (lane >> 4) * 4;
#pragma unroll
    for (int n = 0; n < 4; ++n) {
      const int col = bn + wc * 64 + n * 16 + l15;
      const float bv = bias[col];
      const f32x4 a = acc[m][n];
#pragma unroll
      for (int q2 = 0; q2 < 4; ++q2) {
        float o = a[q2] + bv;
        if (RELU) o = fmaxf(o, 0.f);
        C[(size_t)(row0 + q2) * N + col] = o;
      }
    }
  }
}

// ---------------- sampled QK^T -> M scores --------------------------------
__global__ __launch_bounds__(256) void qks_m_kernel(
    const float* __restrict__ Q, const float* __restrict__ K,
    const int* __restrict__ idx, float* __restrict__ Mout)
{
  const int gw   = blockIdx.x * 4 + (threadIdx.x >> 6);
  const int lane = threadIdx.x & 63;
  const int l  = gw & (L_ - 1);
  const int bh = gw >> 10;
  const int h  = bh & (H_ - 1);
  const int b  = bh >> 4;
  const float q = Q[(size_t)(b * L_ + l) * DM_ + h * DH_ + lane];
  float mx = -__builtin_inff();
  float sm = 0.f;
  const int* ip = idx + l * U_;
  for (int s = 0; s < U_; ++s) {
    const int ks = ip[s];
    float p = q * K[(size_t)(b * L_ + ks) * DM_ + h * DH_ + lane];
#pragma unroll
    for (int off = 32; off > 0; off >>= 1) p += __shfl_xor(p, off, 64);
    mx = fmaxf(mx, p);
    sm += p;
  }
  if (lane == 0) Mout[gw] = mx - sm * (1.0f / 1024.0f);
}

// ---------------- top-35 indices per (b,h) --------------------------------
__global__ __launch_bounds__(256) void topk_kernel(
    const float* __restrict__ M, int* __restrict__ Mtop)
{
  const int bh  = blockIdx.x;
  const int tid = threadIdx.x;
  __shared__ float vals[L_];
  __shared__ float rv[256];
  __shared__ int   ri[256];
  for (int i = tid; i < L_; i += 256) vals[i] = M[(size_t)bh * L_ + i];
  __syncthreads();
  for (int t = 0; t < U_; ++t) {
    float best = -__builtin_inff();
    int   bi   = L_;
    for (int i = tid; i < L_; i += 256) {
      const float v = vals[i];
      if (v > best) { best = v; bi = i; }
    }
    rv[tid] = best; ri[tid] = bi;
    __syncthreads();
    for (int s = 128; s > 0; s >>= 1) {
      if (tid < s) {
        if (rv[tid+s] > rv[tid] || (rv[tid+s] == rv[tid] && ri[tid+s] < ri[tid])) {
          rv[tid] = rv[tid+s]; ri[tid] = ri[tid+s];
        }
      }
      __syncthreads();
    }
    if (tid == 0) { Mtop[bh * U_ + t] = ri[0]; vals[ri[0]] = -__builtin_inff(); }
    __syncthreads();
  }
}

// ---------------- fused attention: one block per (b,h) --------------------
// 1024 threads = 16 waves. Thread t owns k-row t: 35 scores in registers,
// softmax via wave-shuffle + 16-wide LDS tree, P packed to bf16 pairs in LDS
// (two k-halves of [512][18]u32), PV with wave->u-pair mapping:
// wave w accumulates u=2w,2w+1 (+32+w for w<3); V loads coalesced per wave.
__global__ __launch_bounds__(1024) void attn_fused(
    const float* __restrict__ Q, const float* __restrict__ K,
    const float* __restrict__ V, const int* __restrict__ Mtop,
    float* __restrict__ ctx_rows, int masked)
{
  __shared__ float    qs[U_ * DH_];     // 8960 B
  __shared__ uint32_t Pl[512 * 18];     // 36864 B
  __shared__ float    wredA[U_ * 16];   // 2240 B
  __shared__ float    wredB[U_ * 16];   // 2240 B
  __shared__ int      rowsL[U_ + 1];

  const int bh   = blockIdx.x;
  const int h    = bh & (H_ - 1), b = bh >> 4;
  const int tid  = threadIdx.x;
  const int lane = tid & 63, wid = tid >> 6;
  const size_t kvbase = (size_t)(b * L_) * DM_ + h * DH_;

  if (tid < U_) rowsL[tid] = Mtop[bh * U_ + tid];
  __syncthreads();
  for (int i = tid; i < U_ * DH_; i += 1024)
    qs[i] = Q[kvbase + (size_t)rowsL[i >> 6] * DM_ + (i & 63)];
  __syncthreads();

  // ---- scores: thread owns k = tid ----
  const int k = tid;
  float s[U_];
#pragma unroll
  for (int u = 0; u < U_; ++u) s[u] = 0.f;
  const float* kp = K + kvbase + (size_t)k * DM_;
#pragma unroll
  for (int dc = 0; dc < 64; dc += 16) {
    const float4 k0 = *(const float4*)(kp + dc);
    const float4 k1 = *(const float4*)(kp + dc + 4);
    const float4 k2 = *(const float4*)(kp + dc + 8);
    const float4 k3 = *(const float4*)(kp + dc + 12);
#pragma unroll
    for (int u = 0; u < U_; ++u) {
      const float4* qp = (const float4*)&qs[u * 64 + dc];
      const float4 q0 = qp[0], q1 = qp[1], q2 = qp[2], q3 = qp[3];
      float acc = s[u];
      acc = fmaf(q0.x, k0.x, acc); acc = fmaf(q0.y, k0.y, acc);
      acc = fmaf(q0.z, k0.z, acc); acc = fmaf(q0.w, k0.w, acc);
      acc = fmaf(q1.x, k1.x, acc); acc = fmaf(q1.y, k1.y, acc);
      acc = fmaf(q1.z, k1.z, acc); acc = fmaf(q1.w, k1.w, acc);
      acc = fmaf(q2.x, k2.x, acc); acc = fmaf(q2.y, k2.y, acc);
      acc = fmaf(q2.z, k2.z, acc); acc = fmaf(q2.w, k2.w, acc);
      acc = fmaf(q3.x, k3.x, acc); acc = fmaf(q3.y, k3.y, acc);
      acc = fmaf(q3.z, k3.z, acc); acc = fmaf(q3.w, k3.w, acc);
      s[u] = acc;
    }
  }
#pragma unroll
  for (int u = 0; u < U_; ++u) {
    float v = s[u] * 0.125f;                       // 1/sqrt(64)
    if (masked && k > rowsL[u]) v = -__builtin_inff();
    s[u] = v;
  }

  // ---- row max (wave shuffle + cross-wave LDS) ----
#pragma unroll
  for (int u = 0; u < U_; ++u) {
    float m = s[u];
#pragma unroll
    for (int off = 32; off > 0; off >>= 1) m = fmaxf(m, __shfl_xor(m, off, 64));
    if (lane == 0) wredA[u * 16 + wid] = m;
  }
  __syncthreads();
#pragma unroll
  for (int u = 0; u < U_; ++u) {
    float m = wredA[u * 16];
#pragma unroll
    for (int w2 = 1; w2 < 16; ++w2) m = fmaxf(m, wredA[u * 16 + w2]);
    s[u] = expf(s[u] - m);                         // exp(-inf)=0 handles mask
  }

  // ---- row sum ----
#pragma unroll
  for (int u = 0; u < U_; ++u) {
    float m = s[u];
#pragma unroll
    for (int off = 32; off > 0; off >>= 1) m += __shfl_xor(m, off, 64);
    if (lane == 0) wredB[u * 16 + wid] = m;
  }
  __syncthreads();
  float inv[U_];
#pragma unroll
  for (int u = 0; u < U_; ++u) {
    float t = wredB[u * 16];
#pragma unroll
    for (int w2 = 1; w2 < 16; ++w2) t += wredB[u * 16 + w2];
    inv[u] = 1.0f / t;
  }

  // ---- PV in two k-halves through LDS (bf16-packed P) ----
  float a0 = 0.f, a1 = 0.f, a2 = 0.f;
  const int u0 = 2 * wid, u1 = 2 * wid + 1;        // u2 = 32+wid for wid<3
  const float* vp = V + kvbase + lane;
  const int kr = k & 511;
#pragma unroll
  for (int half = 0; half < 2; ++half) {
    __syncthreads();
    if ((k >> 9) == half) {
#pragma unroll
      for (int j = 0; j < 17; ++j)
        Pl[kr * 18 + j] = bf16rne(s[2*j] * inv[2*j]) | (bf16rne(s[2*j+1] * inv[2*j+1]) << 16);
      Pl[kr * 18 + 17] = bf16rne(s[34] * inv[34]);
    }
    __syncthreads();
    const size_t vbase = (size_t)half * 512 * DM_;
    for (int kk = 0; kk < 512; kk += 2) {
      const float v0 = vp[vbase + (size_t)kk * DM_];
      const float v1 = vp[vbase + (size_t)(kk + 1) * DM_];
      const uint32_t p0 = Pl[kk * 18 + wid];
      const uint32_t p1 = Pl[(kk + 1) * 18 + wid];
      a0 = fmaf(bitsf32(p0 << 16), v0, a0);
      a1 = fmaf(bitsf32(p0 & 0xFFFF0000u), v0, a1);
      a0 = fmaf(bitsf32(p1 << 16), v1, a0);
      a1 = fmaf(bitsf32(p1 & 0xFFFF0000u), v1, a1);
      if (wid == 0) {
        a2 = fmaf(bitsf32(Pl[kk * 18 + 16] << 16), v0, a2);
        a2 = fmaf(bitsf32(Pl[(kk+1) * 18 + 16] << 16), v1, a2);
      } else if (wid == 1) {
        a2 = fmaf(bitsf32(Pl[kk * 18 + 16] & 0xFFFF0000u), v0, a2);
        a2 = fmaf(bitsf32(Pl[(kk+1) * 18 + 16] & 0xFFFF0000u), v1, a2);
      } else if (wid == 2) {
        a2 = fmaf(bitsf32(Pl[kk * 18 + 17] << 16), v0, a2);
        a2 = fmaf(bitsf32(Pl[(kk+1) * 18 + 17] << 16), v1, a2);
      }
    }
  }
  ctx_rows[(size_t)(bh * U_ + u0) * DH_ + lane] = a0;
  ctx_rows[(size_t)(bh * U_ + u1) * DH_ + lane] = a1;
  if (wid < 3)
    ctx_rows[(size_t)(bh * U_ + 32 + wid) * DH_ + lane] = a2;
}

// ---------------- cumsum(V) over L per (b,h,d) ----------------------------
__global__ __launch_bounds__(256) void cumsum_kernel(
    const float* __restrict__ V, float* __restrict__ C)
{
  const int bh = blockIdx.x;
  const int h = bh & (H_ - 1), b = bh >> 4;
  const int d = threadIdx.x & 63, qq = threadIdx.x >> 6;
  __shared__ float chs[4][DH_];
  const size_t base = (size_t)b * L_ * DM_ + h * DH_ + d;
  float acc = 0.f;
  const int l0 = qq * 256;
  for (int l = l0; l < l0 + 256; ++l) acc += V[base + (size_t)l * DM_];
  chs[qq][d] = acc;
  __syncthreads();
  float off = 0.f;
  for (int j = 0; j < qq; ++j) off += chs[j][d];
  acc = off;
  for (int l = l0; l < l0 + 256; ++l) {
    acc += V[base + (size_t)l * DM_];
    C[base + (size_t)l * DM_] = acc;
  }
}

__global__ __launch_bounds__(256) void vmean_kernel(
    const float* __restrict__ V, float* __restrict__ vm)
{
  const int bh = blockIdx.x;
  const int h = bh & (H_ - 1), b = bh >> 4;
  const int d = threadIdx.x & 63, qq = threadIdx.x >> 6;
  __shared__ float chs[4][DH_];
  const size_t base = (size_t)b * L_ * DM_ + h * DH_ + d;
  float acc = 0.f;
  for (int l = qq * 256; l < qq * 256 + 256; ++l) acc += V[base + (size_t)l * DM_];
  chs[qq][d] = acc;
  __syncthreads();
  if (qq == 0)
    vm[bh * DH_ + d] = (chs[0][d] + chs[1][d] + chs[2][d] + chs[3][d]) * (1.0f / 1024.0f);
}

__global__ void fill_kernel(const float* __restrict__ vm, float* __restrict__ C)
{
  const size_t i = (size_t)blockIdx.x * 256 + threadIdx.x;
  const int d = (int)(i & 63);
  const int h = (int)((i >> 6) & (H_ - 1));
  const int b = (int)(i >> 20);
  C[i] = vm[(b * H_ + h) * DH_ + d];
}

__global__ void scatter_kernel(const float* __restrict__ ctx_rows,
                               const int* __restrict__ Mtop, float* __restrict__ C)
{
  const int bhu = blockIdx.x;
  const int u  = bhu % U_;
  const int bh = bhu / U_;
  const int h = bh & (H_ - 1), b = bh >> 4;
  const int row = Mtop[bh * U_ + u];
  C[(size_t)(b * L_ + row) * DM_ + h * DH_ + threadIdx.x] =
      ctx_rows[(size_t)bhu * DH_ + threadIdx.x];
}

// ---------------- LayerNorm(xa + xb) --------------------------------------
__global__ __launch_bounds__(256) void ln_kernel(
    const float* __restrict__ xa, const float* __restrict__ xb,
    const float* __restrict__ g, const float* __restrict__ bt,
    float* __restrict__ out)
{
  const int row = blockIdx.x;
  const int tid = threadIdx.x;
  __shared__ float v[DM_];
  __shared__ float red[256];
  float s = 0.f;
  for (int i = tid; i < DM_; i += 256) {
    const float t = xa[(size_t)row * DM_ + i] + xb[(size_t)row * DM_ + i];
    v[i] = t; s += t;
  }
  red[tid] = s; __syncthreads();
  for (int st = 128; st > 0; st >>= 1) { if (tid < st) red[tid] += red[tid+st]; __syncthreads(); }
  const float mean = red[0] * (1.0f / DM_);
  __syncthreads();
  float s2 = 0.f;
  for (int i = tid; i < DM_; i += 256) { const float dd = v[i] - mean; s2 += dd * dd; }
  red[tid] = s2; __syncthreads();
  for (int st = 128; st > 0; st >>= 1) { if (tid < st) red[tid] += red[tid+st]; __syncthreads(); }
  const float rstd = rsqrtf(red[0] * (1.0f / DM_) + 1e-5f);
  __syncthreads();
  for (int i = tid; i < DM_; i += 256)
    out[(size_t)row * DM_ + i] = (v[i] - mean) * rstd * g[i] + bt[i];
}

// ---------------- host orchestration --------------------------------------
extern "C" void kernel_launch(void* const* d_in, const int* in_sizes, int n_in,
                              void* d_out, int out_size, void* d_ws, size_t ws_size,
                              hipStream_t stream)
{
  (void)in_sizes; (void)n_in; (void)out_size; (void)ws_size;
  const float* x    = (const float*)d_in[0];
  const float* enc  = (const float*)d_in[1];
  const float* saWq = (const float*)d_in[2];  const float* sabq = (const float*)d_in[3];
  const float* saWk = (const float*)d_in[4];  const float* sabk = (const float*)d_in[5];
  const float* saWv = (const float*)d_in[6];  const float* sabv = (const float*)d_in[7];
  const float* saWo = (const float*)d_in[8];  const float* sabo = (const float*)d_in[9];
  const float* caWq = (const float*)d_in[10]; const float* cabq = (const float*)d_in[11];
  const float* caWk = (const float*)d_in[12]; const float* cabk = (const float*)d_in[13];
  const float* caWv = (const float*)d_in[14]; const float* cabv = (const float*)d_in[15];
  const float* caWo = (const float*)d_in[16]; const float* cabo = (const float*)d_in[17];
  const float* fW1  = (const float*)d_in[18]; const float* fb1  = (const float*)d_in[19];
  const float* fW2  = (const float*)d_in[20]; const float* fb2  = (const float*)d_in[21];
  const float* l1g  = (const float*)d_in[22]; const float* l1b  = (const float*)d_in[23];
  const float* l2g  = (const float*)d_in[24]; const float* l2b  = (const float*)d_in[25];
  const float* l3g  = (const float*)d_in[26]; const float* l3b  = (const float*)d_in[27];

  float* ws = (float*)d_ws;
  const size_t SL = (size_t)MROWS_ * DM_;      // 4M floats / 16 MB
  float* bufQ   = ws;
  float* bufK   = ws + SL;
  float* bufV   = ws + 2 * SL;
  float* bufC   = ws + 3 * SL;
  float* xcur   = ws + 4 * SL;
  float* tmp    = ws + 5 * SL;
  float* hidden = ws;                           // FFN stage reuses slots 0..3 (64 MB)
  float* smallp = ws + 6 * SL;
  int*   idxb = (int*)smallp;                                // 35840
  float* Mbuf = smallp + 36864;                              // 65536
  int*   Mtop = (int*)(smallp + 36864 + 65536);              // 2240 (pad to 2304)
  float* ctxr = smallp + 36864 + 65536 + 2304;               // 2240*64
  float* vm   = ctxr + 143360;                               // 1024

  // --- JAX partitionable-threefry key ladder (verified round 3) ---
  uint32_t k1a, k1b, k2a, k2b;
  tf2x32(0u, 42u, 0u, 0u, k1a, k1b);   // k1 = split(key)[0]
  tf2x32(0u, 42u, 0u, 1u, k2a, k2b);   // k2 = split(key)[1]
  uint32_t kb1a, kb1b, kb2a, kb2b;
  tf2x32(k1a, k1b, 0u, 1u, kb1a, kb1b);  // randint-internal split(k1)[1]
  tf2x32(k2a, k2b, 0u, 1u, kb2a, kb2b);  // randint-internal split(k2)[1]

  const dim3 thr(256);
  const int gIdx = (IDXN_ + 255) / 256;

  const dim3 gP1(DM_ / 128, MROWS_ / 128, 1);   // (8,32,1)
  const dim3 gP3(DM_ / 128, MROWS_ / 128, 3);   // (8,32,3)
  const dim3 gF1(FF_ / 128, MROWS_ / 128, 1);   // (32,32,1)

  // ---- self attention (masked) ----
  {
    Gemm3 g = {{x, x, x}, {saWq, saWk, saWv}, {sabq, sabk, sabv}, {bufQ, bufK, bufV}};
    gemm_mfma<3, false, false><<<gP3, thr, 0, stream>>>(g, DM_, DM_);
  }
  idx_kernel<<<gIdx, thr, 0, stream>>>(kb1a, kb1b, idxb);
  qks_m_kernel<<<(B_ * H_ * L_) / 4, thr, 0, stream>>>(bufQ, bufK, idxb, Mbuf);
  topk_kernel<<<B_ * H_, thr, 0, stream>>>(Mbuf, Mtop);
  attn_fused<<<B_ * H_, dim3(1024), 0, stream>>>(bufQ, bufK, bufV, Mtop, ctxr, 1);
  cumsum_kernel<<<B_ * H_, thr, 0, stream>>>(bufV, bufC);
  scatter_kernel<<<B_ * H_ * U_, dim3(64), 0, stream>>>(ctxr, Mtop, bufC);
  {
    Gemm3 g = {{bufC, nullptr, nullptr}, {saWo, nullptr, nullptr},
               {sabo, nullptr, nullptr}, {tmp, nullptr, nullptr}};
    gemm_mfma<2, false, true><<<gP1, thr, 0, stream>>>(g, DM_, DM_);
  }
  ln_kernel<<<MROWS_, thr, 0, stream>>>(x, tmp, l1g, l1b, xcur);

  // ---- cross attention (unmasked) ----
  {
    Gemm3 g = {{xcur, enc, enc}, {caWq, caWk, caWv}, {cabq, cabk, cabv}, {bufQ, bufK, bufV}};
    gemm_mfma<3, false, false><<<gP3, thr, 0, stream>>>(g, DM_, DM_);
  }
  idx_kernel<<<gIdx, thr, 0, stream>>>(kb2a, kb2b, idxb);
  qks_m_kernel<<<(B_ * H_ * L_) / 4, thr, 0, stream>>>(bufQ, bufK, idxb, Mbuf);
  topk_kernel<<<B_ * H_, thr, 0, stream>>>(Mbuf, Mtop);
  attn_fused<<<B_ * H_, dim3(1024), 0, stream>>>(bufQ, bufK, bufV, Mtop, ctxr, 0);
  vmean_kernel<<<B_ * H_, thr, 0, stream>>>(bufV, vm);
  fill_kernel<<<(int)(SL / 256), thr, 0, stream>>>(vm, bufC);
  scatter_kernel<<<B_ * H_ * U_, dim3(64), 0, stream>>>(ctxr, Mtop, bufC);
  {
    Gemm3 g = {{bufC, nullptr, nullptr}, {caWo, nullptr, nullptr},
               {cabo, nullptr, nullptr}, {tmp, nullptr, nullptr}};
    gemm_mfma<2, false, true><<<gP1, thr, 0, stream>>>(g, DM_, DM_);
  }
  ln_kernel<<<MROWS_, thr, 0, stream>>>(xcur, tmp, l2g, l2b, xcur);

  // ---- FFN ----
  {
    Gemm3 g = {{xcur, nullptr, nullptr}, {fW1, nullptr, nullptr},
               {fb1, nullptr, nullptr}, {hidden, nullptr, nullptr}};
    gemm_mfma<2, true, true><<<gF1, thr, 0, stream>>>(g, DM_, FF_);
  }
  {
    Gemm3 g = {{hidden, nullptr, nullptr}, {fW2, nullptr, nullptr},
               {fb2, nullptr, nullptr}, {tmp, nullptr, nullptr}};
    gemm_mfma<2, false, true><<<gP1, thr, 0, stream>>>(g, FF_, DM_);
  }
  ln_kernel<<<MROWS_, thr, 0, stream>>>(xcur, tmp, l3g, l3b, (float*)d_out);
}

// Round 7
// 3148.850 us; speedup vs baseline: 1.1110x; 1.1110x over previous
//
#include <hip/hip_runtime.h>
#include <cstdint>
#include <cstddef>

// Informer ProbSparse decoder layer. GEMMs via split-bf16 MFMA emulation.
// B=4 L=1024 Dm=1024 H=16 Dh=64 U=U_part=35 FF=4096.
#define B_     4
#define L_     1024
#define DM_    1024
#define H_     16
#define DH_    64
#define U_     35
#define FF_    4096
#define MROWS_ 4096          // B_*L_
#define IDXN_  35840         // L_*U_ random draws per attention

typedef __attribute__((ext_vector_type(8))) short bf16x8;
typedef __attribute__((ext_vector_type(4))) float f32x4;

// ---------------- Threefry-2x32-20 (exact JAX semantics) ----------------
__host__ __device__ inline void tf2x32(uint32_t k0, uint32_t k1,
                                       uint32_t x0, uint32_t x1,
                                       uint32_t& y0, uint32_t& y1) {
  const uint32_t ks2 = k0 ^ k1 ^ 0x1BD11BDAu;
  uint32_t v0 = x0 + k0, v1 = x1 + k1;
#define ROTL_(x,d) (((x)<<(d))|((x)>>(32-(d))))
#define RND_(r) { v0 += v1; v1 = ROTL_(v1,(r)); v1 ^= v0; }
  RND_(13) RND_(15) RND_(26) RND_(6)   v0 += k1;  v1 += ks2 + 1u;
  RND_(17) RND_(29) RND_(16) RND_(24)  v0 += ks2; v1 += k0  + 2u;
  RND_(13) RND_(15) RND_(26) RND_(6)   v0 += k0;  v1 += k1  + 3u;
  RND_(17) RND_(29) RND_(16) RND_(24)  v0 += k1;  v1 += ks2 + 4u;
  RND_(13) RND_(15) RND_(26) RND_(6)   v0 += ks2; v1 += k0  + 5u;
#undef RND_
#undef ROTL_
  y0 = v0; y1 = v1;
}

// JAX partitionable threefry random_bits, 32-bit: bits[i] = y0 ^ y1 (XOR fold).
__global__ void idx_kernel(uint32_t k0, uint32_t k1, int* __restrict__ idx) {
  const int i = blockIdx.x * 256 + threadIdx.x;
  if (i >= IDXN_) return;
  uint32_t y0, y1;
  tf2x32(k0, k1, 0u, (uint32_t)i, y0, y1);
  idx[i] = (int)((y0 ^ y1) & 1023u);
}

// ---------------- split-bf16 MFMA GEMM ------------------------------------
struct Gemm3 {
  const float* A[3];
  const float* B[3];
  const float* bias[3];
  float*       C[3];
};

__device__ __forceinline__ uint32_t f32bits(float x) {
  union { float f; uint32_t u; } c; c.f = x; return c.u;
}
__device__ __forceinline__ float bitsf32(uint32_t u) {
  union { uint32_t u; float f; } c; c.u = u; return c.f;
}
__device__ __forceinline__ uint32_t bf16rne(float x) {
  const uint32_t u = f32bits(x);
  return (u + 0x7FFFu + ((u >> 16) & 1u)) >> 16;
}

__device__ __forceinline__ void load_a16(const float* p, float (&v)[16]) {
  const float4* q = (const float4*)p;
  float4 x0 = q[0], x1 = q[1], x2 = q[2], x3 = q[3];
  v[0]=x0.x; v[1]=x0.y; v[2]=x0.z; v[3]=x0.w;
  v[4]=x1.x; v[5]=x1.y; v[6]=x1.z; v[7]=x1.w;
  v[8]=x2.x; v[9]=x2.y; v[10]=x2.z; v[11]=x2.w;
  v[12]=x3.x; v[13]=x3.y; v[14]=x3.z; v[15]=x3.w;
}
__device__ __forceinline__ void load_b16(const float* p, int N, float (&v)[16]) {
#pragma unroll
  for (int j = 0; j < 16; ++j) v[j] = p[(size_t)j * N];
}

template<int WAYS>
__device__ __forceinline__ void split_write(const float (&v)[16], int sr, int skh,
                                            uint32_t* H, uint32_t* Mi, uint32_t* L)
{
  uint32_t hp[8], lp[8], mp[8];
#pragma unroll
  for (int e = 0; e < 8; ++e) {
    const float a0 = v[2*e], a1 = v[2*e+1];
    const uint32_t h0 = f32bits(a0) & 0xFFFF0000u;
    const uint32_t h1 = f32bits(a1) & 0xFFFF0000u;
    hp[e] = (h0 >> 16) | h1;
    float r0 = a0 - bitsf32(h0);
    float r1 = a1 - bitsf32(h1);
    if (WAYS == 3) {
      const uint32_t m0 = f32bits(r0) & 0xFFFF0000u;
      const uint32_t m1 = f32bits(r1) & 0xFFFF0000u;
      mp[e] = (m0 >> 16) | m1;
      r0 -= bitsf32(m0); r1 -= bitsf32(m1);
    }
    lp[e] = bf16rne(r0) | (bf16rne(r1) << 16);
  }
  const int q  = (sr >> 1) & 3;
  const int b0 = sr * 64 + (((skh * 2 + 0) ^ q) << 4);
  const int b1 = sr * 64 + (((skh * 2 + 1) ^ q) << 4);
  *(uint4*)((char*)H + b0) = make_uint4(hp[0], hp[1], hp[2], hp[3]);
  *(uint4*)((char*)H + b1) = make_uint4(hp[4], hp[5], hp[6], hp[7]);
  if (WAYS == 3) {
    *(uint4*)((char*)Mi + b0) = make_uint4(mp[0], mp[1], mp[2], mp[3]);
    *(uint4*)((char*)Mi + b1) = make_uint4(mp[4], mp[5], mp[6], mp[7]);
  }
  *(uint4*)((char*)L + b0) = make_uint4(lp[0], lp[1], lp[2], lp[3]);
  *(uint4*)((char*)L + b1) = make_uint4(lp[4], lp[5], lp[6], lp[7]);
}

template<int WAYS, bool RELU, bool LOAD_EARLY>
__global__ __launch_bounds__(256, 2) void gemm_mfma(Gemm3 g, int K, int N)
{
  constexpr int NB = (WAYS == 3) ? 2048 : 4;
  __shared__ uint32_t AhL[2048], BhL[2048], AlL[2048], BlL[2048];
  __shared__ uint32_t AmL[NB], BmL[NB];

  const int z = blockIdx.z;
  const float* __restrict__ A    = g.A[z];
  const float* __restrict__ B    = g.B[z];
  const float* __restrict__ bias = g.bias[z];
  float* __restrict__       C    = g.C[z];
  const int bm = blockIdx.y * 128, bn = blockIdx.x * 128;

  const int t   = threadIdx.x;
  const int sr  = t >> 1, skh = t & 1;
  const int lane = t & 63, wid = t >> 6;
  const int wr = wid >> 1, wc = wid & 1;
  const int kg = lane >> 4, l15 = lane & 15;

  int aoff[4], boff[4];
#pragma unroll
  for (int m = 0; m < 4; ++m) {
    const int row = wr * 64 + m * 16 + l15;
    aoff[m] = row * 64 + ((kg ^ ((row >> 1) & 3)) << 4);
    const int col = wc * 64 + m * 16 + l15;
    boff[m] = col * 64 + ((kg ^ ((col >> 1) & 3)) << 4);
  }

  f32x4 acc[4][4];
#pragma unroll
  for (int m = 0; m < 4; ++m)
#pragma unroll
    for (int n = 0; n < 4; ++n) acc[m][n] = (f32x4){0.f, 0.f, 0.f, 0.f};

  float va[16], vb[16];
  load_a16(A + (size_t)(bm + sr) * K + skh * 16, va);
  load_b16(B + (size_t)(skh * 16) * N + bn + sr, N, vb);

  for (int kk = 0; kk < K; kk += 32) {
    __syncthreads();
    split_write<WAYS>(va, sr, skh, AhL, AmL, AlL);
    split_write<WAYS>(vb, sr, skh, BhL, BmL, BlL);
    __syncthreads();
    const bool more = (kk + 32 < K);
    if (LOAD_EARLY && more) {
      load_a16(A + (size_t)(bm + sr) * K + kk + 32 + skh * 16, va);
      load_b16(B + (size_t)(kk + 32 + skh * 16) * N + bn + sr, N, vb);
    }
    bf16x8 ah[4], al[4], bh[4], bl[4], am[4], bmf[4];
#pragma unroll
    for (int m = 0; m < 4; ++m) {
      ah[m] = *(const bf16x8*)((const char*)AhL + aoff[m]);
      al[m] = *(const bf16x8*)((const char*)AlL + aoff[m]);
      bh[m] = *(const bf16x8*)((const char*)BhL + boff[m]);
      bl[m] = *(const bf16x8*)((const char*)BlL + boff[m]);
      if (WAYS == 3) {
        am[m]  = *(const bf16x8*)((const char*)AmL + aoff[m]);
        bmf[m] = *(const bf16x8*)((const char*)BmL + boff[m]);
      }
    }
#pragma unroll
    for (int m = 0; m < 4; ++m)
#pragma unroll
      for (int n = 0; n < 4; ++n) {
        acc[m][n] = __builtin_amdgcn_mfma_f32_16x16x32_bf16(ah[m], bh[n], acc[m][n], 0, 0, 0);
        if (WAYS == 3) {
          acc[m][n] = __builtin_amdgcn_mfma_f32_16x16x32_bf16(ah[m], bmf[n], acc[m][n], 0, 0, 0);
          acc[m][n] = __builtin_amdgcn_mfma_f32_16x16x32_bf16(am[m], bh[n],  acc[m][n], 0, 0, 0);
          acc[m][n] = __builtin_amdgcn_mfma_f32_16x16x32_bf16(am[m], bmf[n], acc[m][n], 0, 0, 0);
        }
        acc[m][n] = __builtin_amdgcn_mfma_f32_16x16x32_bf16(ah[m], bl[n], acc[m][n], 0, 0, 0);
        acc[m][n] = __builtin_amdgcn_mfma_f32_16x16x32_bf16(al[m], bh[n], acc[m][n], 0, 0, 0);
      }
    if (!LOAD_EARLY && more) {
      load_a16(A + (size_t)(bm + sr) * K + kk + 32 + skh * 16, va);
      load_b16(B + (size_t)(kk + 32 + skh * 16) * N + bn + sr, N, vb);
    }
  }

#pragma unroll
  for (int m = 0; m < 4; ++m) {
    const int row0 = bm + wr * 64 + m * 16 + (lane >> 4) * 4;
#pragma unroll
    for (int n = 0; n < 4; ++n) {
      const int col = bn + wc * 64 + n * 16 + l15;
      const float bv = bias[col];
      const f32x4 a = acc[m][n];
#pragma unroll
      for (int q2 = 0; q2 < 4; ++q2) {
        float o = a[q2] + bv;
        if (RELU) o = fmaxf(o, 0.f);
        C[(size_t)(row0 + q2) * N + col] = o;
      }
    }
  }
}

// ---------------- sampled QK^T -> M scores --------------------------------
__global__ __launch_bounds__(256) void qks_m_kernel(
    const float* __restrict__ Q, const float* __restrict__ K,
    const int* __restrict__ idx, float* __restrict__ Mout)
{
  const int gw   = blockIdx.x * 4 + (threadIdx.x >> 6);
  const int lane = threadIdx.x & 63;
  const int l  = gw & (L_ - 1);
  const int bh = gw >> 10;
  const int h  = bh & (H_ - 1);
  const int b  = bh >> 4;
  const float q = Q[(size_t)(b * L_ + l) * DM_ + h * DH_ + lane];
  float mx = -__builtin_inff();
  float sm = 0.f;
  const int* ip = idx + l * U_;
  for (int s = 0; s < U_; ++s) {
    const int ks = ip[s];
    float p = q * K[(size_t)(b * L_ + ks) * DM_ + h * DH_ + lane];
#pragma unroll
    for (int off = 32; off > 0; off >>= 1) p += __shfl_xor(p, off, 64);
    mx = fmaxf(mx, p);
    sm += p;
  }
  if (lane == 0) Mout[gw] = mx - sm * (1.0f / 1024.0f);
}

// ---------------- top-35 indices per (b,h) --------------------------------
__global__ __launch_bounds__(256) void topk_kernel(
    const float* __restrict__ M, int* __restrict__ Mtop)
{
  const int bh  = blockIdx.x;
  const int tid = threadIdx.x;
  __shared__ float vals[L_];
  __shared__ float rv[256];
  __shared__ int   ri[256];
  for (int i = tid; i < L_; i += 256) vals[i] = M[(size_t)bh * L_ + i];
  __syncthreads();
  for (int t = 0; t < U_; ++t) {
    float best = -__builtin_inff();
    int   bi   = L_;
    for (int i = tid; i < L_; i += 256) {
      const float v = vals[i];
      if (v > best) { best = v; bi = i; }
    }
    rv[tid] = best; ri[tid] = bi;
    __syncthreads();
    for (int s = 128; s > 0; s >>= 1) {
      if (tid < s) {
        if (rv[tid+s] > rv[tid] || (rv[tid+s] == rv[tid] && ri[tid+s] < ri[tid])) {
          rv[tid] = rv[tid+s]; ri[tid] = ri[tid+s];
        }
      }
      __syncthreads();
    }
    if (tid == 0) { Mtop[bh * U_ + t] = ri[0]; vals[ri[0]] = -__builtin_inff(); }
    __syncthreads();
  }
}

// ---------------- fused attention: one block per (b,h) --------------------
// 1024 threads = 16 waves, 1 block/CU (launch_bounds(1024,4) -> 128 VGPR cap,
// no spill: s[35] + temps ~ 80 VGPR). Thread t owns k-row t: 35 scores in
// registers; softmax via wave shuffle + finalize-by-35-threads (no per-thread
// 16-wide scans); P stored UNNORMALIZED bf16 in LDS (normalization applied in
// the PV epilogue from the per-u totals) -> no inv[35] register array.
__global__ __launch_bounds__(1024, 4) void attn_fused(
    const float* __restrict__ Q, const float* __restrict__ K,
    const float* __restrict__ V, const int* __restrict__ Mtop,
    float* __restrict__ ctx_rows, int masked)
{
  __shared__ float    qs[U_ * DH_];     // 8960 B
  __shared__ uint32_t Pl[512 * 18];     // 36864 B
  __shared__ float    wredA[U_ * 16];   // 2240 B  (max partials / final at [u*16])
  __shared__ float    wredB[U_ * 16];   // 2240 B  (sum partials / final at [u*16])
  __shared__ int      rowsL[U_ + 1];

  const int bh   = blockIdx.x;
  const int h    = bh & (H_ - 1), b = bh >> 4;
  const int tid  = threadIdx.x;
  const int lane = tid & 63, wid = tid >> 6;
  const size_t kvbase = (size_t)(b * L_) * DM_ + h * DH_;

  if (tid < U_) rowsL[tid] = Mtop[bh * U_ + tid];
  __syncthreads();
  for (int i = tid; i < U_ * DH_; i += 1024)
    qs[i] = Q[kvbase + (size_t)rowsL[i >> 6] * DM_ + (i & 63)];
  __syncthreads();

  // ---- scores: thread owns k = tid ----
  const int k = tid;
  float s[U_];
#pragma unroll
  for (int u = 0; u < U_; ++u) s[u] = 0.f;
  const float* kp = K + kvbase + (size_t)k * DM_;
#pragma unroll
  for (int dc = 0; dc < 64; dc += 16) {
    const float4 k0 = *(const float4*)(kp + dc);
    const float4 k1 = *(const float4*)(kp + dc + 4);
    const float4 k2 = *(const float4*)(kp + dc + 8);
    const float4 k3 = *(const float4*)(kp + dc + 12);
#pragma unroll
    for (int u = 0; u < U_; ++u) {
      const float4* qp = (const float4*)&qs[u * 64 + dc];
      const float4 q0 = qp[0], q1 = qp[1], q2 = qp[2], q3 = qp[3];
      float acc = s[u];
      acc = fmaf(q0.x, k0.x, acc); acc = fmaf(q0.y, k0.y, acc);
      acc = fmaf(q0.z, k0.z, acc); acc = fmaf(q0.w, k0.w, acc);
      acc = fmaf(q1.x, k1.x, acc); acc = fmaf(q1.y, k1.y, acc);
      acc = fmaf(q1.z, k1.z, acc); acc = fmaf(q1.w, k1.w, acc);
      acc = fmaf(q2.x, k2.x, acc); acc = fmaf(q2.y, k2.y, acc);
      acc = fmaf(q2.z, k2.z, acc); acc = fmaf(q2.w, k2.w, acc);
      acc = fmaf(q3.x, k3.x, acc); acc = fmaf(q3.y, k3.y, acc);
      acc = fmaf(q3.z, k3.z, acc); acc = fmaf(q3.w, k3.w, acc);
      s[u] = acc;
    }
  }
#pragma unroll
  for (int u = 0; u < U_; ++u) {
    float v = s[u] * 0.125f;                       // 1/sqrt(64)
    if (masked && k > rowsL[u]) v = -__builtin_inff();
    s[u] = v;
  }

  // ---- row max: wave shuffle -> partials -> finalize by threads <35 ----
#pragma unroll
  for (int u = 0; u < U_; ++u) {
    float m = s[u];
#pragma unroll
    for (int off = 32; off > 0; off >>= 1) m = fmaxf(m, __shfl_xor(m, off, 64));
    if (lane == 0) wredA[u * 16 + wid] = m;
  }
  __syncthreads();
  if (tid < U_) {
    float m = wredA[tid * 16];
#pragma unroll
    for (int w2 = 1; w2 < 16; ++w2) m = fmaxf(m, wredA[tid * 16 + w2]);
    wredA[tid * 16] = m;
  }
  __syncthreads();
#pragma unroll
  for (int u = 0; u < U_; ++u)
    s[u] = expf(s[u] - wredA[u * 16]);             // exp(-inf)=0 handles mask

  // ---- row sum: same pattern ----
#pragma unroll
  for (int u = 0; u < U_; ++u) {
    float m = s[u];
#pragma unroll
    for (int off = 32; off > 0; off >>= 1) m += __shfl_xor(m, off, 64);
    if (lane == 0) wredB[u * 16 + wid] = m;
  }
  __syncthreads();
  if (tid < U_) {
    float t = wredB[tid * 16];
#pragma unroll
    for (int w2 = 1; w2 < 16; ++w2) t += wredB[tid * 16 + w2];
    wredB[tid * 16] = t;
  }
  // (next __syncthreads at top of the half-loop publishes the totals)

  // ---- PV in two k-halves through LDS (unnormalized bf16 P) ----
  float a0 = 0.f, a1 = 0.f, a2 = 0.f;
  const int u0 = 2 * wid, u1 = 2 * wid + 1;        // u2 = 32+wid for wid<3
  const float* vp = V + kvbase + lane;
  const int kr = k & 511;
#pragma unroll
  for (int half = 0; half < 2; ++half) {
    __syncthreads();
    if ((k >> 9) == half) {
#pragma unroll
      for (int j = 0; j < 17; ++j)
        Pl[kr * 18 + j] = bf16rne(s[2*j]) | (bf16rne(s[2*j+1]) << 16);
      Pl[kr * 18 + 17] = bf16rne(s[34]);
    }
    __syncthreads();
    const size_t vbase = (size_t)half * 512 * DM_;
    for (int kk = 0; kk < 512; kk += 2) {
      const float v0 = vp[vbase + (size_t)kk * DM_];
      const float v1 = vp[vbase + (size_t)(kk + 1) * DM_];
      const uint32_t p0 = Pl[kk * 18 + wid];
      const uint32_t p1 = Pl[(kk + 1) * 18 + wid];
      a0 = fmaf(bitsf32(p0 << 16), v0, a0);
      a1 = fmaf(bitsf32(p0 & 0xFFFF0000u), v0, a1);
      a0 = fmaf(bitsf32(p1 << 16), v1, a0);
      a1 = fmaf(bitsf32(p1 & 0xFFFF0000u), v1, a1);
      if (wid == 0) {
        a2 = fmaf(bitsf32(Pl[kk * 18 + 16] << 16), v0, a2);
        a2 = fmaf(bitsf32(Pl[(kk+1) * 18 + 16] << 16), v1, a2);
      } else if (wid == 1) {
        a2 = fmaf(bitsf32(Pl[kk * 18 + 16] & 0xFFFF0000u), v0, a2);
        a2 = fmaf(bitsf32(Pl[(kk+1) * 18 + 16] & 0xFFFF0000u), v1, a2);
      } else if (wid == 2) {
        a2 = fmaf(bitsf32(Pl[kk * 18 + 17] << 16), v0, a2);
        a2 = fmaf(bitsf32(Pl[(kk+1) * 18 + 17] << 16), v1, a2);
      }
    }
  }
  ctx_rows[(size_t)(bh * U_ + u0) * DH_ + lane] = a0 / wredB[u0 * 16];
  ctx_rows[(size_t)(bh * U_ + u1) * DH_ + lane] = a1 / wredB[u1 * 16];
  if (wid < 3)
    ctx_rows[(size_t)(bh * U_ + 32 + wid) * DH_ + lane] = a2 / wredB[(32 + wid) * 16];
}

// ---------------- cumsum(V) over L per (b,h,d) ----------------------------
__global__ __launch_bounds__(256) void cumsum_kernel(
    const float* __restrict__ V, float* __restrict__ C)
{
  const int bh = blockIdx.x;
  const int h = bh & (H_ - 1), b = bh >> 4;
  const int d = threadIdx.x & 63, qq = threadIdx.x >> 6;
  __shared__ float chs[4][DH_];
  const size_t base = (size_t)b * L_ * DM_ + h * DH_ + d;
  float acc = 0.f;
  const int l0 = qq * 256;
  for (int l = l0; l < l0 + 256; ++l) acc += V[base + (size_t)l * DM_];
  chs[qq][d] = acc;
  __syncthreads();
  float off = 0.f;
  for (int j = 0; j < qq; ++j) off += chs[j][d];
  acc = off;
  for (int l = l0; l < l0 + 256; ++l) {
    acc += V[base + (size_t)l * DM_];
    C[base + (size_t)l * DM_] = acc;
  }
}

__global__ __launch_bounds__(256) void vmean_kernel(
    const float* __restrict__ V, float* __restrict__ vm)
{
  const int bh = blockIdx.x;
  const int h = bh & (H_ - 1), b = bh >> 4;
  const int d = threadIdx.x & 63, qq = threadIdx.x >> 6;
  __shared__ float chs[4][DH_];
  const size_t base = (size_t)b * L_ * DM_ + h * DH_ + d;
  float acc = 0.f;
  for (int l = qq * 256; l < qq * 256 + 256; ++l) acc += V[base + (size_t)l * DM_];
  chs[qq][d] = acc;
  __syncthreads();
  if (qq == 0)
    vm[bh * DH_ + d] = (chs[0][d] + chs[1][d] + chs[2][d] + chs[3][d]) * (1.0f / 1024.0f);
}

__global__ void fill_kernel(const float* __restrict__ vm, float* __restrict__ C)
{
  const size_t i = (size_t)blockIdx.x * 256 + threadIdx.x;
  const int d = (int)(i & 63);
  const int h = (int)((i >> 6) & (H_ - 1));
  const int b = (int)(i >> 20);
  C[i] = vm[(b * H_ + h) * DH_ + d];
}

__global__ void scatter_kernel(const float* __restrict__ ctx_rows,
                               const int* __restrict__ Mtop, float* __restrict__ C)
{
  const int bhu = blockIdx.x;
  const int u  = bhu % U_;
  const int bh = bhu / U_;
  const int h = bh & (H_ - 1), b = bh >> 4;
  const int row = Mtop[bh * U_ + u];
  C[(size_t)(b * L_ + row) * DM_ + h * DH_ + threadIdx.x] =
      ctx_rows[(size_t)bhu * DH_ + threadIdx.x];
}

// ---------------- LayerNorm(xa + xb) --------------------------------------
__global__ __launch_bounds__(256) void ln_kernel(
    const float* __restrict__ xa, const float* __restrict__ xb,
    const float* __restrict__ g, const float* __restrict__ bt,
    float* __restrict__ out)
{
  const int row = blockIdx.x;
  const int tid = threadIdx.x;
  __shared__ float v[DM_];
  __shared__ float red[256];
  float s = 0.f;
  for (int i = tid; i < DM_; i += 256) {
    const float t = xa[(size_t)row * DM_ + i] + xb[(size_t)row * DM_ + i];
    v[i] = t; s += t;
  }
  red[tid] = s; __syncthreads();
  for (int st = 128; st > 0; st >>= 1) { if (tid < st) red[tid] += red[tid+st]; __syncthreads(); }
  const float mean = red[0] * (1.0f / DM_);
  __syncthreads();
  float s2 = 0.f;
  for (int i = tid; i < DM_; i += 256) { const float dd = v[i] - mean; s2 += dd * dd; }
  red[tid] = s2; __syncthreads();
  for (int st = 128; st > 0; st >>= 1) { if (tid < st) red[tid] += red[tid+st]; __syncthreads(); }
  const float rstd = rsqrtf(red[0] * (1.0f / DM_) + 1e-5f);
  __syncthreads();
  for (int i = tid; i < DM_; i += 256)
    out[(size_t)row * DM_ + i] = (v[i] - mean) * rstd * g[i] + bt[i];
}

// ---------------- host orchestration --------------------------------------
extern "C" void kernel_launch(void* const* d_in, const int* in_sizes, int n_in,
                              void* d_out, int out_size, void* d_ws, size_t ws_size,
                              hipStream_t stream)
{
  (void)in_sizes; (void)n_in; (void)out_size; (void)ws_size;
  const float* x    = (const float*)d_in[0];
  const float* enc  = (const float*)d_in[1];
  const float* saWq = (const float*)d_in[2];  const float* sabq = (const float*)d_in[3];
  const float* saWk = (const float*)d_in[4];  const float* sabk = (const float*)d_in[5];
  const float* saWv = (const float*)d_in[6];  const float* sabv = (const float*)d_in[7];
  const float* saWo = (const float*)d_in[8];  const float* sabo = (const float*)d_in[9];
  const float* caWq = (const float*)d_in[10]; const float* cabq = (const float*)d_in[11];
  const float* caWk = (const float*)d_in[12]; const float* cabk = (const float*)d_in[13];
  const float* caWv = (const float*)d_in[14]; const float* cabv = (const float*)d_in[15];
  const float* caWo = (const float*)d_in[16]; const float* cabo = (const float*)d_in[17];
  const float* fW1  = (const float*)d_in[18]; const float* fb1  = (const float*)d_in[19];
  const float* fW2  = (const float*)d_in[20]; const float* fb2  = (const float*)d_in[21];
  const float* l1g  = (const float*)d_in[22]; const float* l1b  = (const float*)d_in[23];
  const float* l2g  = (const float*)d_in[24]; const float* l2b  = (const float*)d_in[25];
  const float* l3g  = (const float*)d_in[26]; const float* l3b  = (const float*)d_in[27];

  float* ws = (float*)d_ws;
  const size_t SL = (size_t)MROWS_ * DM_;      // 4M floats / 16 MB
  float* bufQ   = ws;
  float* bufK   = ws + SL;
  float* bufV   = ws + 2 * SL;
  float* bufC   = ws + 3 * SL;
  float* xcur   = ws + 4 * SL;
  float* tmp    = ws + 5 * SL;
  float* hidden = ws;                           // FFN stage reuses slots 0..3 (64 MB)
  float* smallp = ws + 6 * SL;
  int*   idxb = (int*)smallp;                                // 35840
  float* Mbuf = smallp + 36864;                              // 65536
  int*   Mtop = (int*)(smallp + 36864 + 65536);              // 2240 (pad to 2304)
  float* ctxr = smallp + 36864 + 65536 + 2304;               // 2240*64
  float* vm   = ctxr + 143360;                               // 1024

  // --- JAX partitionable-threefry key ladder (verified round 3) ---
  uint32_t k1a, k1b, k2a, k2b;
  tf2x32(0u, 42u, 0u, 0u, k1a, k1b);   // k1 = split(key)[0]
  tf2x32(0u, 42u, 0u, 1u, k2a, k2b);   // k2 = split(key)[1]
  uint32_t kb1a, kb1b, kb2a, kb2b;
  tf2x32(k1a, k1b, 0u, 1u, kb1a, kb1b);  // randint-internal split(k1)[1]
  tf2x32(k2a, k2b, 0u, 1u, kb2a, kb2b);  // randint-internal split(k2)[1]

  const dim3 thr(256);
  const int gIdx = (IDXN_ + 255) / 256;

  const dim3 gP1(DM_ / 128, MROWS_ / 128, 1);   // (8,32,1)
  const dim3 gP3(DM_ / 128, MROWS_ / 128, 3);   // (8,32,3)
  const dim3 gF1(FF_ / 128, MROWS_ / 128, 1);   // (32,32,1)

  // ---- self attention (masked) ----
  {
    Gemm3 g = {{x, x, x}, {saWq, saWk, saWv}, {sabq, sabk, sabv}, {bufQ, bufK, bufV}};
    gemm_mfma<3, false, false><<<gP3, thr, 0, stream>>>(g, DM_, DM_);
  }
  idx_kernel<<<gIdx, thr, 0, stream>>>(kb1a, kb1b, idxb);
  qks_m_kernel<<<(B_ * H_ * L_) / 4, thr, 0, stream>>>(bufQ, bufK, idxb, Mbuf);
  topk_kernel<<<B_ * H_, thr, 0, stream>>>(Mbuf, Mtop);
  attn_fused<<<B_ * H_, dim3(1024), 0, stream>>>(bufQ, bufK, bufV, Mtop, ctxr, 1);
  cumsum_kernel<<<B_ * H_, thr, 0, stream>>>(bufV, bufC);
  scatter_kernel<<<B_ * H_ * U_, dim3(64), 0, stream>>>(ctxr, Mtop, bufC);
  {
    Gemm3 g = {{bufC, nullptr, nullptr}, {saWo, nullptr, nullptr},
               {sabo, nullptr, nullptr}, {tmp, nullptr, nullptr}};
    gemm_mfma<2, false, true><<<gP1, thr, 0, stream>>>(g, DM_, DM_);
  }
  ln_kernel<<<MROWS_, thr, 0, stream>>>(x, tmp, l1g, l1b, xcur);

  // ---- cross attention (unmasked) ----
  {
    Gemm3 g = {{xcur, enc, enc}, {caWq, caWk, caWv}, {cabq, cabk, cabv}, {bufQ, bufK, bufV}};
    gemm_mfma<3, false, false><<<gP3, thr, 0, stream>>>(g, DM_, DM_);
  }
  idx_kernel<<<gIdx, thr, 0, stream>>>(kb2a, kb2b, idxb);
  qks_m_kernel<<<(B_ * H_ * L_) / 4, thr, 0, stream>>>(bufQ, bufK, idxb, Mbuf);
  topk_kernel<<<B_ * H_, thr, 0, stream>>>(Mbuf, Mtop);
  attn_fused<<<B_ * H_, dim3(1024), 0, stream>>>(bufQ, bufK, bufV, Mtop, ctxr, 0);
  vmean_kernel<<<B_ * H_, thr, 0, stream>>>(bufV, vm);
  fill_kernel<<<(int)(SL / 256), thr, 0, stream>>>(vm, bufC);
  scatter_kernel<<<B_ * H_ * U_, dim3(64), 0, stream>>>(ctxr, Mtop, bufC);
  {
    Gemm3 g = {{bufC, nullptr, nullptr}, {caWo, nullptr, nullptr},
               {cabo, nullptr, nullptr}, {tmp, nullptr, nullptr}};
    gemm_mfma<2, false, true><<<gP1, thr, 0, stream>>>(g, DM_, DM_);
  }
  ln_kernel<<<MROWS_, thr, 0, stream>>>(xcur, tmp, l2g, l2b, xcur);

  // ---- FFN ----
  {
    Gemm3 g = {{xcur, nullptr, nullptr}, {fW1, nullptr, nullptr},
               {fb1, nullptr, nullptr}, {hidden, nullptr, nullptr}};
    gemm_mfma<2, true, true><<<gF1, thr, 0, stream>>>(g, DM_, FF_);
  }
  {
    Gemm3 g = {{hidden, nullptr, nullptr}, {fW2, nullptr, nullptr},
               {fb2, nullptr, nullptr}, {tmp, nullptr, nullptr}};
    gemm_mfma<2, false, true><<<gP1, thr, 0, stream>>>(g, FF_, DM_);
  }
  ln_kernel<<<MROWS_, thr, 0, stream>>>(xcur, tmp, l3g, l3b, (float*)d_out);
}

// Round 8
// 2862.609 us; speedup vs baseline: 1.2221x; 1.1000x over previous
//
#include <hip/hip_runtime.h>
#include <cstdint>
#include <cstddef>

// Informer ProbSparse decoder layer. GEMMs via split-bf16 MFMA emulation.
// B=4 L=1024 Dm=1024 H=16 Dh=64 U=U_part=35 FF=4096.
#define B_     4
#define L_     1024
#define DM_    1024
#define H_     16
#define DH_    64
#define U_     35
#define FF_    4096
#define MROWS_ 4096          // B_*L_
#define IDXN_  35840         // L_*U_ random draws per attention

typedef __attribute__((ext_vector_type(8))) short bf16x8;
typedef __attribute__((ext_vector_type(4))) float f32x4;

// ---------------- Threefry-2x32-20 (exact JAX semantics) ----------------
__host__ __device__ inline void tf2x32(uint32_t k0, uint32_t k1,
                                       uint32_t x0, uint32_t x1,
                                       uint32_t& y0, uint32_t& y1) {
  const uint32_t ks2 = k0 ^ k1 ^ 0x1BD11BDAu;
  uint32_t v0 = x0 + k0, v1 = x1 + k1;
#define ROTL_(x,d) (((x)<<(d))|((x)>>(32-(d))))
#define RND_(r) { v0 += v1; v1 = ROTL_(v1,(r)); v1 ^= v0; }
  RND_(13) RND_(15) RND_(26) RND_(6)   v0 += k1;  v1 += ks2 + 1u;
  RND_(17) RND_(29) RND_(16) RND_(24)  v0 += ks2; v1 += k0  + 2u;
  RND_(13) RND_(15) RND_(26) RND_(6)   v0 += k0;  v1 += k1  + 3u;
  RND_(17) RND_(29) RND_(16) RND_(24)  v0 += k1;  v1 += ks2 + 4u;
  RND_(13) RND_(15) RND_(26) RND_(6)   v0 += ks2; v1 += k0  + 5u;
#undef RND_
#undef ROTL_
  y0 = v0; y1 = v1;
}

// JAX partitionable threefry random_bits, 32-bit: bits[i] = y0 ^ y1 (XOR fold).
__global__ void idx_kernel(uint32_t k0, uint32_t k1, int* __restrict__ idx) {
  const int i = blockIdx.x * 256 + threadIdx.x;
  if (i >= IDXN_) return;
  uint32_t y0, y1;
  tf2x32(k0, k1, 0u, (uint32_t)i, y0, y1);
  idx[i] = (int)((y0 ^ y1) & 1023u);
}

// ---------------- split-bf16 MFMA GEMM ------------------------------------
struct Gemm3 {
  const float* A[3];
  const float* B[3];
  const float* bias[3];
  float*       C[3];
};

__device__ __forceinline__ uint32_t f32bits(float x) {
  union { float f; uint32_t u; } c; c.f = x; return c.u;
}
__device__ __forceinline__ float bitsf32(uint32_t u) {
  union { uint32_t u; float f; } c; c.u = u; return c.f;
}
__device__ __forceinline__ uint32_t bf16rne(float x) {
  const uint32_t u = f32bits(x);
  return (u + 0x7FFFu + ((u >> 16) & 1u)) >> 16;
}

__device__ __forceinline__ void load_a16(const float* p, float (&v)[16]) {
  const float4* q = (const float4*)p;
  float4 x0 = q[0], x1 = q[1], x2 = q[2], x3 = q[3];
  v[0]=x0.x; v[1]=x0.y; v[2]=x0.z; v[3]=x0.w;
  v[4]=x1.x; v[5]=x1.y; v[6]=x1.z; v[7]=x1.w;
  v[8]=x2.x; v[9]=x2.y; v[10]=x2.z; v[11]=x2.w;
  v[12]=x3.x; v[13]=x3.y; v[14]=x3.z; v[15]=x3.w;
}
__device__ __forceinline__ void load_b16(const float* p, int N, float (&v)[16]) {
#pragma unroll
  for (int j = 0; j < 16; ++j) v[j] = p[(size_t)j * N];
}

template<int WAYS>
__device__ __forceinline__ void split_write(const float (&v)[16], int sr, int skh,
                                            uint32_t* H, uint32_t* Mi, uint32_t* L)
{
  uint32_t hp[8], lp[8], mp[8];
#pragma unroll
  for (int e = 0; e < 8; ++e) {
    const float a0 = v[2*e], a1 = v[2*e+1];
    const uint32_t h0 = f32bits(a0) & 0xFFFF0000u;
    const uint32_t h1 = f32bits(a1) & 0xFFFF0000u;
    hp[e] = (h0 >> 16) | h1;
    float r0 = a0 - bitsf32(h0);
    float r1 = a1 - bitsf32(h1);
    if (WAYS == 3) {
      const uint32_t m0 = f32bits(r0) & 0xFFFF0000u;
      const uint32_t m1 = f32bits(r1) & 0xFFFF0000u;
      mp[e] = (m0 >> 16) | m1;
      r0 -= bitsf32(m0); r1 -= bitsf32(m1);
    }
    lp[e] = bf16rne(r0) | (bf16rne(r1) << 16);
  }
  const int q  = (sr >> 1) & 3;
  const int b0 = sr * 64 + (((skh * 2 + 0) ^ q) << 4);
  const int b1 = sr * 64 + (((skh * 2 + 1) ^ q) << 4);
  *(uint4*)((char*)H + b0) = make_uint4(hp[0], hp[1], hp[2], hp[3]);
  *(uint4*)((char*)H + b1) = make_uint4(hp[4], hp[5], hp[6], hp[7]);
  if (WAYS == 3) {
    *(uint4*)((char*)Mi + b0) = make_uint4(mp[0], mp[1], mp[2], mp[3]);
    *(uint4*)((char*)Mi + b1) = make_uint4(mp[4], mp[5], mp[6], mp[7]);
  }
  *(uint4*)((char*)L + b0) = make_uint4(lp[0], lp[1], lp[2], lp[3]);
  *(uint4*)((char*)L + b1) = make_uint4(lp[4], lp[5], lp[6], lp[7]);
}

template<int WAYS, bool RELU, bool LOAD_EARLY>
__global__ __launch_bounds__(256, 2) void gemm_mfma(Gemm3 g, int K, int N)
{
  constexpr int NB = (WAYS == 3) ? 2048 : 4;
  __shared__ uint32_t AhL[2048], BhL[2048], AlL[2048], BlL[2048];
  __shared__ uint32_t AmL[NB], BmL[NB];

  const int z = blockIdx.z;
  const float* __restrict__ A    = g.A[z];
  const float* __restrict__ B    = g.B[z];
  const float* __restrict__ bias = g.bias[z];
  float* __restrict__       C    = g.C[z];
  const int bm = blockIdx.y * 128, bn = blockIdx.x * 128;

  const int t   = threadIdx.x;
  const int sr  = t >> 1, skh = t & 1;
  const int lane = t & 63, wid = t >> 6;
  const int wr = wid >> 1, wc = wid & 1;
  const int kg = lane >> 4, l15 = lane & 15;

  int aoff[4], boff[4];
#pragma unroll
  for (int m = 0; m < 4; ++m) {
    const int row = wr * 64 + m * 16 + l15;
    aoff[m] = row * 64 + ((kg ^ ((row >> 1) & 3)) << 4);
    const int col = wc * 64 + m * 16 + l15;
    boff[m] = col * 64 + ((kg ^ ((col >> 1) & 3)) << 4);
  }

  f32x4 acc[4][4];
#pragma unroll
  for (int m = 0; m < 4; ++m)
#pragma unroll
    for (int n = 0; n < 4; ++n) acc[m][n] = (f32x4){0.f, 0.f, 0.f, 0.f};

  float va[16], vb[16];
  load_a16(A + (size_t)(bm + sr) * K + skh * 16, va);
  load_b16(B + (size_t)(skh * 16) * N + bn + sr, N, vb);

  for (int kk = 0; kk < K; kk += 32) {
    __syncthreads();
    split_write<WAYS>(va, sr, skh, AhL, AmL, AlL);
    split_write<WAYS>(vb, sr, skh, BhL, BmL, BlL);
    __syncthreads();
    const bool more = (kk + 32 < K);
    if (LOAD_EARLY && more) {
      load_a16(A + (size_t)(bm + sr) * K + kk + 32 + skh * 16, va);
      load_b16(B + (size_t)(kk + 32 + skh * 16) * N + bn + sr, N, vb);
    }
    bf16x8 ah[4], al[4], bh[4], bl[4], am[4], bmf[4];
#pragma unroll
    for (int m = 0; m < 4; ++m) {
      ah[m] = *(const bf16x8*)((const char*)AhL + aoff[m]);
      al[m] = *(const bf16x8*)((const char*)AlL + aoff[m]);
      bh[m] = *(const bf16x8*)((const char*)BhL + boff[m]);
      bl[m] = *(const bf16x8*)((const char*)BlL + boff[m]);
      if (WAYS == 3) {
        am[m]  = *(const bf16x8*)((const char*)AmL + aoff[m]);
        bmf[m] = *(const bf16x8*)((const char*)BmL + boff[m]);
      }
    }
#pragma unroll
    for (int m = 0; m < 4; ++m)
#pragma unroll
      for (int n = 0; n < 4; ++n) {
        acc[m][n] = __builtin_amdgcn_mfma_f32_16x16x32_bf16(ah[m], bh[n], acc[m][n], 0, 0, 0);
        if (WAYS == 3) {
          acc[m][n] = __builtin_amdgcn_mfma_f32_16x16x32_bf16(ah[m], bmf[n], acc[m][n], 0, 0, 0);
          acc[m][n] = __builtin_amdgcn_mfma_f32_16x16x32_bf16(am[m], bh[n],  acc[m][n], 0, 0, 0);
          acc[m][n] = __builtin_amdgcn_mfma_f32_16x16x32_bf16(am[m], bmf[n], acc[m][n], 0, 0, 0);
        }
        acc[m][n] = __builtin_amdgcn_mfma_f32_16x16x32_bf16(ah[m], bl[n], acc[m][n], 0, 0, 0);
        acc[m][n] = __builtin_amdgcn_mfma_f32_16x16x32_bf16(al[m], bh[n], acc[m][n], 0, 0, 0);
      }
    if (!LOAD_EARLY && more) {
      load_a16(A + (size_t)(bm + sr) * K + kk + 32 + skh * 16, va);
      load_b16(B + (size_t)(kk + 32 + skh * 16) * N + bn + sr, N, vb);
    }
  }

#pragma unroll
  for (int m = 0; m < 4; ++m) {
    const int row0 = bm + wr * 64 + m * 16 + (lane >> 4) * 4;
#pragma unroll
    for (int n = 0; n < 4; ++n) {
      const int col = bn + wc * 64 + n * 16 + l15;
      const float bv = bias[col];
      const f32x4 a = acc[m][n];
#pragma unroll
      for (int q2 = 0; q2 < 4; ++q2) {
        float o = a[q2] + bv;
        if (RELU) o = fmaxf(o, 0.f);
        C[(size_t)(row0 + q2) * N + col] = o;
      }
    }
  }
}

// ---------------- sampled QK^T -> M scores --------------------------------
__global__ __launch_bounds__(256) void qks_m_kernel(
    const float* __restrict__ Q, const float* __restrict__ K,
    const int* __restrict__ idx, float* __restrict__ Mout)
{
  const int gw   = blockIdx.x * 4 + (threadIdx.x >> 6);
  const int lane = threadIdx.x & 63;
  const int l  = gw & (L_ - 1);
  const int bh = gw >> 10;
  const int h  = bh & (H_ - 1);
  const int b  = bh >> 4;
  const float q = Q[(size_t)(b * L_ + l) * DM_ + h * DH_ + lane];
  float mx = -__builtin_inff();
  float sm = 0.f;
  const int* ip = idx + l * U_;
  for (int s = 0; s < U_; ++s) {
    const int ks = ip[s];
    float p = q * K[(size_t)(b * L_ + ks) * DM_ + h * DH_ + lane];
#pragma unroll
    for (int off = 32; off > 0; off >>= 1) p += __shfl_xor(p, off, 64);
    mx = fmaxf(mx, p);
    sm += p;
  }
  if (lane == 0) Mout[gw] = mx - sm * (1.0f / 1024.0f);
}

// ---------------- top-35 indices per (b,h) --------------------------------
__global__ __launch_bounds__(256) void topk_kernel(
    const float* __restrict__ M, int* __restrict__ Mtop)
{
  const int bh  = blockIdx.x;
  const int tid = threadIdx.x;
  __shared__ float vals[L_];
  __shared__ float rv[256];
  __shared__ int   ri[256];
  for (int i = tid; i < L_; i += 256) vals[i] = M[(size_t)bh * L_ + i];
  __syncthreads();
  for (int t = 0; t < U_; ++t) {
    float best = -__builtin_inff();
    int   bi   = L_;
    for (int i = tid; i < L_; i += 256) {
      const float v = vals[i];
      if (v > best) { best = v; bi = i; }
    }
    rv[tid] = best; ri[tid] = bi;
    __syncthreads();
    for (int s = 128; s > 0; s >>= 1) {
      if (tid < s) {
        if (rv[tid+s] > rv[tid] || (rv[tid+s] == rv[tid] && ri[tid+s] < ri[tid])) {
          rv[tid] = rv[tid+s]; ri[tid] = ri[tid+s];
        }
      }
      __syncthreads();
    }
    if (tid == 0) { Mtop[bh * U_ + t] = ri[0]; vals[ri[0]] = -__builtin_inff(); }
    __syncthreads();
  }
}

// ---------------- fused attention: one block per (b,h) --------------------
// 1024 threads = 16 waves, thread t owns k-row t. Round-7 post-mortem: the
// allocator targets 64 VGPR (LDS allows 2 blocks/CU -> 8 waves/EU heuristic),
// so s[35] spilled (555 MB scratch). Fix: process u in 3 GROUPS of <=12 —
// per group: scores -> max -> exp -> sum -> pack exp'd bf16 pairs into pk[18]
// registers; group's f32 scores then die. Peak live ~52 VGPR -> fits 64.
__global__ __launch_bounds__(1024, 4) void attn_fused(
    const float* __restrict__ Q, const float* __restrict__ K,
    const float* __restrict__ V, const int* __restrict__ Mtop,
    float* __restrict__ ctx_rows, int masked)
{
  __shared__ float    qs[U_ * DH_];     // 8960 B
  __shared__ uint32_t Pl[512 * 18];     // 36864 B
  __shared__ float    wredA[12 * 16];   // 768 B  (per-group max partials)
  __shared__ float    wredB[12 * 16];   // 768 B  (per-group sum partials)
  __shared__ float    wredTot[U_ + 1];  // final per-u softmax denominators
  __shared__ int      rowsL[U_ + 1];

  const int bh   = blockIdx.x;
  const int h    = bh & (H_ - 1), b = bh >> 4;
  const int tid  = threadIdx.x;
  const int lane = tid & 63, wid = tid >> 6;
  const size_t kvbase = (size_t)(b * L_) * DM_ + h * DH_;

  if (tid < U_) rowsL[tid] = Mtop[bh * U_ + tid];
  __syncthreads();
  for (int i = tid; i < U_ * DH_; i += 1024)
    qs[i] = Q[kvbase + (size_t)rowsL[i >> 6] * DM_ + (i & 63)];
  __syncthreads();

  const int k = tid;
  const float* kp = K + kvbase + (size_t)k * DM_;
  uint32_t pk[18];

#pragma unroll
  for (int g = 0; g < 3; ++g) {
    const int ubase = 12 * g;
    const int ucnt  = (g == 2) ? 11 : 12;
    float s[12];
#pragma unroll
    for (int ug = 0; ug < 12; ++ug) s[ug] = 0.f;

#pragma unroll
    for (int dc = 0; dc < 64; dc += 16) {
      const float4 k0 = *(const float4*)(kp + dc);
      const float4 k1 = *(const float4*)(kp + dc + 4);
      const float4 k2 = *(const float4*)(kp + dc + 8);
      const float4 k3 = *(const float4*)(kp + dc + 12);
#pragma unroll
      for (int ug = 0; ug < 12; ++ug) {
        if (ug >= ucnt) break;
        const float4* qp = (const float4*)&qs[(ubase + ug) * 64 + dc];
        const float4 q0 = qp[0], q1 = qp[1], q2 = qp[2], q3 = qp[3];
        float acc = s[ug];
        acc = fmaf(q0.x, k0.x, acc); acc = fmaf(q0.y, k0.y, acc);
        acc = fmaf(q0.z, k0.z, acc); acc = fmaf(q0.w, k0.w, acc);
        acc = fmaf(q1.x, k1.x, acc); acc = fmaf(q1.y, k1.y, acc);
        acc = fmaf(q1.z, k1.z, acc); acc = fmaf(q1.w, k1.w, acc);
        acc = fmaf(q2.x, k2.x, acc); acc = fmaf(q2.y, k2.y, acc);
        acc = fmaf(q2.z, k2.z, acc); acc = fmaf(q2.w, k2.w, acc);
        acc = fmaf(q3.x, k3.x, acc); acc = fmaf(q3.y, k3.y, acc);
        acc = fmaf(q3.z, k3.z, acc); acc = fmaf(q3.w, k3.w, acc);
        s[ug] = acc;
      }
    }

#pragma unroll
    for (int ug = 0; ug < 12; ++ug) {
      if (ug >= ucnt) break;
      float v = s[ug] * 0.125f;                    // 1/sqrt(64)
      if (masked && k > rowsL[ubase + ug]) v = -__builtin_inff();
      s[ug] = v;
    }

    // max: wave shuffle -> partials -> finalize by ucnt threads
#pragma unroll
    for (int ug = 0; ug < 12; ++ug) {
      if (ug >= ucnt) break;
      float m = s[ug];
#pragma unroll
      for (int off = 32; off > 0; off >>= 1) m = fmaxf(m, __shfl_xor(m, off, 64));
      if (lane == 0) wredA[ug * 16 + wid] = m;
    }
    __syncthreads();
    if (tid < ucnt) {
      float m = wredA[tid * 16];
#pragma unroll
      for (int w2 = 1; w2 < 16; ++w2) m = fmaxf(m, wredA[tid * 16 + w2]);
      wredA[tid * 16] = m;
    }
    __syncthreads();
#pragma unroll
    for (int ug = 0; ug < 12; ++ug) {
      if (ug >= ucnt) break;
      s[ug] = expf(s[ug] - wredA[ug * 16]);        // exp(-inf)=0 handles mask
    }

    // sum: same pattern, finalize into wredTot
#pragma unroll
    for (int ug = 0; ug < 12; ++ug) {
      if (ug >= ucnt) break;
      float m = s[ug];
#pragma unroll
      for (int off = 32; off > 0; off >>= 1) m += __shfl_xor(m, off, 64);
      if (lane == 0) wredB[ug * 16 + wid] = m;
    }
    __syncthreads();
    if (tid < ucnt) {
      float t = wredB[tid * 16];
#pragma unroll
      for (int w2 = 1; w2 < 16; ++w2) t += wredB[tid * 16 + w2];
      wredTot[ubase + tid] = t;
    }

    // pack exp'd (unnormalized) values to bf16 pairs in registers
    if (g < 2) {
#pragma unroll
      for (int j = 0; j < 6; ++j)
        pk[6 * g + j] = bf16rne(s[2 * j]) | (bf16rne(s[2 * j + 1]) << 16);
    } else {
#pragma unroll
      for (int j = 0; j < 5; ++j)
        pk[12 + j] = bf16rne(s[2 * j]) | (bf16rne(s[2 * j + 1]) << 16);
      pk[17] = bf16rne(s[10]);
    }
  }

  // ---- PV in two k-halves through LDS (unnormalized bf16 P) ----
  float a0 = 0.f, a1 = 0.f, a2 = 0.f;
  const int u0 = 2 * wid, u1 = 2 * wid + 1;        // u2 = 32+wid for wid<3
  const float* vp = V + kvbase + lane;
  const int kr = k & 511;
#pragma unroll
  for (int half = 0; half < 2; ++half) {
    __syncthreads();
    if ((k >> 9) == half) {
#pragma unroll
      for (int j = 0; j < 18; ++j) Pl[kr * 18 + j] = pk[j];
    }
    __syncthreads();
    const size_t vbase = (size_t)half * 512 * DM_;
    for (int kk = 0; kk < 512; kk += 2) {
      const float v0 = vp[vbase + (size_t)kk * DM_];
      const float v1 = vp[vbase + (size_t)(kk + 1) * DM_];
      const uint32_t p0 = Pl[kk * 18 + wid];
      const uint32_t p1 = Pl[(kk + 1) * 18 + wid];
      a0 = fmaf(bitsf32(p0 << 16), v0, a0);
      a1 = fmaf(bitsf32(p0 & 0xFFFF0000u), v0, a1);
      a0 = fmaf(bitsf32(p1 << 16), v1, a0);
      a1 = fmaf(bitsf32(p1 & 0xFFFF0000u), v1, a1);
      if (wid == 0) {
        a2 = fmaf(bitsf32(Pl[kk * 18 + 16] << 16), v0, a2);
        a2 = fmaf(bitsf32(Pl[(kk+1) * 18 + 16] << 16), v1, a2);
      } else if (wid == 1) {
        a2 = fmaf(bitsf32(Pl[kk * 18 + 16] & 0xFFFF0000u), v0, a2);
        a2 = fmaf(bitsf32(Pl[(kk+1) * 18 + 16] & 0xFFFF0000u), v1, a2);
      } else if (wid == 2) {
        a2 = fmaf(bitsf32(Pl[kk * 18 + 17] << 16), v0, a2);
        a2 = fmaf(bitsf32(Pl[(kk+1) * 18 + 17] << 16), v1, a2);
      }
    }
  }
  ctx_rows[(size_t)(bh * U_ + u0) * DH_ + lane] = a0 / wredTot[u0];
  ctx_rows[(size_t)(bh * U_ + u1) * DH_ + lane] = a1 / wredTot[u1];
  if (wid < 3)
    ctx_rows[(size_t)(bh * U_ + 32 + wid) * DH_ + lane] = a2 / wredTot[32 + wid];
}

// ---------------- cumsum(V) over L per (b,h,d) ----------------------------
__global__ __launch_bounds__(256) void cumsum_kernel(
    const float* __restrict__ V, float* __restrict__ C)
{
  const int bh = blockIdx.x;
  const int h = bh & (H_ - 1), b = bh >> 4;
  const int d = threadIdx.x & 63, qq = threadIdx.x >> 6;
  __shared__ float chs[4][DH_];
  const size_t base = (size_t)b * L_ * DM_ + h * DH_ + d;
  float acc = 0.f;
  const int l0 = qq * 256;
  for (int l = l0; l < l0 + 256; ++l) acc += V[base + (size_t)l * DM_];
  chs[qq][d] = acc;
  __syncthreads();
  float off = 0.f;
  for (int j = 0; j < qq; ++j) off += chs[j][d];
  acc = off;
  for (int l = l0; l < l0 + 256; ++l) {
    acc += V[base + (size_t)l * DM_];
    C[base + (size_t)l * DM_] = acc;
  }
}

__global__ __launch_bounds__(256) void vmean_kernel(
    const float* __restrict__ V, float* __restrict__ vm)
{
  const int bh = blockIdx.x;
  const int h = bh & (H_ - 1), b = bh >> 4;
  const int d = threadIdx.x & 63, qq = threadIdx.x >> 6;
  __shared__ float chs[4][DH_];
  const size_t base = (size_t)b * L_ * DM_ + h * DH_ + d;
  float acc = 0.f;
  for (int l = qq * 256; l < qq * 256 + 256; ++l) acc += V[base + (size_t)l * DM_];
  chs[qq][d] = acc;
  __syncthreads();
  if (qq == 0)
    vm[bh * DH_ + d] = (chs[0][d] + chs[1][d] + chs[2][d] + chs[3][d]) * (1.0f / 1024.0f);
}

__global__ void fill_kernel(const float* __restrict__ vm, float* __restrict__ C)
{
  const size_t i = (size_t)blockIdx.x * 256 + threadIdx.x;
  const int d = (int)(i & 63);
  const int h = (int)((i >> 6) & (H_ - 1));
  const int b = (int)(i >> 20);
  C[i] = vm[(b * H_ + h) * DH_ + d];
}

__global__ void scatter_kernel(const float* __restrict__ ctx_rows,
                               const int* __restrict__ Mtop, float* __restrict__ C)
{
  const int bhu = blockIdx.x;
  const int u  = bhu % U_;
  const int bh = bhu / U_;
  const int h = bh & (H_ - 1), b = bh >> 4;
  const int row = Mtop[bh * U_ + u];
  C[(size_t)(b * L_ + row) * DM_ + h * DH_ + threadIdx.x] =
      ctx_rows[(size_t)bhu * DH_ + threadIdx.x];
}

// ---------------- LayerNorm(xa + xb) --------------------------------------
__global__ __launch_bounds__(256) void ln_kernel(
    const float* __restrict__ xa, const float* __restrict__ xb,
    const float* __restrict__ g, const float* __restrict__ bt,
    float* __restrict__ out)
{
  const int row = blockIdx.x;
  const int tid = threadIdx.x;
  __shared__ float v[DM_];
  __shared__ float red[256];
  float s = 0.f;
  for (int i = tid; i < DM_; i += 256) {
    const float t = xa[(size_t)row * DM_ + i] + xb[(size_t)row * DM_ + i];
    v[i] = t; s += t;
  }
  red[tid] = s; __syncthreads();
  for (int st = 128; st > 0; st >>= 1) { if (tid < st) red[tid] += red[tid+st]; __syncthreads(); }
  const float mean = red[0] * (1.0f / DM_);
  __syncthreads();
  float s2 = 0.f;
  for (int i = tid; i < DM_; i += 256) { const float dd = v[i] - mean; s2 += dd * dd; }
  red[tid] = s2; __syncthreads();
  for (int st = 128; st > 0; st >>= 1) { if (tid < st) red[tid] += red[tid+st]; __syncthreads(); }
  const float rstd = rsqrtf(red[0] * (1.0f / DM_) + 1e-5f);
  __syncthreads();
  for (int i = tid; i < DM_; i += 256)
    out[(size_t)row * DM_ + i] = (v[i] - mean) * rstd * g[i] + bt[i];
}

// ---------------- host orchestration --------------------------------------
extern "C" void kernel_launch(void* const* d_in, const int* in_sizes, int n_in,
                              void* d_out, int out_size, void* d_ws, size_t ws_size,
                              hipStream_t stream)
{
  (void)in_sizes; (void)n_in; (void)out_size; (void)ws_size;
  const float* x    = (const float*)d_in[0];
  const float* enc  = (const float*)d_in[1];
  const float* saWq = (const float*)d_in[2];  const float* sabq = (const float*)d_in[3];
  const float* saWk = (const float*)d_in[4];  const float* sabk = (const float*)d_in[5];
  const float* saWv = (const float*)d_in[6];  const float* sabv = (const float*)d_in[7];
  const float* saWo = (const float*)d_in[8];  const float* sabo = (const float*)d_in[9];
  const float* caWq = (const float*)d_in[10]; const float* cabq = (const float*)d_in[11];
  const float* caWk = (const float*)d_in[12]; const float* cabk = (const float*)d_in[13];
  const float* caWv = (const float*)d_in[14]; const float* cabv = (const float*)d_in[15];
  const float* caWo = (const float*)d_in[16]; const float* cabo = (const float*)d_in[17];
  const float* fW1  = (const float*)d_in[18]; const float* fb1  = (const float*)d_in[19];
  const float* fW2  = (const float*)d_in[20]; const float* fb2  = (const float*)d_in[21];
  const float* l1g  = (const float*)d_in[22]; const float* l1b  = (const float*)d_in[23];
  const float* l2g  = (const float*)d_in[24]; const float* l2b  = (const float*)d_in[25];
  const float* l3g  = (const float*)d_in[26]; const float* l3b  = (const float*)d_in[27];

  float* ws = (float*)d_ws;
  const size_t SL = (size_t)MROWS_ * DM_;      // 4M floats / 16 MB
  float* bufQ   = ws;
  float* bufK   = ws + SL;
  float* bufV   = ws + 2 * SL;
  float* bufC   = ws + 3 * SL;
  float* xcur   = ws + 4 * SL;
  float* tmp    = ws + 5 * SL;
  float* hidden = ws;                           // FFN stage reuses slots 0..3 (64 MB)
  float* smallp = ws + 6 * SL;
  int*   idxb = (int*)smallp;                                // 35840
  float* Mbuf = smallp + 36864;                              // 65536
  int*   Mtop = (int*)(smallp + 36864 + 65536);              // 2240 (pad to 2304)
  float* ctxr = smallp + 36864 + 65536 + 2304;               // 2240*64
  float* vm   = ctxr + 143360;                               // 1024

  // --- JAX partitionable-threefry key ladder (verified round 3) ---
  uint32_t k1a, k1b, k2a, k2b;
  tf2x32(0u, 42u, 0u, 0u, k1a, k1b);   // k1 = split(key)[0]
  tf2x32(0u, 42u, 0u, 1u, k2a, k2b);   // k2 = split(key)[1]
  uint32_t kb1a, kb1b, kb2a, kb2b;
  tf2x32(k1a, k1b, 0u, 1u, kb1a, kb1b);  // randint-internal split(k1)[1]
  tf2x32(k2a, k2b, 0u, 1u, kb2a, kb2b);  // randint-internal split(k2)[1]

  const dim3 thr(256);
  const int gIdx = (IDXN_ + 255) / 256;

  const dim3 gP1(DM_ / 128, MROWS_ / 128, 1);   // (8,32,1)
  const dim3 gP3(DM_ / 128, MROWS_ / 128, 3);   // (8,32,3)
  const dim3 gF1(FF_ / 128, MROWS_ / 128, 1);   // (32,32,1)

  // ---- self attention (masked) ----
  {
    Gemm3 g = {{x, x, x}, {saWq, saWk, saWv}, {sabq, sabk, sabv}, {bufQ, bufK, bufV}};
    gemm_mfma<3, false, false><<<gP3, thr, 0, stream>>>(g, DM_, DM_);
  }
  idx_kernel<<<gIdx, thr, 0, stream>>>(kb1a, kb1b, idxb);
  qks_m_kernel<<<(B_ * H_ * L_) / 4, thr, 0, stream>>>(bufQ, bufK, idxb, Mbuf);
  topk_kernel<<<B_ * H_, thr, 0, stream>>>(Mbuf, Mtop);
  attn_fused<<<B_ * H_, dim3(1024), 0, stream>>>(bufQ, bufK, bufV, Mtop, ctxr, 1);
  cumsum_kernel<<<B_ * H_, thr, 0, stream>>>(bufV, bufC);
  scatter_kernel<<<B_ * H_ * U_, dim3(64), 0, stream>>>(ctxr, Mtop, bufC);
  {
    Gemm3 g = {{bufC, nullptr, nullptr}, {saWo, nullptr, nullptr},
               {sabo, nullptr, nullptr}, {tmp, nullptr, nullptr}};
    gemm_mfma<2, false, true><<<gP1, thr, 0, stream>>>(g, DM_, DM_);
  }
  ln_kernel<<<MROWS_, thr, 0, stream>>>(x, tmp, l1g, l1b, xcur);

  // ---- cross attention (unmasked) ----
  {
    Gemm3 g = {{xcur, enc, enc}, {caWq, caWk, caWv}, {cabq, cabk, cabv}, {bufQ, bufK, bufV}};
    gemm_mfma<3, false, false><<<gP3, thr, 0, stream>>>(g, DM_, DM_);
  }
  idx_kernel<<<gIdx, thr, 0, stream>>>(kb2a, kb2b, idxb);
  qks_m_kernel<<<(B_ * H_ * L_) / 4, thr, 0, stream>>>(bufQ, bufK, idxb, Mbuf);
  topk_kernel<<<B_ * H_, thr, 0, stream>>>(Mbuf, Mtop);
  attn_fused<<<B_ * H_, dim3(1024), 0, stream>>>(bufQ, bufK, bufV, Mtop, ctxr, 0);
  vmean_kernel<<<B_ * H_, thr, 0, stream>>>(bufV, vm);
  fill_kernel<<<(int)(SL / 256), thr, 0, stream>>>(vm, bufC);
  scatter_kernel<<<B_ * H_ * U_, dim3(64), 0, stream>>>(ctxr, Mtop, bufC);
  {
    Gemm3 g = {{bufC, nullptr, nullptr}, {caWo, nullptr, nullptr},
               {cabo, nullptr, nullptr}, {tmp, nullptr, nullptr}};
    gemm_mfma<2, false, true><<<gP1, thr, 0, stream>>>(g, DM_, DM_);
  }
  ln_kernel<<<MROWS_, thr, 0, stream>>>(xcur, tmp, l2g, l2b, xcur);

  // ---- FFN ----
  {
    Gemm3 g = {{xcur, nullptr, nullptr}, {fW1, nullptr, nullptr},
               {fb1, nullptr, nullptr}, {hidden, nullptr, nullptr}};
    gemm_mfma<2, true, true><<<gF1, thr, 0, stream>>>(g, DM_, FF_);
  }
  {
    Gemm3 g = {{hidden, nullptr, nullptr}, {fW2, nullptr, nullptr},
               {fb2, nullptr, nullptr}, {tmp, nullptr, nullptr}};
    gemm_mfma<2, false, true><<<gP1, thr, 0, stream>>>(g, FF_, DM_);
  }
  ln_kernel<<<MROWS_, thr, 0, stream>>>(xcur, tmp, l3g, l3b, (float*)d_out);
}

// Round 9
// 1622.835 us; speedup vs baseline: 2.1558x; 1.7640x over previous
//
#include <hip/hip_runtime.h>
#include <cstdint>
#include <cstddef>

// Informer ProbSparse decoder layer. GEMMs via split-bf16 MFMA emulation.
// B=4 L=1024 Dm=1024 H=16 Dh=64 U=U_part=35 FF=4096.
#define B_     4
#define L_     1024
#define DM_    1024
#define H_     16
#define DH_    64
#define U_     35
#define FF_    4096
#define MROWS_ 4096          // B_*L_
#define IDXN_  35840         // L_*U_ random draws per attention

typedef __attribute__((ext_vector_type(8))) short bf16x8;
typedef __attribute__((ext_vector_type(4))) float f32x4;

// ---------------- Threefry-2x32-20 (exact JAX semantics) ----------------
__host__ __device__ inline void tf2x32(uint32_t k0, uint32_t k1,
                                       uint32_t x0, uint32_t x1,
                                       uint32_t& y0, uint32_t& y1) {
  const uint32_t ks2 = k0 ^ k1 ^ 0x1BD11BDAu;
  uint32_t v0 = x0 + k0, v1 = x1 + k1;
#define ROTL_(x,d) (((x)<<(d))|((x)>>(32-(d))))
#define RND_(r) { v0 += v1; v1 = ROTL_(v1,(r)); v1 ^= v0; }
  RND_(13) RND_(15) RND_(26) RND_(6)   v0 += k1;  v1 += ks2 + 1u;
  RND_(17) RND_(29) RND_(16) RND_(24)  v0 += ks2; v1 += k0  + 2u;
  RND_(13) RND_(15) RND_(26) RND_(6)   v0 += k0;  v1 += k1  + 3u;
  RND_(17) RND_(29) RND_(16) RND_(24)  v0 += k1;  v1 += ks2 + 4u;
  RND_(13) RND_(15) RND_(26) RND_(6)   v0 += ks2; v1 += k0  + 5u;
#undef RND_
#undef ROTL_
  y0 = v0; y1 = v1;
}

// JAX partitionable threefry random_bits, 32-bit: bits[i] = y0 ^ y1 (XOR fold).
__global__ void idx_kernel(uint32_t k0, uint32_t k1, int* __restrict__ idx) {
  const int i = blockIdx.x * 256 + threadIdx.x;
  if (i >= IDXN_) return;
  uint32_t y0, y1;
  tf2x32(k0, k1, 0u, (uint32_t)i, y0, y1);
  idx[i] = (int)((y0 ^ y1) & 1023u);
}

// ---------------- split-bf16 MFMA GEMM ------------------------------------
struct Gemm3 {
  const float* A[3];
  const float* B[3];
  const float* bias[3];
  float*       C[3];
};

__device__ __forceinline__ uint32_t f32bits(float x) {
  union { float f; uint32_t u; } c; c.f = x; return c.u;
}
__device__ __forceinline__ float bitsf32(uint32_t u) {
  union { uint32_t u; float f; } c; c.u = u; return c.f;
}
__device__ __forceinline__ uint32_t bf16rne(float x) {
  const uint32_t u = f32bits(x);
  return (u + 0x7FFFu + ((u >> 16) & 1u)) >> 16;
}

__device__ __forceinline__ void load_a16(const float* p, float (&v)[16]) {
  const float4* q = (const float4*)p;
  float4 x0 = q[0], x1 = q[1], x2 = q[2], x3 = q[3];
  v[0]=x0.x; v[1]=x0.y; v[2]=x0.z; v[3]=x0.w;
  v[4]=x1.x; v[5]=x1.y; v[6]=x1.z; v[7]=x1.w;
  v[8]=x2.x; v[9]=x2.y; v[10]=x2.z; v[11]=x2.w;
  v[12]=x3.x; v[13]=x3.y; v[14]=x3.z; v[15]=x3.w;
}
__device__ __forceinline__ void load_b16(const float* p, int N, float (&v)[16]) {
#pragma unroll
  for (int j = 0; j < 16; ++j) v[j] = p[(size_t)j * N];
}

template<int WAYS>
__device__ __forceinline__ void split_write(const float (&v)[16], int sr, int skh,
                                            uint32_t* H, uint32_t* Mi, uint32_t* L)
{
  uint32_t hp[8], lp[8], mp[8];
#pragma unroll
  for (int e = 0; e < 8; ++e) {
    const float a0 = v[2*e], a1 = v[2*e+1];
    const uint32_t h0 = f32bits(a0) & 0xFFFF0000u;
    const uint32_t h1 = f32bits(a1) & 0xFFFF0000u;
    hp[e] = (h0 >> 16) | h1;
    float r0 = a0 - bitsf32(h0);
    float r1 = a1 - bitsf32(h1);
    if (WAYS == 3) {
      const uint32_t m0 = f32bits(r0) & 0xFFFF0000u;
      const uint32_t m1 = f32bits(r1) & 0xFFFF0000u;
      mp[e] = (m0 >> 16) | m1;
      r0 -= bitsf32(m0); r1 -= bitsf32(m1);
    }
    lp[e] = bf16rne(r0) | (bf16rne(r1) << 16);
  }
  const int q  = (sr >> 1) & 3;
  const int b0 = sr * 64 + (((skh * 2 + 0) ^ q) << 4);
  const int b1 = sr * 64 + (((skh * 2 + 1) ^ q) << 4);
  *(uint4*)((char*)H + b0) = make_uint4(hp[0], hp[1], hp[2], hp[3]);
  *(uint4*)((char*)H + b1) = make_uint4(hp[4], hp[5], hp[6], hp[7]);
  if (WAYS == 3) {
    *(uint4*)((char*)Mi + b0) = make_uint4(mp[0], mp[1], mp[2], mp[3]);
    *(uint4*)((char*)Mi + b1) = make_uint4(mp[4], mp[5], mp[6], mp[7]);
  }
  *(uint4*)((char*)L + b0) = make_uint4(lp[0], lp[1], lp[2], lp[3]);
  *(uint4*)((char*)L + b1) = make_uint4(lp[4], lp[5], lp[6], lp[7]);
}

template<int WAYS, bool RELU, bool LOAD_EARLY>
__global__ __launch_bounds__(256, 2) void gemm_mfma(Gemm3 g, int K, int N)
{
  constexpr int NB = (WAYS == 3) ? 2048 : 4;
  __shared__ uint32_t AhL[2048], BhL[2048], AlL[2048], BlL[2048];
  __shared__ uint32_t AmL[NB], BmL[NB];

  const int z = blockIdx.z;
  const float* __restrict__ A    = g.A[z];
  const float* __restrict__ B    = g.B[z];
  const float* __restrict__ bias = g.bias[z];
  float* __restrict__       C    = g.C[z];
  const int bm = blockIdx.y * 128, bn = blockIdx.x * 128;

  const int t   = threadIdx.x;
  const int sr  = t >> 1, skh = t & 1;
  const int lane = t & 63, wid = t >> 6;
  const int wr = wid >> 1, wc = wid & 1;
  const int kg = lane >> 4, l15 = lane & 15;

  int aoff[4], boff[4];
#pragma unroll
  for (int m = 0; m < 4; ++m) {
    const int row = wr * 64 + m * 16 + l15;
    aoff[m] = row * 64 + ((kg ^ ((row >> 1) & 3)) << 4);
    const int col = wc * 64 + m * 16 + l15;
    boff[m] = col * 64 + ((kg ^ ((col >> 1) & 3)) << 4);
  }

  f32x4 acc[4][4];
#pragma unroll
  for (int m = 0; m < 4; ++m)
#pragma unroll
    for (int n = 0; n < 4; ++n) acc[m][n] = (f32x4){0.f, 0.f, 0.f, 0.f};

  float va[16], vb[16];
  load_a16(A + (size_t)(bm + sr) * K + skh * 16, va);
  load_b16(B + (size_t)(skh * 16) * N + bn + sr, N, vb);

  for (int kk = 0; kk < K; kk += 32) {
    __syncthreads();
    split_write<WAYS>(va, sr, skh, AhL, AmL, AlL);
    split_write<WAYS>(vb, sr, skh, BhL, BmL, BlL);
    __syncthreads();
    const bool more = (kk + 32 < K);
    if (LOAD_EARLY && more) {
      load_a16(A + (size_t)(bm + sr) * K + kk + 32 + skh * 16, va);
      load_b16(B + (size_t)(kk + 32 + skh * 16) * N + bn + sr, N, vb);
    }
    bf16x8 ah[4], al[4], bh[4], bl[4], am[4], bmf[4];
#pragma unroll
    for (int m = 0; m < 4; ++m) {
      ah[m] = *(const bf16x8*)((const char*)AhL + aoff[m]);
      al[m] = *(const bf16x8*)((const char*)AlL + aoff[m]);
      bh[m] = *(const bf16x8*)((const char*)BhL + boff[m]);
      bl[m] = *(const bf16x8*)((const char*)BlL + boff[m]);
      if (WAYS == 3) {
        am[m]  = *(const bf16x8*)((const char*)AmL + aoff[m]);
        bmf[m] = *(const bf16x8*)((const char*)BmL + boff[m]);
      }
    }
#pragma unroll
    for (int m = 0; m < 4; ++m)
#pragma unroll
      for (int n = 0; n < 4; ++n) {
        acc[m][n] = __builtin_amdgcn_mfma_f32_16x16x32_bf16(ah[m], bh[n], acc[m][n], 0, 0, 0);
        if (WAYS == 3) {
          acc[m][n] = __builtin_amdgcn_mfma_f32_16x16x32_bf16(ah[m], bmf[n], acc[m][n], 0, 0, 0);
          acc[m][n] = __builtin_amdgcn_mfma_f32_16x16x32_bf16(am[m], bh[n],  acc[m][n], 0, 0, 0);
          acc[m][n] = __builtin_amdgcn_mfma_f32_16x16x32_bf16(am[m], bmf[n], acc[m][n], 0, 0, 0);
        }
        acc[m][n] = __builtin_amdgcn_mfma_f32_16x16x32_bf16(ah[m], bl[n], acc[m][n], 0, 0, 0);
        acc[m][n] = __builtin_amdgcn_mfma_f32_16x16x32_bf16(al[m], bh[n], acc[m][n], 0, 0, 0);
      }
    if (!LOAD_EARLY && more) {
      load_a16(A + (size_t)(bm + sr) * K + kk + 32 + skh * 16, va);
      load_b16(B + (size_t)(kk + 32 + skh * 16) * N + bn + sr, N, vb);
    }
  }

#pragma unroll
  for (int m = 0; m < 4; ++m) {
    const int row0 = bm + wr * 64 + m * 16 + (lane >> 4) * 4;
#pragma unroll
    for (int n = 0; n < 4; ++n) {
      const int col = bn + wc * 64 + n * 16 + l15;
      const float bv = bias[col];
      const f32x4 a = acc[m][n];
#pragma unroll
      for (int q2 = 0; q2 < 4; ++q2) {
        float o = a[q2] + bv;
        if (RELU) o = fmaxf(o, 0.f);
        C[(size_t)(row0 + q2) * N + col] = o;
      }
    }
  }
}

// ---------------- sampled QK^T -> M scores --------------------------------
__global__ __launch_bounds__(256) void qks_m_kernel(
    const float* __restrict__ Q, const float* __restrict__ K,
    const int* __restrict__ idx, float* __restrict__ Mout)
{
  const int gw   = blockIdx.x * 4 + (threadIdx.x >> 6);
  const int lane = threadIdx.x & 63;
  const int l  = gw & (L_ - 1);
  const int bh = gw >> 10;
  const int h  = bh & (H_ - 1);
  const int b  = bh >> 4;
  const float q = Q[(size_t)(b * L_ + l) * DM_ + h * DH_ + lane];
  float mx = -__builtin_inff();
  float sm = 0.f;
  const int* ip = idx + l * U_;
  for (int s = 0; s < U_; ++s) {
    const int ks = ip[s];
    float p = q * K[(size_t)(b * L_ + ks) * DM_ + h * DH_ + lane];
#pragma unroll
    for (int off = 32; off > 0; off >>= 1) p += __shfl_xor(p, off, 64);
    mx = fmaxf(mx, p);
    sm += p;
  }
  if (lane == 0) Mout[gw] = mx - sm * (1.0f / 1024.0f);
}

// ---------------- top-35 indices per (b,h) --------------------------------
__global__ __launch_bounds__(256) void topk_kernel(
    const float* __restrict__ M, int* __restrict__ Mtop)
{
  const int bh  = blockIdx.x;
  const int tid = threadIdx.x;
  __shared__ float vals[L_];
  __shared__ float rv[256];
  __shared__ int   ri[256];
  for (int i = tid; i < L_; i += 256) vals[i] = M[(size_t)bh * L_ + i];
  __syncthreads();
  for (int t = 0; t < U_; ++t) {
    float best = -__builtin_inff();
    int   bi   = L_;
    for (int i = tid; i < L_; i += 256) {
      const float v = vals[i];
      if (v > best) { best = v; bi = i; }
    }
    rv[tid] = best; ri[tid] = bi;
    __syncthreads();
    for (int s = 128; s > 0; s >>= 1) {
      if (tid < s) {
        if (rv[tid+s] > rv[tid] || (rv[tid+s] == rv[tid] && ri[tid+s] < ri[tid])) {
          rv[tid] = rv[tid+s]; ri[tid] = ri[tid+s];
        }
      }
      __syncthreads();
    }
    if (tid == 0) { Mtop[bh * U_ + t] = ri[0]; vals[ri[0]] = -__builtin_inff(); }
    __syncthreads();
  }
}

// ---------------- fused attention: one block per (b,h) --------------------
// 1024 threads = 16 waves, thread t owns k-row t. Round-8 post-mortem: pk[18]
// held across the scores phase kept peak-live > 64 VGPR -> allocator (targeting
// 8 waves/EU at 48KB LDS) spilled 502 MB. Fix: FULL-size Pl[1024][18] in LDS
// (82.8 KB total, gfx950 allows >64KB static) so each group's packed bf16 P is
// written to LDS immediately — no persistent register state. 82.8 KB LDS also
// caps occupancy at 4 waves/EU structurally -> 128 VGPR budget. Softmax drops
// max-subtraction (|scores| <~ 5, exp safe; softmax shift-invariant) and the
// denominators are accumulated from the broadcast Pl reads inside PV.
template<int UBASE, int UCNT>
__device__ __forceinline__ void score_group(
    const float* __restrict__ kp, const float* qs, const int* rowsL,
    uint32_t* Pl, const int k, const int masked)
{
  float s[UCNT];
#pragma unroll
  for (int ug = 0; ug < UCNT; ++ug) s[ug] = 0.f;
#pragma unroll
  for (int dc = 0; dc < 64; dc += 16) {
    const float4 k0 = *(const float4*)(kp + dc);
    const float4 k1 = *(const float4*)(kp + dc + 4);
    const float4 k2 = *(const float4*)(kp + dc + 8);
    const float4 k3 = *(const float4*)(kp + dc + 12);
#pragma unroll
    for (int ug = 0; ug < UCNT; ++ug) {
      const float4* qp = (const float4*)&qs[(UBASE + ug) * 64 + dc];
      const float4 q0 = qp[0], q1 = qp[1], q2 = qp[2], q3 = qp[3];
      float acc = s[ug];
      acc = fmaf(q0.x, k0.x, acc); acc = fmaf(q0.y, k0.y, acc);
      acc = fmaf(q0.z, k0.z, acc); acc = fmaf(q0.w, k0.w, acc);
      acc = fmaf(q1.x, k1.x, acc); acc = fmaf(q1.y, k1.y, acc);
      acc = fmaf(q1.z, k1.z, acc); acc = fmaf(q1.w, k1.w, acc);
      acc = fmaf(q2.x, k2.x, acc); acc = fmaf(q2.y, k2.y, acc);
      acc = fmaf(q2.z, k2.z, acc); acc = fmaf(q2.w, k2.w, acc);
      acc = fmaf(q3.x, k3.x, acc); acc = fmaf(q3.y, k3.y, acc);
      acc = fmaf(q3.z, k3.z, acc); acc = fmaf(q3.w, k3.w, acc);
      s[ug] = acc;
    }
  }
#pragma unroll
  for (int ug = 0; ug < UCNT; ++ug) {
    float v = s[ug] * 0.125f;                      // 1/sqrt(64)
    if (masked && k > rowsL[UBASE + ug]) v = -__builtin_inff();
    s[ug] = expf(v);                               // no max-subtract (safe range)
  }
#pragma unroll
  for (int j = 0; j < UCNT / 2; ++j)
    Pl[k * 18 + UBASE / 2 + j] = bf16rne(s[2 * j]) | (bf16rne(s[2 * j + 1]) << 16);
  if (UCNT & 1)
    Pl[k * 18 + UBASE / 2 + UCNT / 2] = bf16rne(s[UCNT - 1]);
}

__global__ __launch_bounds__(1024, 4) void attn_fused(
    const float* __restrict__ Q, const float* __restrict__ K,
    const float* __restrict__ V, const int* __restrict__ Mtop,
    float* __restrict__ ctx_rows, int masked)
{
  __shared__ float    qs[U_ * DH_];     // 8960 B
  __shared__ uint32_t Pl[L_ * 18];      // 73728 B (full P, bf16-pair packed)
  __shared__ int      rowsL[U_ + 1];
  // total ~82.8 KB -> 1 block/CU, 4 waves/EU max -> 128 VGPR budget

  const int bh   = blockIdx.x;
  const int h    = bh & (H_ - 1), b = bh >> 4;
  const int tid  = threadIdx.x;
  const int lane = tid & 63, wid = tid >> 6;
  const size_t kvbase = (size_t)(b * L_) * DM_ + h * DH_;

  if (tid < U_) rowsL[tid] = Mtop[bh * U_ + tid];
  __syncthreads();
  for (int i = tid; i < U_ * DH_; i += 1024)
    qs[i] = Q[kvbase + (size_t)rowsL[i >> 6] * DM_ + (i & 63)];
  __syncthreads();

  const int k = tid;
  const float* kp = K + kvbase + (size_t)k * DM_;
  score_group<0, 12>(kp, qs, rowsL, Pl, k, masked);
  score_group<12, 12>(kp, qs, rowsL, Pl, k, masked);
  score_group<24, 11>(kp, qs, rowsL, Pl, k, masked);
  __syncthreads();

  // ---- PV: wave wid owns u=2wid,2wid+1 (+32+wid for wid<3); denominators
  // accumulated from the same broadcast Pl reads.
  float a0 = 0.f, a1 = 0.f, a2 = 0.f;
  float d0 = 0.f, d1 = 0.f, d2 = 0.f;
  const float* vp = V + kvbase + lane;
#pragma unroll 4
  for (int kk = 0; kk < L_; ++kk) {
    const float v0 = vp[(size_t)kk * DM_];
    const uint32_t p0 = Pl[kk * 18 + wid];
    const float plo = bitsf32(p0 << 16);
    const float phi = bitsf32(p0 & 0xFFFF0000u);
    a0 = fmaf(plo, v0, a0); d0 += plo;
    a1 = fmaf(phi, v0, a1); d1 += phi;
    if (wid < 3) {
      const uint32_t pe = Pl[kk * 18 + 16 + (wid >> 1)];  // wid0,1->w16; wid2->w17
      const float pv = (wid == 1) ? bitsf32(pe & 0xFFFF0000u) : bitsf32(pe << 16);
      a2 = fmaf(pv, v0, a2); d2 += pv;
    }
  }
  ctx_rows[(size_t)(bh * U_ + 2 * wid) * DH_ + lane]     = a0 / d0;
  ctx_rows[(size_t)(bh * U_ + 2 * wid + 1) * DH_ + lane] = a1 / d1;
  if (wid < 3)
    ctx_rows[(size_t)(bh * U_ + 32 + wid) * DH_ + lane]  = a2 / d2;
}

// ---------------- cumsum(V) over L per (b,h,d) ----------------------------
__global__ __launch_bounds__(256) void cumsum_kernel(
    const float* __restrict__ V, float* __restrict__ C)
{
  const int bh = blockIdx.x;
  const int h = bh & (H_ - 1), b = bh >> 4;
  const int d = threadIdx.x & 63, qq = threadIdx.x >> 6;
  __shared__ float chs[4][DH_];
  const size_t base = (size_t)b * L_ * DM_ + h * DH_ + d;
  float acc = 0.f;
  const int l0 = qq * 256;
  for (int l = l0; l < l0 + 256; ++l) acc += V[base + (size_t)l * DM_];
  chs[qq][d] = acc;
  __syncthreads();
  float off = 0.f;
  for (int j = 0; j < qq; ++j) off += chs[j][d];
  acc = off;
  for (int l = l0; l < l0 + 256; ++l) {
    acc += V[base + (size_t)l * DM_];
    C[base + (size_t)l * DM_] = acc;
  }
}

__global__ __launch_bounds__(256) void vmean_kernel(
    const float* __restrict__ V, float* __restrict__ vm)
{
  const int bh = blockIdx.x;
  const int h = bh & (H_ - 1), b = bh >> 4;
  const int d = threadIdx.x & 63, qq = threadIdx.x >> 6;
  __shared__ float chs[4][DH_];
  const size_t base = (size_t)b * L_ * DM_ + h * DH_ + d;
  float acc = 0.f;
  for (int l = qq * 256; l < qq * 256 + 256; ++l) acc += V[base + (size_t)l * DM_];
  chs[qq][d] = acc;
  __syncthreads();
  if (qq == 0)
    vm[bh * DH_ + d] = (chs[0][d] + chs[1][d] + chs[2][d] + chs[3][d]) * (1.0f / 1024.0f);
}

__global__ void fill_kernel(const float* __restrict__ vm, float* __restrict__ C)
{
  const size_t i = (size_t)blockIdx.x * 256 + threadIdx.x;
  const int d = (int)(i & 63);
  const int h = (int)((i >> 6) & (H_ - 1));
  const int b = (int)(i >> 20);
  C[i] = vm[(b * H_ + h) * DH_ + d];
}

__global__ void scatter_kernel(const float* __restrict__ ctx_rows,
                               const int* __restrict__ Mtop, float* __restrict__ C)
{
  const int bhu = blockIdx.x;
  const int u  = bhu % U_;
  const int bh = bhu / U_;
  const int h = bh & (H_ - 1), b = bh >> 4;
  const int row = Mtop[bh * U_ + u];
  C[(size_t)(b * L_ + row) * DM_ + h * DH_ + threadIdx.x] =
      ctx_rows[(size_t)bhu * DH_ + threadIdx.x];
}

// ---------------- LayerNorm(xa + xb) --------------------------------------
__global__ __launch_bounds__(256) void ln_kernel(
    const float* __restrict__ xa, const float* __restrict__ xb,
    const float* __restrict__ g, const float* __restrict__ bt,
    float* __restrict__ out)
{
  const int row = blockIdx.x;
  const int tid = threadIdx.x;
  __shared__ float v[DM_];
  __shared__ float red[256];
  float s = 0.f;
  for (int i = tid; i < DM_; i += 256) {
    const float t = xa[(size_t)row * DM_ + i] + xb[(size_t)row * DM_ + i];
    v[i] = t; s += t;
  }
  red[tid] = s; __syncthreads();
  for (int st = 128; st > 0; st >>= 1) { if (tid < st) red[tid] += red[tid+st]; __syncthreads(); }
  const float mean = red[0] * (1.0f / DM_);
  __syncthreads();
  float s2 = 0.f;
  for (int i = tid; i < DM_; i += 256) { const float dd = v[i] - mean; s2 += dd * dd; }
  red[tid] = s2; __syncthreads();
  for (int st = 128; st > 0; st >>= 1) { if (tid < st) red[tid] += red[tid+st]; __syncthreads(); }
  const float rstd = rsqrtf(red[0] * (1.0f / DM_) + 1e-5f);
  __syncthreads();
  for (int i = tid; i < DM_; i += 256)
    out[(size_t)row * DM_ + i] = (v[i] - mean) * rstd * g[i] + bt[i];
}

// ---------------- host orchestration --------------------------------------
extern "C" void kernel_launch(void* const* d_in, const int* in_sizes, int n_in,
                              void* d_out, int out_size, void* d_ws, size_t ws_size,
                              hipStream_t stream)
{
  (void)in_sizes; (void)n_in; (void)out_size; (void)ws_size;
  const float* x    = (const float*)d_in[0];
  const float* enc  = (const float*)d_in[1];
  const float* saWq = (const float*)d_in[2];  const float* sabq = (const float*)d_in[3];
  const float* saWk = (const float*)d_in[4];  const float* sabk = (const float*)d_in[5];
  const float* saWv = (const float*)d_in[6];  const float* sabv = (const float*)d_in[7];
  const float* saWo = (const float*)d_in[8];  const float* sabo = (const float*)d_in[9];
  const float* caWq = (const float*)d_in[10]; const float* cabq = (const float*)d_in[11];
  const float* caWk = (const float*)d_in[12]; const float* cabk = (const float*)d_in[13];
  const float* caWv = (const float*)d_in[14]; const float* cabv = (const float*)d_in[15];
  const float* caWo = (const float*)d_in[16]; const float* cabo = (const float*)d_in[17];
  const float* fW1  = (const float*)d_in[18]; const float* fb1  = (const float*)d_in[19];
  const float* fW2  = (const float*)d_in[20]; const float* fb2  = (const float*)d_in[21];
  const float* l1g  = (const float*)d_in[22]; const float* l1b  = (const float*)d_in[23];
  const float* l2g  = (const float*)d_in[24]; const float* l2b  = (const float*)d_in[25];
  const float* l3g  = (const float*)d_in[26]; const float* l3b  = (const float*)d_in[27];

  float* ws = (float*)d_ws;
  const size_t SL = (size_t)MROWS_ * DM_;      // 4M floats / 16 MB
  float* bufQ   = ws;
  float* bufK   = ws + SL;
  float* bufV   = ws + 2 * SL;
  float* bufC   = ws + 3 * SL;
  float* xcur   = ws + 4 * SL;
  float* tmp    = ws + 5 * SL;
  float* hidden = ws;                           // FFN stage reuses slots 0..3 (64 MB)
  float* smallp = ws + 6 * SL;
  int*   idxb = (int*)smallp;                                // 35840
  float* Mbuf = smallp + 36864;                              // 65536
  int*   Mtop = (int*)(smallp + 36864 + 65536);              // 2240 (pad to 2304)
  float* ctxr = smallp + 36864 + 65536 + 2304;               // 2240*64
  float* vm   = ctxr + 143360;                               // 1024

  // --- JAX partitionable-threefry key ladder (verified round 3) ---
  uint32_t k1a, k1b, k2a, k2b;
  tf2x32(0u, 42u, 0u, 0u, k1a, k1b);   // k1 = split(key)[0]
  tf2x32(0u, 42u, 0u, 1u, k2a, k2b);   // k2 = split(key)[1]
  uint32_t kb1a, kb1b, kb2a, kb2b;
  tf2x32(k1a, k1b, 0u, 1u, kb1a, kb1b);  // randint-internal split(k1)[1]
  tf2x32(k2a, k2b, 0u, 1u, kb2a, kb2b);  // randint-internal split(k2)[1]

  const dim3 thr(256);
  const int gIdx = (IDXN_ + 255) / 256;

  const dim3 gP1(DM_ / 128, MROWS_ / 128, 1);   // (8,32,1)
  const dim3 gP3(DM_ / 128, MROWS_ / 128, 3);   // (8,32,3)
  const dim3 gF1(FF_ / 128, MROWS_ / 128, 1);   // (32,32,1)

  // ---- self attention (masked) ----
  {
    Gemm3 g = {{x, x, x}, {saWq, saWk, saWv}, {sabq, sabk, sabv}, {bufQ, bufK, bufV}};
    gemm_mfma<3, false, false><<<gP3, thr, 0, stream>>>(g, DM_, DM_);
  }
  idx_kernel<<<gIdx, thr, 0, stream>>>(kb1a, kb1b, idxb);
  qks_m_kernel<<<(B_ * H_ * L_) / 4, thr, 0, stream>>>(bufQ, bufK, idxb, Mbuf);
  topk_kernel<<<B_ * H_, thr, 0, stream>>>(Mbuf, Mtop);
  attn_fused<<<B_ * H_, dim3(1024), 0, stream>>>(bufQ, bufK, bufV, Mtop, ctxr, 1);
  cumsum_kernel<<<B_ * H_, thr, 0, stream>>>(bufV, bufC);
  scatter_kernel<<<B_ * H_ * U_, dim3(64), 0, stream>>>(ctxr, Mtop, bufC);
  {
    Gemm3 g = {{bufC, nullptr, nullptr}, {saWo, nullptr, nullptr},
               {sabo, nullptr, nullptr}, {tmp, nullptr, nullptr}};
    gemm_mfma<2, false, true><<<gP1, thr, 0, stream>>>(g, DM_, DM_);
  }
  ln_kernel<<<MROWS_, thr, 0, stream>>>(x, tmp, l1g, l1b, xcur);

  // ---- cross attention (unmasked) ----
  {
    Gemm3 g = {{xcur, enc, enc}, {caWq, caWk, caWv}, {cabq, cabk, cabv}, {bufQ, bufK, bufV}};
    gemm_mfma<3, false, false><<<gP3, thr, 0, stream>>>(g, DM_, DM_);
  }
  idx_kernel<<<gIdx, thr, 0, stream>>>(kb2a, kb2b, idxb);
  qks_m_kernel<<<(B_ * H_ * L_) / 4, thr, 0, stream>>>(bufQ, bufK, idxb, Mbuf);
  topk_kernel<<<B_ * H_, thr, 0, stream>>>(Mbuf, Mtop);
  attn_fused<<<B_ * H_, dim3(1024), 0, stream>>>(bufQ, bufK, bufV, Mtop, ctxr, 0);
  vmean_kernel<<<B_ * H_, thr, 0, stream>>>(bufV, vm);
  fill_kernel<<<(int)(SL / 256), thr, 0, stream>>>(vm, bufC);
  scatter_kernel<<<B_ * H_ * U_, dim3(64), 0, stream>>>(ctxr, Mtop, bufC);
  {
    Gemm3 g = {{bufC, nullptr, nullptr}, {caWo, nullptr, nullptr},
               {cabo, nullptr, nullptr}, {tmp, nullptr, nullptr}};
    gemm_mfma<2, false, true><<<gP1, thr, 0, stream>>>(g, DM_, DM_);
  }
  ln_kernel<<<MROWS_, thr, 0, stream>>>(xcur, tmp, l2g, l2b, xcur);

  // ---- FFN ----
  {
    Gemm3 g = {{xcur, nullptr, nullptr}, {fW1, nullptr, nullptr},
               {fb1, nullptr, nullptr}, {hidden, nullptr, nullptr}};
    gemm_mfma<2, true, true><<<gF1, thr, 0, stream>>>(g, DM_, FF_);
  }
  {
    Gemm3 g = {{hidden, nullptr, nullptr}, {fW2, nullptr, nullptr},
               {fb2, nullptr, nullptr}, {tmp, nullptr, nullptr}};
    gemm_mfma<2, false, true><<<gP1, thr, 0, stream>>>(g, FF_, DM_);
  }
  ln_kernel<<<MROWS_, thr, 0, stream>>>(xcur, tmp, l3g, l3b, (float*)d_out);
}

// Round 10
// 1470.715 us; speedup vs baseline: 2.3788x; 1.1034x over previous
//
#include <hip/hip_runtime.h>
#include <cstdint>
#include <cstddef>

// Informer ProbSparse decoder layer.
// GEMMs: split-once bf16 limbs + pure-bf16 segment GEMM (global_load_lds).
// Q/K projections: 6 limb-product segments (~f32 accuracy, protects top-k).
// V/O/FFN: 1 segment (rne bf16) — smooth paths, LN renormalizes errors.
#define B_     4
#define L_     1024
#define DM_    1024
#define H_     16
#define DH_    64
#define U_     35
#define FF_    4096
#define MROWS_ 4096
#define IDXN_  35840

typedef __attribute__((ext_vector_type(8))) short bf16x8;
typedef __attribute__((ext_vector_type(4))) float f32x4;

// ---------------- Threefry-2x32-20 (exact JAX semantics) ----------------
__host__ __device__ inline void tf2x32(uint32_t k0, uint32_t k1,
                                       uint32_t x0, uint32_t x1,
                                       uint32_t& y0, uint32_t& y1) {
  const uint32_t ks2 = k0 ^ k1 ^ 0x1BD11BDAu;
  uint32_t v0 = x0 + k0, v1 = x1 + k1;
#define ROTL_(x,d) (((x)<<(d))|((x)>>(32-(d))))
#define RND_(r) { v0 += v1; v1 = ROTL_(v1,(r)); v1 ^= v0; }
  RND_(13) RND_(15) RND_(26) RND_(6)   v0 += k1;  v1 += ks2 + 1u;
  RND_(17) RND_(29) RND_(16) RND_(24)  v0 += ks2; v1 += k0  + 2u;
  RND_(13) RND_(15) RND_(26) RND_(6)   v0 += k0;  v1 += k1  + 3u;
  RND_(17) RND_(29) RND_(16) RND_(24)  v0 += k1;  v1 += ks2 + 4u;
  RND_(13) RND_(15) RND_(26) RND_(6)   v0 += ks2; v1 += k0  + 5u;
#undef RND_
#undef ROTL_
  y0 = v0; y1 = v1;
}

__global__ void idx_kernel(uint32_t k0, uint32_t k1, int* __restrict__ idx) {
  const int i = blockIdx.x * 256 + threadIdx.x;
  if (i >= IDXN_) return;
  uint32_t y0, y1;
  tf2x32(k0, k1, 0u, (uint32_t)i, y0, y1);
  idx[i] = (int)((y0 ^ y1) & 1023u);
}

// ---------------- bf16 helpers --------------------------------------------
__device__ __forceinline__ uint32_t f32bits(float x) {
  union { float f; uint32_t u; } c; c.f = x; return c.u;
}
__device__ __forceinline__ float bitsf32(uint32_t u) {
  union { uint32_t u; float f; } c; c.u = u; return c.f;
}
__device__ __forceinline__ uint32_t bf16rne(float x) {
  const uint32_t u = f32bits(x);
  return (u + 0x7FFFu + ((u >> 16) & 1u)) >> 16;
}
__device__ __forceinline__ float bf16tof(uint32_t h) { return bitsf32(h << 16); }

// rne 3-limb split: x = h + m + l + O(2^-27 x)
__device__ __forceinline__ void split3(float x, uint32_t& h, uint32_t& m, uint32_t& l) {
  h = bf16rne(x); const float r  = x - bf16tof(h);
  m = bf16rne(r); const float r2 = r - bf16tof(m);
  l = bf16rne(r2);
}

// ---------------- async global -> LDS (16B per lane) ----------------------
__device__ __forceinline__ void gload16(const void* g, void* l) {
  __builtin_amdgcn_global_load_lds(
      (const __attribute__((address_space(1))) void*)g,
      (__attribute__((address_space(3))) void*)l, 16, 0, 0);
}

// ---------------- transpose-split: W (KxN f32) -> W^T limbs (NxK bf16) ----
template<int LIMBS>
__global__ __launch_bounds__(256) void tsplit_kernel(
    const float* __restrict__ W, short* __restrict__ Th,
    short* __restrict__ Tm, short* __restrict__ Tl, int K, int N)
{
  __shared__ float tile[64][65];
  const int n0 = blockIdx.x * 64, k0 = blockIdx.y * 64;
  const int t = threadIdx.x;
  const int r = t >> 2, c0 = (t & 3) * 16;
  const float* src = W + (size_t)(k0 + r) * N + n0 + c0;
  const float4 v0 = *(const float4*)src;
  const float4 v1 = *(const float4*)(src + 4);
  const float4 v2 = *(const float4*)(src + 8);
  const float4 v3 = *(const float4*)(src + 12);
  float* tr = &tile[r][c0];
  tr[0]=v0.x; tr[1]=v0.y; tr[2]=v0.z; tr[3]=v0.w;
  tr[4]=v1.x; tr[5]=v1.y; tr[6]=v1.z; tr[7]=v1.w;
  tr[8]=v2.x; tr[9]=v2.y; tr[10]=v2.z; tr[11]=v2.w;
  tr[12]=v3.x; tr[13]=v3.y; tr[14]=v3.z; tr[15]=v3.w;
  __syncthreads();
  uint32_t ph[8], pm[8], pl[8];
#pragma unroll
  for (int j = 0; j < 16; j += 2) {
    uint32_t h0,m0,l0,h1,m1,l1;
    split3(tile[c0 + j][r], h0, m0, l0);
    split3(tile[c0 + j + 1][r], h1, m1, l1);
    ph[j>>1] = h0 | (h1 << 16);
    pm[j>>1] = m0 | (m1 << 16);
    pl[j>>1] = l0 | (l1 << 16);
  }
  const size_t ob = (size_t)(n0 + r) * K + k0 + c0;
  *(uint4*)(Th + ob)     = make_uint4(ph[0], ph[1], ph[2], ph[3]);
  *(uint4*)(Th + ob + 8) = make_uint4(ph[4], ph[5], ph[6], ph[7]);
  if (LIMBS == 3) {
    *(uint4*)(Tm + ob)     = make_uint4(pm[0], pm[1], pm[2], pm[3]);
    *(uint4*)(Tm + ob + 8) = make_uint4(pm[4], pm[5], pm[6], pm[7]);
    *(uint4*)(Tl + ob)     = make_uint4(pl[0], pl[1], pl[2], pl[3]);
    *(uint4*)(Tl + ob + 8) = make_uint4(pl[4], pl[5], pl[6], pl[7]);
  }
}

// ---------------- row split: X (f32) -> limbs (bf16), elementwise ---------
template<int LIMBS>
__global__ void rsplit_kernel(const float* __restrict__ X, short* __restrict__ Th,
                              short* __restrict__ Tm, short* __restrict__ Tl, int n8)
{
  const int i = blockIdx.x * 256 + threadIdx.x;
  if (i >= n8) return;
  const float4 a = ((const float4*)X)[2*i], b = ((const float4*)X)[2*i+1];
  const float v[8] = {a.x,a.y,a.z,a.w,b.x,b.y,b.z,b.w};
  uint32_t ph[4], pm[4], pl[4];
#pragma unroll
  for (int j = 0; j < 4; ++j) {
    uint32_t h0,m0,l0,h1,m1,l1;
    split3(v[2*j], h0, m0, l0);
    split3(v[2*j+1], h1, m1, l1);
    ph[j] = h0 | (h1 << 16); pm[j] = m0 | (m1 << 16); pl[j] = l0 | (l1 << 16);
  }
  ((uint4*)Th)[i] = make_uint4(ph[0], ph[1], ph[2], ph[3]);
  if (LIMBS == 3) {
    ((uint4*)Tm)[i] = make_uint4(pm[0], pm[1], pm[2], pm[3]);
    ((uint4*)Tl)[i] = make_uint4(pl[0], pl[1], pl[2], pl[3]);
  }
}

// ---------------- pure-bf16 segment GEMM (m97 structure) ------------------
// C = sum_s A_s (MxK bf16) @ B_s^T (NxK bf16) + bias. 128x128 tile, BK=32,
// 4 waves 2x2, global_load_lds w16 staging into linear LDS [128][32] bf16.
struct Seg { const short* A; const short* B; };
struct Job {
  Seg seg[6];
  int nseg;
  const float* bias;
  float* C;       // nullable
  short* Ch;      // nullable: rne-bf16 of output
  int relu;
};
struct Jobs { Job j[3]; };

__global__ __launch_bounds__(256, 2) void gemm_seg(Jobs jobs, int K, int N)
{
  __shared__ short As[4096] __attribute__((aligned(16)));   // [128][32] bf16
  __shared__ short Bs[4096] __attribute__((aligned(16)));
  const int z = blockIdx.z;
  const int bm = blockIdx.y * 128, bn = blockIdx.x * 128;
  const int t = threadIdx.x, lane = t & 63;
  const int wid = t >> 6, wr = wid >> 1, wc = wid & 1;
  const int l15 = lane & 15, kg = lane >> 4;
  const int srow = t >> 2, sch = (t & 3) * 8;   // staging row / short-chunk

  f32x4 acc[4][4];
#pragma unroll
  for (int m = 0; m < 4; ++m)
#pragma unroll
    for (int n = 0; n < 4; ++n) acc[m][n] = (f32x4){0.f,0.f,0.f,0.f};

  short* ad0 = As + t * 8;         short* ad1 = As + 2048 + t * 8;
  short* bd0 = Bs + t * 8;         short* bd1 = Bs + 2048 + t * 8;

  const int nseg = jobs.j[z].nseg;
  for (int s = 0; s < nseg; ++s) {
    const short* Ab = jobs.j[z].seg[s].A;
    const short* Bb = jobs.j[z].seg[s].B;
    const short* ap0 = Ab + (size_t)(bm + srow) * K + sch;
    const short* ap1 = Ab + (size_t)(bm + 64 + srow) * K + sch;
    const short* bp0 = Bb + (size_t)(bn + srow) * K + sch;
    const short* bp1 = Bb + (size_t)(bn + 64 + srow) * K + sch;
    for (int kk = 0; kk < K; kk += 32) {
      __syncthreads();                       // LDS reuse guard
      gload16(ap0 + kk, ad0);
      gload16(ap1 + kk, ad1);
      gload16(bp0 + kk, bd0);
      gload16(bp1 + kk, bd1);
      __syncthreads();                       // drains vmcnt before reads
      bf16x8 a[4], b[4];
#pragma unroll
      for (int m = 0; m < 4; ++m)
        a[m] = *(const bf16x8*)(As + (wr*64 + m*16 + l15) * 32 + kg * 8);
#pragma unroll
      for (int n = 0; n < 4; ++n)
        b[n] = *(const bf16x8*)(Bs + (wc*64 + n*16 + l15) * 32 + kg * 8);
#pragma unroll
      for (int m = 0; m < 4; ++m)
#pragma unroll
        for (int n = 0; n < 4; ++n)
          acc[m][n] = __builtin_amdgcn_mfma_f32_16x16x32_bf16(a[m], b[n], acc[m][n], 0, 0, 0);
    }
  }

  const float* bias = jobs.j[z].bias;
  float* C  = jobs.j[z].C;
  short* Ch = jobs.j[z].Ch;
  const int relu = jobs.j[z].relu;
  float bv[4];
#pragma unroll
  for (int n = 0; n < 4; ++n) bv[n] = bias[bn + wc*64 + n*16 + l15];
#pragma unroll
  for (int m = 0; m < 4; ++m) {
    const int row0 = bm + wr*64 + m*16 + kg*4;
#pragma unroll
    for (int n = 0; n < 4; ++n) {
      const int col = bn + wc*64 + n*16 + l15;
#pragma unroll
      for (int q = 0; q < 4; ++q) {
        float o = acc[m][n][q] + bv[n];
        if (relu) o = fmaxf(o, 0.f);
        const size_t off = (size_t)(row0 + q) * N + col;
        if (C)  C[off]  = o;
        if (Ch) Ch[off] = (short)bf16rne(o);
      }
    }
  }
}

// ---------------- sampled QK^T -> M scores --------------------------------
__global__ __launch_bounds__(256) void qks_m_kernel(
    const float* __restrict__ Q, const float* __restrict__ K,
    const int* __restrict__ idx, float* __restrict__ Mout)
{
  const int gw   = blockIdx.x * 4 + (threadIdx.x >> 6);
  const int lane = threadIdx.x & 63;
  const int l  = gw & (L_ - 1);
  const int bh = gw >> 10;
  const int h  = bh & (H_ - 1);
  const int b  = bh >> 4;
  const float q = Q[(size_t)(b * L_ + l) * DM_ + h * DH_ + lane];
  float mx = -__builtin_inff();
  float sm = 0.f;
  const int* ip = idx + l * U_;
  for (int s = 0; s < U_; ++s) {
    const int ks = ip[s];
    float p = q * K[(size_t)(b * L_ + ks) * DM_ + h * DH_ + lane];
#pragma unroll
    for (int off = 32; off > 0; off >>= 1) p += __shfl_xor(p, off, 64);
    mx = fmaxf(mx, p);
    sm += p;
  }
  if (lane == 0) Mout[gw] = mx - sm * (1.0f / 1024.0f);
}

// ---------------- top-35 indices per (b,h) --------------------------------
__global__ __launch_bounds__(256) void topk_kernel(
    const float* __restrict__ M, int* __restrict__ Mtop)
{
  const int bh  = blockIdx.x;
  const int tid = threadIdx.x;
  __shared__ float vals[L_];
  __shared__ float rv[256];
  __shared__ int   ri[256];
  for (int i = tid; i < L_; i += 256) vals[i] = M[(size_t)bh * L_ + i];
  __syncthreads();
  for (int t = 0; t < U_; ++t) {
    float best = -__builtin_inff();
    int   bi   = L_;
    for (int i = tid; i < L_; i += 256) {
      const float v = vals[i];
      if (v > best) { best = v; bi = i; }
    }
    rv[tid] = best; ri[tid] = bi;
    __syncthreads();
    for (int s = 128; s > 0; s >>= 1) {
      if (tid < s) {
        if (rv[tid+s] > rv[tid] || (rv[tid+s] == rv[tid] && ri[tid+s] < ri[tid])) {
          rv[tid] = rv[tid+s]; ri[tid] = ri[tid+s];
        }
      }
      __syncthreads();
    }
    if (tid == 0) { Mtop[bh * U_ + t] = ri[0]; vals[ri[0]] = -__builtin_inff(); }
    __syncthreads();
  }
}

// ---------------- fused attention: one block per (b,h) (round-9 verified) -
template<int UBASE, int UCNT>
__device__ __forceinline__ void score_group(
    const float* __restrict__ kp, const float* qs, const int* rowsL,
    uint32_t* Pl, const int k, const int masked)
{
  float s[UCNT];
#pragma unroll
  for (int ug = 0; ug < UCNT; ++ug) s[ug] = 0.f;
#pragma unroll
  for (int dc = 0; dc < 64; dc += 16) {
    const float4 k0 = *(const float4*)(kp + dc);
    const float4 k1 = *(const float4*)(kp + dc + 4);
    const float4 k2 = *(const float4*)(kp + dc + 8);
    const float4 k3 = *(const float4*)(kp + dc + 12);
#pragma unroll
    for (int ug = 0; ug < UCNT; ++ug) {
      const float4* qp = (const float4*)&qs[(UBASE + ug) * 64 + dc];
      const float4 q0 = qp[0], q1 = qp[1], q2 = qp[2], q3 = qp[3];
      float acc = s[ug];
      acc = fmaf(q0.x, k0.x, acc); acc = fmaf(q0.y, k0.y, acc);
      acc = fmaf(q0.z, k0.z, acc); acc = fmaf(q0.w, k0.w, acc);
      acc = fmaf(q1.x, k1.x, acc); acc = fmaf(q1.y, k1.y, acc);
      acc = fmaf(q1.z, k1.z, acc); acc = fmaf(q1.w, k1.w, acc);
      acc = fmaf(q2.x, k2.x, acc); acc = fmaf(q2.y, k2.y, acc);
      acc = fmaf(q2.z, k2.z, acc); acc = fmaf(q2.w, k2.w, acc);
      acc = fmaf(q3.x, k3.x, acc); acc = fmaf(q3.y, k3.y, acc);
      acc = fmaf(q3.z, k3.z, acc); acc = fmaf(q3.w, k3.w, acc);
      s[ug] = acc;
    }
  }
#pragma unroll
  for (int ug = 0; ug < UCNT; ++ug) {
    float v = s[ug] * 0.125f;
    if (masked && k > rowsL[UBASE + ug]) v = -__builtin_inff();
    s[ug] = expf(v);
  }
#pragma unroll
  for (int j = 0; j < UCNT / 2; ++j)
    Pl[k * 18 + UBASE / 2 + j] = bf16rne(s[2 * j]) | (bf16rne(s[2 * j + 1]) << 16);
  if (UCNT & 1)
    Pl[k * 18 + UBASE / 2 + UCNT / 2] = bf16rne(s[UCNT - 1]);
}

__global__ __launch_bounds__(1024, 4) void attn_fused(
    const float* __restrict__ Q, const float* __restrict__ K,
    const float* __restrict__ V, const int* __restrict__ Mtop,
    float* __restrict__ ctx_rows, int masked)
{
  __shared__ float    qs[U_ * DH_];
  __shared__ uint32_t Pl[L_ * 18];
  __shared__ int      rowsL[U_ + 1];

  const int bh   = blockIdx.x;
  const int h    = bh & (H_ - 1), b = bh >> 4;
  const int tid  = threadIdx.x;
  const int lane = tid & 63, wid = tid >> 6;
  const size_t kvbase = (size_t)(b * L_) * DM_ + h * DH_;

  if (tid < U_) rowsL[tid] = Mtop[bh * U_ + tid];
  __syncthreads();
  for (int i = tid; i < U_ * DH_; i += 1024)
    qs[i] = Q[kvbase + (size_t)rowsL[i >> 6] * DM_ + (i & 63)];
  __syncthreads();

  const int k = tid;
  const float* kp = K + kvbase + (size_t)k * DM_;
  score_group<0, 12>(kp, qs, rowsL, Pl, k, masked);
  score_group<12, 12>(kp, qs, rowsL, Pl, k, masked);
  score_group<24, 11>(kp, qs, rowsL, Pl, k, masked);
  __syncthreads();

  float a0 = 0.f, a1 = 0.f, a2 = 0.f;
  float d0 = 0.f, d1 = 0.f, d2 = 0.f;
  const float* vp = V + kvbase + lane;
#pragma unroll 4
  for (int kk = 0; kk < L_; ++kk) {
    const float v0 = vp[(size_t)kk * DM_];
    const uint32_t p0 = Pl[kk * 18 + wid];
    const float plo = bitsf32(p0 << 16);
    const float phi = bitsf32(p0 & 0xFFFF0000u);
    a0 = fmaf(plo, v0, a0); d0 += plo;
    a1 = fmaf(phi, v0, a1); d1 += phi;
    if (wid < 3) {
      const uint32_t pe = Pl[kk * 18 + 16 + (wid >> 1)];
      const float pv = (wid == 1) ? bitsf32(pe & 0xFFFF0000u) : bitsf32(pe << 16);
      a2 = fmaf(pv, v0, a2); d2 += pv;
    }
  }
  ctx_rows[(size_t)(bh * U_ + 2 * wid) * DH_ + lane]     = a0 / d0;
  ctx_rows[(size_t)(bh * U_ + 2 * wid + 1) * DH_ + lane] = a1 / d1;
  if (wid < 3)
    ctx_rows[(size_t)(bh * U_ + 32 + wid) * DH_ + lane]  = a2 / d2;
}

// ---------------- cumsum / vmean / fill / scatter -------------------------
__global__ __launch_bounds__(256) void cumsum_kernel(
    const float* __restrict__ V, float* __restrict__ C)
{
  const int bh = blockIdx.x;
  const int h = bh & (H_ - 1), b = bh >> 4;
  const int d = threadIdx.x & 63, qq = threadIdx.x >> 6;
  __shared__ float chs[4][DH_];
  const size_t base = (size_t)b * L_ * DM_ + h * DH_ + d;
  float acc = 0.f;
  const int l0 = qq * 256;
  for (int l = l0; l < l0 + 256; ++l) acc += V[base + (size_t)l * DM_];
  chs[qq][d] = acc;
  __syncthreads();
  float off = 0.f;
  for (int j = 0; j < qq; ++j) off += chs[j][d];
  acc = off;
  for (int l = l0; l < l0 + 256; ++l) {
    acc += V[base + (size_t)l * DM_];
    C[base + (size_t)l * DM_] = acc;
  }
}

__global__ __launch_bounds__(256) void vmean_kernel(
    const float* __restrict__ V, float* __restrict__ vm)
{
  const int bh = blockIdx.x;
  const int h = bh & (H_ - 1), b = bh >> 4;
  const int d = threadIdx.x & 63, qq = threadIdx.x >> 6;
  __shared__ float chs[4][DH_];
  const size_t base = (size_t)b * L_ * DM_ + h * DH_ + d;
  float acc = 0.f;
  for (int l = qq * 256; l < qq * 256 + 256; ++l) acc += V[base + (size_t)l * DM_];
  chs[qq][d] = acc;
  __syncthreads();
  if (qq == 0)
    vm[bh * DH_ + d] = (chs[0][d] + chs[1][d] + chs[2][d] + chs[3][d]) * (1.0f / 1024.0f);
}

__global__ void fill_kernel(const float* __restrict__ vm, float* __restrict__ C)
{
  const size_t i = (size_t)blockIdx.x * 256 + threadIdx.x;
  const int d = (int)(i & 63);
  const int h = (int)((i >> 6) & (H_ - 1));
  const int b = (int)(i >> 20);
  C[i] = vm[(b * H_ + h) * DH_ + d];
}

__global__ void scatter_kernel(const float* __restrict__ ctx_rows,
                               const int* __restrict__ Mtop, float* __restrict__ C)
{
  const int bhu = blockIdx.x;
  const int u  = bhu % U_;
  const int bh = bhu / U_;
  const int h = bh & (H_ - 1), b = bh >> 4;
  const int row = Mtop[bh * U_ + u];
  C[(size_t)(b * L_ + row) * DM_ + h * DH_ + threadIdx.x] =
      ctx_rows[(size_t)bhu * DH_ + threadIdx.x];
}

// ---------------- LayerNorm(xa + xb), optional limb outputs ---------------
__global__ __launch_bounds__(256) void ln_kernel(
    const float* __restrict__ xa, const float* __restrict__ xb,
    const float* __restrict__ g, const float* __restrict__ bt,
    float* __restrict__ out, short* __restrict__ oh,
    short* __restrict__ om, short* __restrict__ ol)
{
  const int row = blockIdx.x;
  const int tid = threadIdx.x;
  __shared__ float v[DM_];
  __shared__ float red[256];
  float s = 0.f;
  for (int i = tid; i < DM_; i += 256) {
    const float t = xa[(size_t)row * DM_ + i] + xb[(size_t)row * DM_ + i];
    v[i] = t; s += t;
  }
  red[tid] = s; __syncthreads();
  for (int st = 128; st > 0; st >>= 1) { if (tid < st) red[tid] += red[tid+st]; __syncthreads(); }
  const float mean = red[0] * (1.0f / DM_);
  __syncthreads();
  float s2 = 0.f;
  for (int i = tid; i < DM_; i += 256) { const float dd = v[i] - mean; s2 += dd * dd; }
  red[tid] = s2; __syncthreads();
  for (int st = 128; st > 0; st >>= 1) { if (tid < st) red[tid] += red[tid+st]; __syncthreads(); }
  const float rstd = rsqrtf(red[0] * (1.0f / DM_) + 1e-5f);
  __syncthreads();
  for (int i = tid; i < DM_; i += 256) {
    const size_t idx = (size_t)row * DM_ + i;
    const float o = (v[i] - mean) * rstd * g[i] + bt[i];
    out[idx] = o;
    if (oh) {
      const uint32_t h = bf16rne(o);
      oh[idx] = (short)h;
      if (om) {
        const float r = o - bf16tof(h);
        const uint32_t m = bf16rne(r);
        om[idx] = (short)m;
        ol[idx] = (short)bf16rne(r - bf16tof(m));
      }
    }
  }
}

// ---------------- host orchestration --------------------------------------
extern "C" void kernel_launch(void* const* d_in, const int* in_sizes, int n_in,
                              void* d_out, int out_size, void* d_ws, size_t ws_size,
                              hipStream_t stream)
{
  (void)in_sizes; (void)n_in; (void)out_size; (void)ws_size;
  const float* x    = (const float*)d_in[0];
  const float* enc  = (const float*)d_in[1];
  const float* saWq = (const float*)d_in[2];  const float* sabq = (const float*)d_in[3];
  const float* saWk = (const float*)d_in[4];  const float* sabk = (const float*)d_in[5];
  const float* saWv = (const float*)d_in[6];  const float* sabv = (const float*)d_in[7];
  const float* saWo = (const float*)d_in[8];  const float* sabo = (const float*)d_in[9];
  const float* caWq = (const float*)d_in[10]; const float* cabq = (const float*)d_in[11];
  const float* caWk = (const float*)d_in[12]; const float* cabk = (const float*)d_in[13];
  const float* caWv = (const float*)d_in[14]; const float* cabv = (const float*)d_in[15];
  const float* caWo = (const float*)d_in[16]; const float* cabo = (const float*)d_in[17];
  const float* fW1  = (const float*)d_in[18]; const float* fb1  = (const float*)d_in[19];
  const float* fW2  = (const float*)d_in[20]; const float* fb2  = (const float*)d_in[21];
  const float* l1g  = (const float*)d_in[22]; const float* l1b  = (const float*)d_in[23];
  const float* l2g  = (const float*)d_in[24]; const float* l2b  = (const float*)d_in[25];
  const float* l3g  = (const float*)d_in[26]; const float* l3b  = (const float*)d_in[27];

  float* ws = (float*)d_ws;
  const size_t SL = (size_t)MROWS_ * DM_;       // 4M floats
  float* bufQ = ws;
  float* bufK = ws + SL;
  float* bufV = ws + 2 * SL;
  float* bufC = ws + 3 * SL;
  float* xcur = ws + 4 * SL;
  float* tmp  = ws + 5 * SL;
  float* smallp = ws + 6 * SL;
  int*   idxb = (int*)smallp;
  float* Mbuf = smallp + 36864;
  int*   Mtop = (int*)(smallp + 36864 + 65536);
  float* ctxr = smallp + 36864 + 65536 + 2304;
  float* vm   = ctxr + 143360;

  const size_t M1 = 1024u * 1024u;              // shorts per 1024^2 limb
  short* wreg = (short*)(ws + 6 * SL + 262144); // 8M shorts (16 MB)
  short* areg = wreg + 8 * M1;                  // 24M shorts (48 MB)
  // weight limbs (per phase)
  short* Wqh = wreg;          short* Wqm = wreg + 1*M1; short* Wql = wreg + 2*M1;
  short* Wkh = wreg + 3*M1;   short* Wkm = wreg + 4*M1; short* Wkl = wreg + 5*M1;
  short* Wvh = wreg + 6*M1;   short* Woh = wreg + 7*M1;
  short* f1h = wreg;          short* f2h = wreg + 4*M1; // FFN phase (4M each)
  // activation limbs
  short* xh = areg;           short* xm = areg + 4*M1;  short* xl = areg + 8*M1;
  short* eh = areg + 12*M1;   short* em = areg + 16*M1; short* el = areg + 20*M1;
  short* bCh = areg + 12*M1;                            // reuses enc-h slot
  short* hidh = (short*)bufQ;                           // 16M shorts over bufQ+bufK

  // --- JAX partitionable-threefry key ladder (verified round 3) ---
  uint32_t k1a, k1b, k2a, k2b;
  tf2x32(0u, 42u, 0u, 0u, k1a, k1b);
  tf2x32(0u, 42u, 0u, 1u, k2a, k2b);
  uint32_t kb1a, kb1b, kb2a, kb2b;
  tf2x32(k1a, k1b, 0u, 1u, kb1a, kb1b);
  tf2x32(k2a, k2b, 0u, 1u, kb2a, kb2b);

  const dim3 thr(256);
  const int gIdx = (IDXN_ + 255) / 256;
  const int n8 = (int)(SL / 8);                 // 8-elem groups per SL buffer
  const dim3 gT(16, 16);                        // 1024x1024 transpose-split

  // ============ self attention (masked) ============
  tsplit_kernel<3><<<gT, thr, 0, stream>>>(saWq, Wqh, Wqm, Wql, DM_, DM_);
  tsplit_kernel<3><<<gT, thr, 0, stream>>>(saWk, Wkh, Wkm, Wkl, DM_, DM_);
  tsplit_kernel<1><<<gT, thr, 0, stream>>>(saWv, Wvh, nullptr, nullptr, DM_, DM_);
  tsplit_kernel<1><<<gT, thr, 0, stream>>>(saWo, Woh, nullptr, nullptr, DM_, DM_);
  rsplit_kernel<3><<<n8 / 256, thr, 0, stream>>>(x, xh, xm, xl, n8);
  {
    Jobs J = {};
    J.j[0] = { {{xh,Wqh},{xh,Wqm},{xm,Wqh},{xm,Wqm},{xh,Wql},{xl,Wqh}}, 6, sabq, bufQ, nullptr, 0 };
    J.j[1] = { {{xh,Wkh},{xh,Wkm},{xm,Wkh},{xm,Wkm},{xh,Wkl},{xl,Wkh}}, 6, sabk, bufK, nullptr, 0 };
    J.j[2] = { {{xh,Wvh},{nullptr,nullptr},{nullptr,nullptr},{nullptr,nullptr},{nullptr,nullptr},{nullptr,nullptr}}, 1, sabv, bufV, nullptr, 0 };
    gemm_seg<<<dim3(8, 32, 3), thr, 0, stream>>>(J, DM_, DM_);
  }
  idx_kernel<<<gIdx, thr, 0, stream>>>(kb1a, kb1b, idxb);
  qks_m_kernel<<<(B_ * H_ * L_) / 4, thr, 0, stream>>>(bufQ, bufK, idxb, Mbuf);
  topk_kernel<<<B_ * H_, thr, 0, stream>>>(Mbuf, Mtop);
  attn_fused<<<B_ * H_, dim3(1024), 0, stream>>>(bufQ, bufK, bufV, Mtop, ctxr, 1);
  cumsum_kernel<<<B_ * H_, thr, 0, stream>>>(bufV, bufC);
  scatter_kernel<<<B_ * H_ * U_, dim3(64), 0, stream>>>(ctxr, Mtop, bufC);
  rsplit_kernel<1><<<n8 / 256, thr, 0, stream>>>(bufC, bCh, nullptr, nullptr, n8);
  {
    Jobs J = {};
    J.j[0] = { {{bCh,Woh},{nullptr,nullptr},{nullptr,nullptr},{nullptr,nullptr},{nullptr,nullptr},{nullptr,nullptr}}, 1, sabo, tmp, nullptr, 0 };
    gemm_seg<<<dim3(8, 32, 1), thr, 0, stream>>>(J, DM_, DM_);
  }
  ln_kernel<<<MROWS_, thr, 0, stream>>>(x, tmp, l1g, l1b, xcur, xh, xm, xl);

  // ============ cross attention (unmasked) ============
  tsplit_kernel<3><<<gT, thr, 0, stream>>>(caWq, Wqh, Wqm, Wql, DM_, DM_);
  tsplit_kernel<3><<<gT, thr, 0, stream>>>(caWk, Wkh, Wkm, Wkl, DM_, DM_);
  tsplit_kernel<1><<<gT, thr, 0, stream>>>(caWv, Wvh, nullptr, nullptr, DM_, DM_);
  tsplit_kernel<1><<<gT, thr, 0, stream>>>(caWo, Woh, nullptr, nullptr, DM_, DM_);
  rsplit_kernel<3><<<n8 / 256, thr, 0, stream>>>(enc, eh, em, el, n8);
  {
    Jobs J = {};
    J.j[0] = { {{xh,Wqh},{xh,Wqm},{xm,Wqh},{xm,Wqm},{xh,Wql},{xl,Wqh}}, 6, cabq, bufQ, nullptr, 0 };
    J.j[1] = { {{eh,Wkh},{eh,Wkm},{em,Wkh},{em,Wkm},{eh,Wkl},{el,Wkh}}, 6, cabk, bufK, nullptr, 0 };
    J.j[2] = { {{eh,Wvh},{nullptr,nullptr},{nullptr,nullptr},{nullptr,nullptr},{nullptr,nullptr},{nullptr,nullptr}}, 1, cabv, bufV, nullptr, 0 };
    gemm_seg<<<dim3(8, 32, 3), thr, 0, stream>>>(J, DM_, DM_);
  }
  idx_kernel<<<gIdx, thr, 0, stream>>>(kb2a, kb2b, idxb);
  qks_m_kernel<<<(B_ * H_ * L_) / 4, thr, 0, stream>>>(bufQ, bufK, idxb, Mbuf);
  topk_kernel<<<B_ * H_, thr, 0, stream>>>(Mbuf, Mtop);
  attn_fused<<<B_ * H_, dim3(1024), 0, stream>>>(bufQ, bufK, bufV, Mtop, ctxr, 0);
  vmean_kernel<<<B_ * H_, thr, 0, stream>>>(bufV, vm);
  fill_kernel<<<(int)(SL / 256), thr, 0, stream>>>(vm, bufC);
  scatter_kernel<<<B_ * H_ * U_, dim3(64), 0, stream>>>(ctxr, Mtop, bufC);
  rsplit_kernel<1><<<n8 / 256, thr, 0, stream>>>(bufC, bCh, nullptr, nullptr, n8);
  {
    Jobs J = {};
    J.j[0] = { {{bCh,Woh},{nullptr,nullptr},{nullptr,nullptr},{nullptr,nullptr},{nullptr,nullptr},{nullptr,nullptr}}, 1, cabo, tmp, nullptr, 0 };
    gemm_seg<<<dim3(8, 32, 1), thr, 0, stream>>>(J, DM_, DM_);
  }
  ln_kernel<<<MROWS_, thr, 0, stream>>>(xcur, tmp, l2g, l2b, xcur, xh, nullptr, nullptr);

  // ============ FFN ============
  tsplit_kernel<1><<<dim3(64, 16), thr, 0, stream>>>(fW1, f1h, nullptr, nullptr, DM_, FF_);
  tsplit_kernel<1><<<dim3(16, 64), thr, 0, stream>>>(fW2, f2h, nullptr, nullptr, FF_, DM_);
  {
    Jobs J = {};
    J.j[0] = { {{xh,f1h},{nullptr,nullptr},{nullptr,nullptr},{nullptr,nullptr},{nullptr,nullptr},{nullptr,nullptr}}, 1, fb1, nullptr, hidh, 1 };
    gemm_seg<<<dim3(32, 32, 1), thr, 0, stream>>>(J, DM_, FF_);
  }
  {
    Jobs J = {};
    J.j[0] = { {{hidh,f2h},{nullptr,nullptr},{nullptr,nullptr},{nullptr,nullptr},{nullptr,nullptr},{nullptr,nullptr}}, 1, fb2, tmp, nullptr, 0 };
    gemm_seg<<<dim3(8, 32, 1), thr, 0, stream>>>(J, FF_, DM_);
  }
  ln_kernel<<<MROWS_, thr, 0, stream>>>(xcur, tmp, l3g, l3b, (float*)d_out,
                                        nullptr, nullptr, nullptr);
}

// Round 11
// 1384.144 us; speedup vs baseline: 2.5275x; 1.0625x over previous
//
#include <hip/hip_runtime.h>
#include <cstdint>
#include <cstddef>

// Informer ProbSparse decoder layer.
// GEMMs: split-once bf16 limbs + pure-bf16 segment GEMM (global_load_lds).
// Q/K projections: 6 limb-product segments (~f32 accuracy, protects top-k).
// V/O/FFN: 1 segment (rne bf16) — smooth paths, LN renormalizes errors.
#define B_     4
#define L_     1024
#define DM_    1024
#define H_     16
#define DH_    64
#define U_     35
#define FF_    4096
#define MROWS_ 4096
#define IDXN_  35840

typedef __attribute__((ext_vector_type(8))) short bf16x8;
typedef __attribute__((ext_vector_type(4))) float f32x4;

// ---------------- Threefry-2x32-20 (exact JAX semantics) ----------------
__host__ __device__ inline void tf2x32(uint32_t k0, uint32_t k1,
                                       uint32_t x0, uint32_t x1,
                                       uint32_t& y0, uint32_t& y1) {
  const uint32_t ks2 = k0 ^ k1 ^ 0x1BD11BDAu;
  uint32_t v0 = x0 + k0, v1 = x1 + k1;
#define ROTL_(x,d) (((x)<<(d))|((x)>>(32-(d))))
#define RND_(r) { v0 += v1; v1 = ROTL_(v1,(r)); v1 ^= v0; }
  RND_(13) RND_(15) RND_(26) RND_(6)   v0 += k1;  v1 += ks2 + 1u;
  RND_(17) RND_(29) RND_(16) RND_(24)  v0 += ks2; v1 += k0  + 2u;
  RND_(13) RND_(15) RND_(26) RND_(6)   v0 += k0;  v1 += k1  + 3u;
  RND_(17) RND_(29) RND_(16) RND_(24)  v0 += k1;  v1 += ks2 + 4u;
  RND_(13) RND_(15) RND_(26) RND_(6)   v0 += ks2; v1 += k0  + 5u;
#undef RND_
#undef ROTL_
  y0 = v0; y1 = v1;
}

__global__ void idx_kernel(uint32_t k0, uint32_t k1, int* __restrict__ idx) {
  const int i = blockIdx.x * 256 + threadIdx.x;
  if (i >= IDXN_) return;
  uint32_t y0, y1;
  tf2x32(k0, k1, 0u, (uint32_t)i, y0, y1);
  idx[i] = (int)((y0 ^ y1) & 1023u);
}

// ---------------- bf16 helpers --------------------------------------------
__device__ __forceinline__ uint32_t f32bits(float x) {
  union { float f; uint32_t u; } c; c.f = x; return c.u;
}
__device__ __forceinline__ float bitsf32(uint32_t u) {
  union { uint32_t u; float f; } c; c.u = u; return c.f;
}
__device__ __forceinline__ uint32_t bf16rne(float x) {
  const uint32_t u = f32bits(x);
  return (u + 0x7FFFu + ((u >> 16) & 1u)) >> 16;
}
__device__ __forceinline__ float bf16tof(uint32_t h) { return bitsf32(h << 16); }

// rne 3-limb split: x = h + m + l + O(2^-27 x)
__device__ __forceinline__ void split3(float x, uint32_t& h, uint32_t& m, uint32_t& l) {
  h = bf16rne(x); const float r  = x - bf16tof(h);
  m = bf16rne(r); const float r2 = r - bf16tof(m);
  l = bf16rne(r2);
}

// ---------------- async global -> LDS (16B per lane) ----------------------
__device__ __forceinline__ void gload16(const void* g, void* l) {
  __builtin_amdgcn_global_load_lds(
      (const __attribute__((address_space(1))) void*)g,
      (__attribute__((address_space(3))) void*)l, 16, 0, 0);
}

// ---------------- transpose-split: W (KxN f32) -> W^T limbs (NxK bf16) ----
template<int LIMBS>
__global__ __launch_bounds__(256) void tsplit_kernel(
    const float* __restrict__ W, short* __restrict__ Th,
    short* __restrict__ Tm, short* __restrict__ Tl, int K, int N)
{
  __shared__ float tile[64][65];
  const int n0 = blockIdx.x * 64, k0 = blockIdx.y * 64;
  const int t = threadIdx.x;
  const int r = t >> 2, c0 = (t & 3) * 16;
  const float* src = W + (size_t)(k0 + r) * N + n0 + c0;
  const float4 v0 = *(const float4*)src;
  const float4 v1 = *(const float4*)(src + 4);
  const float4 v2 = *(const float4*)(src + 8);
  const float4 v3 = *(const float4*)(src + 12);
  float* tr = &tile[r][c0];
  tr[0]=v0.x; tr[1]=v0.y; tr[2]=v0.z; tr[3]=v0.w;
  tr[4]=v1.x; tr[5]=v1.y; tr[6]=v1.z; tr[7]=v1.w;
  tr[8]=v2.x; tr[9]=v2.y; tr[10]=v2.z; tr[11]=v2.w;
  tr[12]=v3.x; tr[13]=v3.y; tr[14]=v3.z; tr[15]=v3.w;
  __syncthreads();
  uint32_t ph[8], pm[8], pl[8];
#pragma unroll
  for (int j = 0; j < 16; j += 2) {
    uint32_t h0,m0,l0,h1,m1,l1;
    split3(tile[c0 + j][r], h0, m0, l0);
    split3(tile[c0 + j + 1][r], h1, m1, l1);
    ph[j>>1] = h0 | (h1 << 16);
    pm[j>>1] = m0 | (m1 << 16);
    pl[j>>1] = l0 | (l1 << 16);
  }
  const size_t ob = (size_t)(n0 + r) * K + k0 + c0;
  *(uint4*)(Th + ob)     = make_uint4(ph[0], ph[1], ph[2], ph[3]);
  *(uint4*)(Th + ob + 8) = make_uint4(ph[4], ph[5], ph[6], ph[7]);
  if (LIMBS == 3) {
    *(uint4*)(Tm + ob)     = make_uint4(pm[0], pm[1], pm[2], pm[3]);
    *(uint4*)(Tm + ob + 8) = make_uint4(pm[4], pm[5], pm[6], pm[7]);
    *(uint4*)(Tl + ob)     = make_uint4(pl[0], pl[1], pl[2], pl[3]);
    *(uint4*)(Tl + ob + 8) = make_uint4(pl[4], pl[5], pl[6], pl[7]);
  }
}

// ---------------- row split: X (f32) -> limbs (bf16), elementwise ---------
template<int LIMBS>
__global__ void rsplit_kernel(const float* __restrict__ X, short* __restrict__ Th,
                              short* __restrict__ Tm, short* __restrict__ Tl, int n8)
{
  const int i = blockIdx.x * 256 + threadIdx.x;
  if (i >= n8) return;
  const float4 a = ((const float4*)X)[2*i], b = ((const float4*)X)[2*i+1];
  const float v[8] = {a.x,a.y,a.z,a.w,b.x,b.y,b.z,b.w};
  uint32_t ph[4], pm[4], pl[4];
#pragma unroll
  for (int j = 0; j < 4; ++j) {
    uint32_t h0,m0,l0,h1,m1,l1;
    split3(v[2*j], h0, m0, l0);
    split3(v[2*j+1], h1, m1, l1);
    ph[j] = h0 | (h1 << 16); pm[j] = m0 | (m1 << 16); pl[j] = l0 | (l1 << 16);
  }
  ((uint4*)Th)[i] = make_uint4(ph[0], ph[1], ph[2], ph[3]);
  if (LIMBS == 3) {
    ((uint4*)Tm)[i] = make_uint4(pm[0], pm[1], pm[2], pm[3]);
    ((uint4*)Tl)[i] = make_uint4(pl[0], pl[1], pl[2], pl[3]);
  }
}

// ---------------- pure-bf16 segment GEMM (m97 structure) ------------------
struct Seg { const short* A; const short* B; };
struct Job {
  Seg seg[6];
  int nseg;
  const float* bias;
  float* C;       // nullable
  short* Ch;      // nullable: rne-bf16 of output
  int relu;
};
struct Jobs { Job j[3]; };

__global__ __launch_bounds__(256, 2) void gemm_seg(Jobs jobs, int K, int N)
{
  __shared__ short As[4096] __attribute__((aligned(16)));   // [128][32] bf16
  __shared__ short Bs[4096] __attribute__((aligned(16)));
  const int z = blockIdx.z;
  const int bm = blockIdx.y * 128, bn = blockIdx.x * 128;
  const int t = threadIdx.x, lane = t & 63;
  const int wid = t >> 6, wr = wid >> 1, wc = wid & 1;
  const int l15 = lane & 15, kg = lane >> 4;
  const int srow = t >> 2, sch = (t & 3) * 8;

  f32x4 acc[4][4];
#pragma unroll
  for (int m = 0; m < 4; ++m)
#pragma unroll
    for (int n = 0; n < 4; ++n) acc[m][n] = (f32x4){0.f,0.f,0.f,0.f};

  short* ad0 = As + t * 8;         short* ad1 = As + 2048 + t * 8;
  short* bd0 = Bs + t * 8;         short* bd1 = Bs + 2048 + t * 8;

  const int nseg = jobs.j[z].nseg;
  for (int s = 0; s < nseg; ++s) {
    const short* Ab = jobs.j[z].seg[s].A;
    const short* Bb = jobs.j[z].seg[s].B;
    const short* ap0 = Ab + (size_t)(bm + srow) * K + sch;
    const short* ap1 = Ab + (size_t)(bm + 64 + srow) * K + sch;
    const short* bp0 = Bb + (size_t)(bn + srow) * K + sch;
    const short* bp1 = Bb + (size_t)(bn + 64 + srow) * K + sch;
    for (int kk = 0; kk < K; kk += 32) {
      __syncthreads();
      gload16(ap0 + kk, ad0);
      gload16(ap1 + kk, ad1);
      gload16(bp0 + kk, bd0);
      gload16(bp1 + kk, bd1);
      __syncthreads();
      bf16x8 a[4], b[4];
#pragma unroll
      for (int m = 0; m < 4; ++m)
        a[m] = *(const bf16x8*)(As + (wr*64 + m*16 + l15) * 32 + kg * 8);
#pragma unroll
      for (int n = 0; n < 4; ++n)
        b[n] = *(const bf16x8*)(Bs + (wc*64 + n*16 + l15) * 32 + kg * 8);
#pragma unroll
      for (int m = 0; m < 4; ++m)
#pragma unroll
        for (int n = 0; n < 4; ++n)
          acc[m][n] = __builtin_amdgcn_mfma_f32_16x16x32_bf16(a[m], b[n], acc[m][n], 0, 0, 0);
    }
  }

  const float* bias = jobs.j[z].bias;
  float* C  = jobs.j[z].C;
  short* Ch = jobs.j[z].Ch;
  const int relu = jobs.j[z].relu;
  float bv[4];
#pragma unroll
  for (int n = 0; n < 4; ++n) bv[n] = bias[bn + wc*64 + n*16 + l15];
#pragma unroll
  for (int m = 0; m < 4; ++m) {
    const int row0 = bm + wr*64 + m*16 + kg*4;
#pragma unroll
    for (int n = 0; n < 4; ++n) {
      const int col = bn + wc*64 + n*16 + l15;
#pragma unroll
      for (int q = 0; q < 4; ++q) {
        float o = acc[m][n][q] + bv[n];
        if (relu) o = fmaxf(o, 0.f);
        const size_t off = (size_t)(row0 + q) * N + col;
        if (C)  C[off]  = o;
        if (Ch) Ch[off] = (short)bf16rne(o);
      }
    }
  }
}

// ---------------- sampled QK^T -> M scores --------------------------------
// Round-10 post-mortem: 197us latency-bound (serial idx->gather->6-shuffle
// chain per s; VALUBusy 32%, HBM 5%). Fix: (1) preload all 35 sampled K
// values into regs (indices via readfirstlane -> SGPR; 35 gathers in flight
// at once); (2) sum-commute: sum_s(q.K_s) = q.(sum_s K_s) -> ONE reduce for
// the mean term; (3) max chains unrolled & independent -> ILP interleave.
__global__ __launch_bounds__(256) void qks_m_kernel(
    const float* __restrict__ Q, const float* __restrict__ K,
    const int* __restrict__ idx, float* __restrict__ Mout)
{
  const int gw   = blockIdx.x * 4 + (threadIdx.x >> 6);
  const int lane = threadIdx.x & 63;
  const int l  = gw & (L_ - 1);
  const int bh = gw >> 10;
  const int h  = bh & (H_ - 1);
  const int b  = bh >> 4;
  const size_t base = (size_t)(b * L_) * DM_ + h * DH_ + lane;
  const float q = Q[base + (size_t)l * DM_];
  const int* ip = idx + l * U_;

  float kv[U_];
#pragma unroll
  for (int s = 0; s < U_; ++s) {
    const int ks = __builtin_amdgcn_readfirstlane(ip[s]);   // wave-uniform
    kv[s] = K[base + (size_t)ks * DM_];
  }
  float ksum = 0.f;
#pragma unroll
  for (int s = 0; s < U_; ++s) ksum += kv[s];

  float sm = q * ksum;
#pragma unroll
  for (int off = 32; off > 0; off >>= 1) sm += __shfl_xor(sm, off, 64);

  float mx = -__builtin_inff();
#pragma unroll
  for (int s = 0; s < U_; ++s) {
    float p = q * kv[s];
#pragma unroll
    for (int off = 32; off > 0; off >>= 1) p += __shfl_xor(p, off, 64);
    mx = fmaxf(mx, p);
  }
  if (lane == 0) Mout[gw] = mx - sm * (1.0f / 1024.0f);
}

// ---------------- top-35 indices per (b,h) --------------------------------
__global__ __launch_bounds__(256) void topk_kernel(
    const float* __restrict__ M, int* __restrict__ Mtop)
{
  const int bh  = blockIdx.x;
  const int tid = threadIdx.x;
  __shared__ float vals[L_];
  __shared__ float rv[256];
  __shared__ int   ri[256];
  for (int i = tid; i < L_; i += 256) vals[i] = M[(size_t)bh * L_ + i];
  __syncthreads();
  for (int t = 0; t < U_; ++t) {
    float best = -__builtin_inff();
    int   bi   = L_;
    for (int i = tid; i < L_; i += 256) {
      const float v = vals[i];
      if (v > best) { best = v; bi = i; }
    }
    rv[tid] = best; ri[tid] = bi;
    __syncthreads();
    for (int s = 128; s > 0; s >>= 1) {
      if (tid < s) {
        if (rv[tid+s] > rv[tid] || (rv[tid+s] == rv[tid] && ri[tid+s] < ri[tid])) {
          rv[tid] = rv[tid+s]; ri[tid] = ri[tid+s];
        }
      }
      __syncthreads();
    }
    if (tid == 0) { Mtop[bh * U_ + t] = ri[0]; vals[ri[0]] = -__builtin_inff(); }
    __syncthreads();
  }
}

// ---------------- fused attention: one block per (b,h) (round-9 verified) -
template<int UBASE, int UCNT>
__device__ __forceinline__ void score_group(
    const float* __restrict__ kp, const float* qs, const int* rowsL,
    uint32_t* Pl, const int k, const int masked)
{
  float s[UCNT];
#pragma unroll
  for (int ug = 0; ug < UCNT; ++ug) s[ug] = 0.f;
#pragma unroll
  for (int dc = 0; dc < 64; dc += 16) {
    const float4 k0 = *(const float4*)(kp + dc);
    const float4 k1 = *(const float4*)(kp + dc + 4);
    const float4 k2 = *(const float4*)(kp + dc + 8);
    const float4 k3 = *(const float4*)(kp + dc + 12);
#pragma unroll
    for (int ug = 0; ug < UCNT; ++ug) {
      const float4* qp = (const float4*)&qs[(UBASE + ug) * 64 + dc];
      const float4 q0 = qp[0], q1 = qp[1], q2 = qp[2], q3 = qp[3];
      float acc = s[ug];
      acc = fmaf(q0.x, k0.x, acc); acc = fmaf(q0.y, k0.y, acc);
      acc = fmaf(q0.z, k0.z, acc); acc = fmaf(q0.w, k0.w, acc);
      acc = fmaf(q1.x, k1.x, acc); acc = fmaf(q1.y, k1.y, acc);
      acc = fmaf(q1.z, k1.z, acc); acc = fmaf(q1.w, k1.w, acc);
      acc = fmaf(q2.x, k2.x, acc); acc = fmaf(q2.y, k2.y, acc);
      acc = fmaf(q2.z, k2.z, acc); acc = fmaf(q2.w, k2.w, acc);
      acc = fmaf(q3.x, k3.x, acc); acc = fmaf(q3.y, k3.y, acc);
      acc = fmaf(q3.z, k3.z, acc); acc = fmaf(q3.w, k3.w, acc);
      s[ug] = acc;
    }
  }
#pragma unroll
  for (int ug = 0; ug < UCNT; ++ug) {
    float v = s[ug] * 0.125f;
    if (masked && k > rowsL[UBASE + ug]) v = -__builtin_inff();
    s[ug] = expf(v);
  }
#pragma unroll
  for (int j = 0; j < UCNT / 2; ++j)
    Pl[k * 18 + UBASE / 2 + j] = bf16rne(s[2 * j]) | (bf16rne(s[2 * j + 1]) << 16);
  if (UCNT & 1)
    Pl[k * 18 + UBASE / 2 + UCNT / 2] = bf16rne(s[UCNT - 1]);
}

__global__ __launch_bounds__(1024, 4) void attn_fused(
    const float* __restrict__ Q, const float* __restrict__ K,
    const float* __restrict__ V, const int* __restrict__ Mtop,
    float* __restrict__ ctx_rows, int masked)
{
  __shared__ float    qs[U_ * DH_];
  __shared__ uint32_t Pl[L_ * 18];
  __shared__ int      rowsL[U_ + 1];

  const int bh   = blockIdx.x;
  const int h    = bh & (H_ - 1), b = bh >> 4;
  const int tid  = threadIdx.x;
  const int lane = tid & 63, wid = tid >> 6;
  const size_t kvbase = (size_t)(b * L_) * DM_ + h * DH_;

  if (tid < U_) rowsL[tid] = Mtop[bh * U_ + tid];
  __syncthreads();
  for (int i = tid; i < U_ * DH_; i += 1024)
    qs[i] = Q[kvbase + (size_t)rowsL[i >> 6] * DM_ + (i & 63)];
  __syncthreads();

  const int k = tid;
  const float* kp = K + kvbase + (size_t)k * DM_;
  score_group<0, 12>(kp, qs, rowsL, Pl, k, masked);
  score_group<12, 12>(kp, qs, rowsL, Pl, k, masked);
  score_group<24, 11>(kp, qs, rowsL, Pl, k, masked);
  __syncthreads();

  float a0 = 0.f, a1 = 0.f, a2 = 0.f;
  float d0 = 0.f, d1 = 0.f, d2 = 0.f;
  const float* vp = V + kvbase + lane;
#pragma unroll 4
  for (int kk = 0; kk < L_; ++kk) {
    const float v0 = vp[(size_t)kk * DM_];
    const uint32_t p0 = Pl[kk * 18 + wid];
    const float plo = bitsf32(p0 << 16);
    const float phi = bitsf32(p0 & 0xFFFF0000u);
    a0 = fmaf(plo, v0, a0); d0 += plo;
    a1 = fmaf(phi, v0, a1); d1 += phi;
    if (wid < 3) {
      const uint32_t pe = Pl[kk * 18 + 16 + (wid >> 1)];
      const float pv = (wid == 1) ? bitsf32(pe & 0xFFFF0000u) : bitsf32(pe << 16);
      a2 = fmaf(pv, v0, a2); d2 += pv;
    }
  }
  ctx_rows[(size_t)(bh * U_ + 2 * wid) * DH_ + lane]     = a0 / d0;
  ctx_rows[(size_t)(bh * U_ + 2 * wid + 1) * DH_ + lane] = a1 / d1;
  if (wid < 3)
    ctx_rows[(size_t)(bh * U_ + 32 + wid) * DH_ + lane]  = a2 / d2;
}

// ---------------- cumsum / vmean / fill / scatter -------------------------
__global__ __launch_bounds__(256) void cumsum_kernel(
    const float* __restrict__ V, float* __restrict__ C)
{
  const int bh = blockIdx.x;
  const int h = bh & (H_ - 1), b = bh >> 4;
  const int d = threadIdx.x & 63, qq = threadIdx.x >> 6;
  __shared__ float chs[4][DH_];
  const size_t base = (size_t)b * L_ * DM_ + h * DH_ + d;
  float acc = 0.f;
  const int l0 = qq * 256;
  for (int l = l0; l < l0 + 256; ++l) acc += V[base + (size_t)l * DM_];
  chs[qq][d] = acc;
  __syncthreads();
  float off = 0.f;
  for (int j = 0; j < qq; ++j) off += chs[j][d];
  acc = off;
  for (int l = l0; l < l0 + 256; ++l) {
    acc += V[base + (size_t)l * DM_];
    C[base + (size_t)l * DM_] = acc;
  }
}

__global__ __launch_bounds__(256) void vmean_kernel(
    const float* __restrict__ V, float* __restrict__ vm)
{
  const int bh = blockIdx.x;
  const int h = bh & (H_ - 1), b = bh >> 4;
  const int d = threadIdx.x & 63, qq = threadIdx.x >> 6;
  __shared__ float chs[4][DH_];
  const size_t base = (size_t)b * L_ * DM_ + h * DH_ + d;
  float acc = 0.f;
  for (int l = qq * 256; l < qq * 256 + 256; ++l) acc += V[base + (size_t)l * DM_];
  chs[qq][d] = acc;
  __syncthreads();
  if (qq == 0)
    vm[bh * DH_ + d] = (chs[0][d] + chs[1][d] + chs[2][d] + chs[3][d]) * (1.0f / 1024.0f);
}

__global__ void fill_kernel(const float* __restrict__ vm, float* __restrict__ C)
{
  const size_t i = (size_t)blockIdx.x * 256 + threadIdx.x;
  const int d = (int)(i & 63);
  const int h = (int)((i >> 6) & (H_ - 1));
  const int b = (int)(i >> 20);
  C[i] = vm[(b * H_ + h) * DH_ + d];
}

__global__ void scatter_kernel(const float* __restrict__ ctx_rows,
                               const int* __restrict__ Mtop, float* __restrict__ C)
{
  const int bhu = blockIdx.x;
  const int u  = bhu % U_;
  const int bh = bhu / U_;
  const int h = bh & (H_ - 1), b = bh >> 4;
  const int row = Mtop[bh * U_ + u];
  C[(size_t)(b * L_ + row) * DM_ + h * DH_ + threadIdx.x] =
      ctx_rows[(size_t)bhu * DH_ + threadIdx.x];
}

// ---------------- LayerNorm(xa + xb), optional limb outputs ---------------
__global__ __launch_bounds__(256) void ln_kernel(
    const float* __restrict__ xa, const float* __restrict__ xb,
    const float* __restrict__ g, const float* __restrict__ bt,
    float* __restrict__ out, short* __restrict__ oh,
    short* __restrict__ om, short* __restrict__ ol)
{
  const int row = blockIdx.x;
  const int tid = threadIdx.x;
  __shared__ float v[DM_];
  __shared__ float red[256];
  float s = 0.f;
  for (int i = tid; i < DM_; i += 256) {
    const float t = xa[(size_t)row * DM_ + i] + xb[(size_t)row * DM_ + i];
    v[i] = t; s += t;
  }
  red[tid] = s; __syncthreads();
  for (int st = 128; st > 0; st >>= 1) { if (tid < st) red[tid] += red[tid+st]; __syncthreads(); }
  const float mean = red[0] * (1.0f / DM_);
  __syncthreads();
  float s2 = 0.f;
  for (int i = tid; i < DM_; i += 256) { const float dd = v[i] - mean; s2 += dd * dd; }
  red[tid] = s2; __syncthreads();
  for (int st = 128; st > 0; st >>= 1) { if (tid < st) red[tid] += red[tid+st]; __syncthreads(); }
  const float rstd = rsqrtf(red[0] * (1.0f / DM_) + 1e-5f);
  __syncthreads();
  for (int i = tid; i < DM_; i += 256) {
    const size_t idx = (size_t)row * DM_ + i;
    const float o = (v[i] - mean) * rstd * g[i] + bt[i];
    out[idx] = o;
    if (oh) {
      const uint32_t h = bf16rne(o);
      oh[idx] = (short)h;
      if (om) {
        const float r = o - bf16tof(h);
        const uint32_t m = bf16rne(r);
        om[idx] = (short)m;
        ol[idx] = (short)bf16rne(r - bf16tof(m));
      }
    }
  }
}

// ---------------- host orchestration --------------------------------------
extern "C" void kernel_launch(void* const* d_in, const int* in_sizes, int n_in,
                              void* d_out, int out_size, void* d_ws, size_t ws_size,
                              hipStream_t stream)
{
  (void)in_sizes; (void)n_in; (void)out_size; (void)ws_size;
  const float* x    = (const float*)d_in[0];
  const float* enc  = (const float*)d_in[1];
  const float* saWq = (const float*)d_in[2];  const float* sabq = (const float*)d_in[3];
  const float* saWk = (const float*)d_in[4];  const float* sabk = (const float*)d_in[5];
  const float* saWv = (const float*)d_in[6];  const float* sabv = (const float*)d_in[7];
  const float* saWo = (const float*)d_in[8];  const float* sabo = (const float*)d_in[9];
  const float* caWq = (const float*)d_in[10]; const float* cabq = (const float*)d_in[11];
  const float* caWk = (const float*)d_in[12]; const float* cabk = (const float*)d_in[13];
  const float* caWv = (const float*)d_in[14]; const float* cabv = (const float*)d_in[15];
  const float* caWo = (const float*)d_in[16]; const float* cabo = (const float*)d_in[17];
  const float* fW1  = (const float*)d_in[18]; const float* fb1  = (const float*)d_in[19];
  const float* fW2  = (const float*)d_in[20]; const float* fb2  = (const float*)d_in[21];
  const float* l1g  = (const float*)d_in[22]; const float* l1b  = (const float*)d_in[23];
  const float* l2g  = (const float*)d_in[24]; const float* l2b  = (const float*)d_in[25];
  const float* l3g  = (const float*)d_in[26]; const float* l3b  = (const float*)d_in[27];

  float* ws = (float*)d_ws;
  const size_t SL = (size_t)MROWS_ * DM_;       // 4M floats
  float* bufQ = ws;
  float* bufK = ws + SL;
  float* bufV = ws + 2 * SL;
  float* bufC = ws + 3 * SL;
  float* xcur = ws + 4 * SL;
  float* tmp  = ws + 5 * SL;
  float* smallp = ws + 6 * SL;
  int*   idxb = (int*)smallp;
  float* Mbuf = smallp + 36864;
  int*   Mtop = (int*)(smallp + 36864 + 65536);
  float* ctxr = smallp + 36864 + 65536 + 2304;
  float* vm   = ctxr + 143360;

  const size_t M1 = 1024u * 1024u;              // shorts per 1024^2 limb
  short* wreg = (short*)(ws + 6 * SL + 262144); // 8M shorts (16 MB)
  short* areg = wreg + 8 * M1;                  // 24M shorts (48 MB)
  short* Wqh = wreg;          short* Wqm = wreg + 1*M1; short* Wql = wreg + 2*M1;
  short* Wkh = wreg + 3*M1;   short* Wkm = wreg + 4*M1; short* Wkl = wreg + 5*M1;
  short* Wvh = wreg + 6*M1;   short* Woh = wreg + 7*M1;
  short* f1h = wreg;          short* f2h = wreg + 4*M1;
  short* xh = areg;           short* xm = areg + 4*M1;  short* xl = areg + 8*M1;
  short* eh = areg + 12*M1;   short* em = areg + 16*M1; short* el = areg + 20*M1;
  short* bCh = areg + 12*M1;
  short* hidh = (short*)bufQ;

  // --- JAX partitionable-threefry key ladder (verified round 3) ---
  uint32_t k1a, k1b, k2a, k2b;
  tf2x32(0u, 42u, 0u, 0u, k1a, k1b);
  tf2x32(0u, 42u, 0u, 1u, k2a, k2b);
  uint32_t kb1a, kb1b, kb2a, kb2b;
  tf2x32(k1a, k1b, 0u, 1u, kb1a, kb1b);
  tf2x32(k2a, k2b, 0u, 1u, kb2a, kb2b);

  const dim3 thr(256);
  const int gIdx = (IDXN_ + 255) / 256;
  const int n8 = (int)(SL / 8);
  const dim3 gT(16, 16);

  // ============ self attention (masked) ============
  tsplit_kernel<3><<<gT, thr, 0, stream>>>(saWq, Wqh, Wqm, Wql, DM_, DM_);
  tsplit_kernel<3><<<gT, thr, 0, stream>>>(saWk, Wkh, Wkm, Wkl, DM_, DM_);
  tsplit_kernel<1><<<gT, thr, 0, stream>>>(saWv, Wvh, nullptr, nullptr, DM_, DM_);
  tsplit_kernel<1><<<gT, thr, 0, stream>>>(saWo, Woh, nullptr, nullptr, DM_, DM_);
  rsplit_kernel<3><<<n8 / 256, thr, 0, stream>>>(x, xh, xm, xl, n8);
  {
    Jobs J = {};
    J.j[0] = { {{xh,Wqh},{xh,Wqm},{xm,Wqh},{xm,Wqm},{xh,Wql},{xl,Wqh}}, 6, sabq, bufQ, nullptr, 0 };
    J.j[1] = { {{xh,Wkh},{xh,Wkm},{xm,Wkh},{xm,Wkm},{xh,Wkl},{xl,Wkh}}, 6, sabk, bufK, nullptr, 0 };
    J.j[2] = { {{xh,Wvh},{nullptr,nullptr},{nullptr,nullptr},{nullptr,nullptr},{nullptr,nullptr},{nullptr,nullptr}}, 1, sabv, bufV, nullptr, 0 };
    gemm_seg<<<dim3(8, 32, 3), thr, 0, stream>>>(J, DM_, DM_);
  }
  idx_kernel<<<gIdx, thr, 0, stream>>>(kb1a, kb1b, idxb);
  qks_m_kernel<<<(B_ * H_ * L_) / 4, thr, 0, stream>>>(bufQ, bufK, idxb, Mbuf);
  topk_kernel<<<B_ * H_, thr, 0, stream>>>(Mbuf, Mtop);
  attn_fused<<<B_ * H_, dim3(1024), 0, stream>>>(bufQ, bufK, bufV, Mtop, ctxr, 1);
  cumsum_kernel<<<B_ * H_, thr, 0, stream>>>(bufV, bufC);
  scatter_kernel<<<B_ * H_ * U_, dim3(64), 0, stream>>>(ctxr, Mtop, bufC);
  rsplit_kernel<1><<<n8 / 256, thr, 0, stream>>>(bufC, bCh, nullptr, nullptr, n8);
  {
    Jobs J = {};
    J.j[0] = { {{bCh,Woh},{nullptr,nullptr},{nullptr,nullptr},{nullptr,nullptr},{nullptr,nullptr},{nullptr,nullptr}}, 1, sabo, tmp, nullptr, 0 };
    gemm_seg<<<dim3(8, 32, 1), thr, 0, stream>>>(J, DM_, DM_);
  }
  ln_kernel<<<MROWS_, thr, 0, stream>>>(x, tmp, l1g, l1b, xcur, xh, xm, xl);

  // ============ cross attention (unmasked) ============
  tsplit_kernel<3><<<gT, thr, 0, stream>>>(caWq, Wqh, Wqm, Wql, DM_, DM_);
  tsplit_kernel<3><<<gT, thr, 0, stream>>>(caWk, Wkh, Wkm, Wkl, DM_, DM_);
  tsplit_kernel<1><<<gT, thr, 0, stream>>>(caWv, Wvh, nullptr, nullptr, DM_, DM_);
  tsplit_kernel<1><<<gT, thr, 0, stream>>>(caWo, Woh, nullptr, nullptr, DM_, DM_);
  rsplit_kernel<3><<<n8 / 256, thr, 0, stream>>>(enc, eh, em, el, n8);
  {
    Jobs J = {};
    J.j[0] = { {{xh,Wqh},{xh,Wqm},{xm,Wqh},{xm,Wqm},{xh,Wql},{xl,Wqh}}, 6, cabq, bufQ, nullptr, 0 };
    J.j[1] = { {{eh,Wkh},{eh,Wkm},{em,Wkh},{em,Wkm},{eh,Wkl},{el,Wkh}}, 6, cabk, bufK, nullptr, 0 };
    J.j[2] = { {{eh,Wvh},{nullptr,nullptr},{nullptr,nullptr},{nullptr,nullptr},{nullptr,nullptr},{nullptr,nullptr}}, 1, cabv, bufV, nullptr, 0 };
    gemm_seg<<<dim3(8, 32, 3), thr, 0, stream>>>(J, DM_, DM_);
  }
  idx_kernel<<<gIdx, thr, 0, stream>>>(kb2a, kb2b, idxb);
  qks_m_kernel<<<(B_ * H_ * L_) / 4, thr, 0, stream>>>(bufQ, bufK, idxb, Mbuf);
  topk_kernel<<<B_ * H_, thr, 0, stream>>>(Mbuf, Mtop);
  attn_fused<<<B_ * H_, dim3(1024), 0, stream>>>(bufQ, bufK, bufV, Mtop, ctxr, 0);
  vmean_kernel<<<B_ * H_, thr, 0, stream>>>(bufV, vm);
  fill_kernel<<<(int)(SL / 256), thr, 0, stream>>>(vm, bufC);
  scatter_kernel<<<B_ * H_ * U_, dim3(64), 0, stream>>>(ctxr, Mtop, bufC);
  rsplit_kernel<1><<<n8 / 256, thr, 0, stream>>>(bufC, bCh, nullptr, nullptr, n8);
  {
    Jobs J = {};
    J.j[0] = { {{bCh,Woh},{nullptr,nullptr},{nullptr,nullptr},{nullptr,nullptr},{nullptr,nullptr},{nullptr,nullptr}}, 1, cabo, tmp, nullptr, 0 };
    gemm_seg<<<dim3(8, 32, 1), thr, 0, stream>>>(J, DM_, DM_);
  }
  ln_kernel<<<MROWS_, thr, 0, stream>>>(xcur, tmp, l2g, l2b, xcur, xh, nullptr, nullptr);

  // ============ FFN ============
  tsplit_kernel<1><<<dim3(64, 16), thr, 0, stream>>>(fW1, f1h, nullptr, nullptr, DM_, FF_);
  tsplit_kernel<1><<<dim3(16, 64), thr, 0, stream>>>(fW2, f2h, nullptr, nullptr, FF_, DM_);
  {
    Jobs J = {};
    J.j[0] = { {{xh,f1h},{nullptr,nullptr},{nullptr,nullptr},{nullptr,nullptr},{nullptr,nullptr},{nullptr,nullptr}}, 1, fb1, nullptr, hidh, 1 };
    gemm_seg<<<dim3(32, 32, 1), thr, 0, stream>>>(J, DM_, FF_);
  }
  {
    Jobs J = {};
    J.j[0] = { {{hidh,f2h},{nullptr,nullptr},{nullptr,nullptr},{nullptr,nullptr},{nullptr,nullptr},{nullptr,nullptr}}, 1, fb2, tmp, nullptr, 0 };
    gemm_seg<<<dim3(8, 32, 1), thr, 0, stream>>>(J, FF_, DM_);
  }
  ln_kernel<<<MROWS_, thr, 0, stream>>>(xcur, tmp, l3g, l3b, (float*)d_out,
                                        nullptr, nullptr, nullptr);
}

// Round 13
// 1266.009 us; speedup vs baseline: 2.7634x; 1.0933x over previous
//
#include <hip/hip_runtime.h>
#include <cstdint>
#include <cstddef>

// Informer ProbSparse decoder layer.
// GEMMs: split-once bf16 limbs + pure-bf16 segment GEMM (global_load_lds).
// Q/K projections: 6 limb-product segments (~f32 accuracy, protects top-k).
// V/O/FFN: 1 segment (rne bf16). Attention: 3-kernel k-split (score/pv/reduce)
// so the 1024-wave job spreads over all 256 CUs (round-11: 64-block version
// left 75% of the chip idle; 9% VALUBusy).
#define B_     4
#define L_     1024
#define DM_    1024
#define H_     16
#define DH_    64
#define U_     35
#define FF_    4096
#define MROWS_ 4096
#define IDXN_  35840
#define KS_    4            // k-splits per (b,h) in attention

typedef __attribute__((ext_vector_type(8))) short bf16x8;
typedef __attribute__((ext_vector_type(4))) float f32x4;

// ---------------- Threefry-2x32-20 (exact JAX semantics) ----------------
__host__ __device__ inline void tf2x32(uint32_t k0, uint32_t k1,
                                       uint32_t x0, uint32_t x1,
                                       uint32_t& y0, uint32_t& y1) {
  const uint32_t ks2 = k0 ^ k1 ^ 0x1BD11BDAu;
  uint32_t v0 = x0 + k0, v1 = x1 + k1;
#define ROTL_(x,d) (((x)<<(d))|((x)>>(32-(d))))
#define RND_(r) { v0 += v1; v1 = ROTL_(v1,(r)); v1 ^= v0; }
  RND_(13) RND_(15) RND_(26) RND_(6)   v0 += k1;  v1 += ks2 + 1u;
  RND_(17) RND_(29) RND_(16) RND_(24)  v0 += ks2; v1 += k0  + 2u;
  RND_(13) RND_(15) RND_(26) RND_(6)   v0 += k0;  v1 += k1  + 3u;
  RND_(17) RND_(29) RND_(16) RND_(24)  v0 += k1;  v1 += ks2 + 4u;
  RND_(13) RND_(15) RND_(26) RND_(6)   v0 += ks2; v1 += k0  + 5u;
#undef RND_
#undef ROTL_
  y0 = v0; y1 = v1;
}

__global__ void idx_kernel(uint32_t k0, uint32_t k1, int* __restrict__ idx) {
  const int i = blockIdx.x * 256 + threadIdx.x;
  if (i >= IDXN_) return;
  uint32_t y0, y1;
  tf2x32(k0, k1, 0u, (uint32_t)i, y0, y1);
  idx[i] = (int)((y0 ^ y1) & 1023u);
}

// ---------------- bf16 helpers --------------------------------------------
__device__ __forceinline__ uint32_t f32bits(float x) {
  union { float f; uint32_t u; } c; c.f = x; return c.u;
}
__device__ __forceinline__ float bitsf32(uint32_t u) {
  union { uint32_t u; float f; } c; c.u = u; return c.f;
}
__device__ __forceinline__ uint32_t bf16rne(float x) {
  const uint32_t u = f32bits(x);
  return (u + 0x7FFFu + ((u >> 16) & 1u)) >> 16;
}
__device__ __forceinline__ float bf16tof(uint32_t h) { return bitsf32(h << 16); }

__device__ __forceinline__ void split3(float x, uint32_t& h, uint32_t& m, uint32_t& l) {
  h = bf16rne(x); const float r  = x - bf16tof(h);
  m = bf16rne(r); const float r2 = r - bf16tof(m);
  l = bf16rne(r2);
}

// ---------------- async global -> LDS (16B per lane) ----------------------
__device__ __forceinline__ void gload16(const void* g, void* l) {
  __builtin_amdgcn_global_load_lds(
      (const __attribute__((address_space(1))) void*)g,
      (__attribute__((address_space(3))) void*)l, 16, 0, 0);
}

// ---------------- transpose-split: W (KxN f32) -> W^T limbs (NxK bf16) ----
template<int LIMBS>
__global__ __launch_bounds__(256) void tsplit_kernel(
    const float* __restrict__ W, short* __restrict__ Th,
    short* __restrict__ Tm, short* __restrict__ Tl, int K, int N)
{
  __shared__ float tile[64][65];
  const int n0 = blockIdx.x * 64, k0 = blockIdx.y * 64;
  const int t = threadIdx.x;
  const int r = t >> 2, c0 = (t & 3) * 16;
  const float* src = W + (size_t)(k0 + r) * N + n0 + c0;
  const float4 v0 = *(const float4*)src;
  const float4 v1 = *(const float4*)(src + 4);
  const float4 v2 = *(const float4*)(src + 8);
  const float4 v3 = *(const float4*)(src + 12);
  float* tr = &tile[r][c0];
  tr[0]=v0.x; tr[1]=v0.y; tr[2]=v0.z; tr[3]=v0.w;
  tr[4]=v1.x; tr[5]=v1.y; tr[6]=v1.z; tr[7]=v1.w;
  tr[8]=v2.x; tr[9]=v2.y; tr[10]=v2.z; tr[11]=v2.w;
  tr[12]=v3.x; tr[13]=v3.y; tr[14]=v3.z; tr[15]=v3.w;
  __syncthreads();
  uint32_t ph[8], pm[8], pl[8];
#pragma unroll
  for (int j = 0; j < 16; j += 2) {
    uint32_t h0,m0,l0,h1,m1,l1;
    split3(tile[c0 + j][r], h0, m0, l0);
    split3(tile[c0 + j + 1][r], h1, m1, l1);
    ph[j>>1] = h0 | (h1 << 16);
    pm[j>>1] = m0 | (m1 << 16);
    pl[j>>1] = l0 | (l1 << 16);
  }
  const size_t ob = (size_t)(n0 + r) * K + k0 + c0;
  *(uint4*)(Th + ob)     = make_uint4(ph[0], ph[1], ph[2], ph[3]);
  *(uint4*)(Th + ob + 8) = make_uint4(ph[4], ph[5], ph[6], ph[7]);
  if (LIMBS == 3) {
    *(uint4*)(Tm + ob)     = make_uint4(pm[0], pm[1], pm[2], pm[3]);
    *(uint4*)(Tm + ob + 8) = make_uint4(pm[4], pm[5], pm[6], pm[7]);
    *(uint4*)(Tl + ob)     = make_uint4(pl[0], pl[1], pl[2], pl[3]);
    *(uint4*)(Tl + ob + 8) = make_uint4(pl[4], pl[5], pl[6], pl[7]);
  }
}

// ---------------- row split: X (f32) -> limbs (bf16), elementwise ---------
template<int LIMBS>
__global__ void rsplit_kernel(const float* __restrict__ X, short* __restrict__ Th,
                              short* __restrict__ Tm, short* __restrict__ Tl, int n8)
{
  const int i = blockIdx.x * 256 + threadIdx.x;
  if (i >= n8) return;
  const float4 a = ((const float4*)X)[2*i], b = ((const float4*)X)[2*i+1];
  const float v[8] = {a.x,a.y,a.z,a.w,b.x,b.y,b.z,b.w};
  uint32_t ph[4], pm[4], pl[4];
#pragma unroll
  for (int j = 0; j < 4; ++j) {
    uint32_t h0,m0,l0,h1,m1,l1;
    split3(v[2*j], h0, m0, l0);
    split3(v[2*j+1], h1, m1, l1);
    ph[j] = h0 | (h1 << 16); pm[j] = m0 | (m1 << 16); pl[j] = l0 | (l1 << 16);
  }
  ((uint4*)Th)[i] = make_uint4(ph[0], ph[1], ph[2], ph[3]);
  if (LIMBS == 3) {
    ((uint4*)Tm)[i] = make_uint4(pm[0], pm[1], pm[2], pm[3]);
    ((uint4*)Tl)[i] = make_uint4(pl[0], pl[1], pl[2], pl[3]);
  }
}

// ---------------- pure-bf16 segment GEMM (m97 structure) ------------------
struct Seg { const short* A; const short* B; };
struct Job {
  Seg seg[6];
  int nseg;
  const float* bias;
  float* C;       // nullable
  short* Ch;      // nullable: rne-bf16 of output
  int relu;
};
struct Jobs { Job j[3]; };

__global__ __launch_bounds__(256, 2) void gemm_seg(Jobs jobs, int K, int N)
{
  __shared__ short As[4096] __attribute__((aligned(16)));   // [128][32] bf16
  __shared__ short Bs[4096] __attribute__((aligned(16)));
  const int z = blockIdx.z;
  const int bm = blockIdx.y * 128, bn = blockIdx.x * 128;
  const int t = threadIdx.x, lane = t & 63;
  const int wid = t >> 6, wr = wid >> 1, wc = wid & 1;
  const int l15 = lane & 15, kg = lane >> 4;
  const int srow = t >> 2, sch = (t & 3) * 8;

  f32x4 acc[4][4];
#pragma unroll
  for (int m = 0; m < 4; ++m)
#pragma unroll
    for (int n = 0; n < 4; ++n) acc[m][n] = (f32x4){0.f,0.f,0.f,0.f};

  short* ad0 = As + t * 8;         short* ad1 = As + 2048 + t * 8;
  short* bd0 = Bs + t * 8;         short* bd1 = Bs + 2048 + t * 8;

  const int nseg = jobs.j[z].nseg;
  for (int s = 0; s < nseg; ++s) {
    const short* Ab = jobs.j[z].seg[s].A;
    const short* Bb = jobs.j[z].seg[s].B;
    const short* ap0 = Ab + (size_t)(bm + srow) * K + sch;
    const short* ap1 = Ab + (size_t)(bm + 64 + srow) * K + sch;
    const short* bp0 = Bb + (size_t)(bn + srow) * K + sch;
    const short* bp1 = Bb + (size_t)(bn + 64 + srow) * K + sch;
    for (int kk = 0; kk < K; kk += 32) {
      __syncthreads();
      gload16(ap0 + kk, ad0);
      gload16(ap1 + kk, ad1);
      gload16(bp0 + kk, bd0);
      gload16(bp1 + kk, bd1);
      __syncthreads();
      bf16x8 a[4], b[4];
#pragma unroll
      for (int m = 0; m < 4; ++m)
        a[m] = *(const bf16x8*)(As + (wr*64 + m*16 + l15) * 32 + kg * 8);
#pragma unroll
      for (int n = 0; n < 4; ++n)
        b[n] = *(const bf16x8*)(Bs + (wc*64 + n*16 + l15) * 32 + kg * 8);
#pragma unroll
      for (int m = 0; m < 4; ++m)
#pragma unroll
        for (int n = 0; n < 4; ++n)
          acc[m][n] = __builtin_amdgcn_mfma_f32_16x16x32_bf16(a[m], b[n], acc[m][n], 0, 0, 0);
    }
  }

  const float* bias = jobs.j[z].bias;
  float* C  = jobs.j[z].C;
  short* Ch = jobs.j[z].Ch;
  const int relu = jobs.j[z].relu;
  float bv[4];
#pragma unroll
  for (int n = 0; n < 4; ++n) bv[n] = bias[bn + wc*64 + n*16 + l15];
#pragma unroll
  for (int m = 0; m < 4; ++m) {
    const int row0 = bm + wr*64 + m*16 + kg*4;
#pragma unroll
    for (int n = 0; n < 4; ++n) {
      const int col = bn + wc*64 + n*16 + l15;
#pragma unroll
      for (int q = 0; q < 4; ++q) {
        float o = acc[m][n][q] + bv[n];
        if (relu) o = fmaxf(o, 0.f);
        const size_t off = (size_t)(row0 + q) * N + col;
        if (C)  C[off]  = o;
        if (Ch) Ch[off] = (short)bf16rne(o);
      }
    }
  }
}

// ---------------- sampled QK^T -> M scores (round-11 verified) ------------
__global__ __launch_bounds__(256) void qks_m_kernel(
    const float* __restrict__ Q, const float* __restrict__ K,
    const int* __restrict__ idx, float* __restrict__ Mout)
{
  const int gw   = blockIdx.x * 4 + (threadIdx.x >> 6);
  const int lane = threadIdx.x & 63;
  const int l  = gw & (L_ - 1);
  const int bh = gw >> 10;
  const int h  = bh & (H_ - 1);
  const int b  = bh >> 4;
  const size_t base = (size_t)(b * L_) * DM_ + h * DH_ + lane;
  const float q = Q[base + (size_t)l * DM_];
  const int* ip = idx + l * U_;

  float kv[U_];
#pragma unroll
  for (int s = 0; s < U_; ++s) {
    const int ks = __builtin_amdgcn_readfirstlane(ip[s]);
    kv[s] = K[base + (size_t)ks * DM_];
  }
  float ksum = 0.f;
#pragma unroll
  for (int s = 0; s < U_; ++s) ksum += kv[s];

  float sm = q * ksum;
#pragma unroll
  for (int off = 32; off > 0; off >>= 1) sm += __shfl_xor(sm, off, 64);

  float mx = -__builtin_inff();
#pragma unroll
  for (int s = 0; s < U_; ++s) {
    float p = q * kv[s];
#pragma unroll
    for (int off = 32; off > 0; off >>= 1) p += __shfl_xor(p, off, 64);
    mx = fmaxf(mx, p);
  }
  if (lane == 0) Mout[gw] = mx - sm * (1.0f / 1024.0f);
}

// ---------------- top-35 indices per (b,h) --------------------------------
__global__ __launch_bounds__(256) void topk_kernel(
    const float* __restrict__ M, int* __restrict__ Mtop)
{
  const int bh  = blockIdx.x;
  const int tid = threadIdx.x;
  __shared__ float vals[L_];
  __shared__ float rv[256];
  __shared__ int   ri[256];
  for (int i = tid; i < L_; i += 256) vals[i] = M[(size_t)bh * L_ + i];
  __syncthreads();
  for (int t = 0; t < U_; ++t) {
    float best = -__builtin_inff();
    int   bi   = L_;
    for (int i = tid; i < L_; i += 256) {
      const float v = vals[i];
      if (v > best) { best = v; bi = i; }
    }
    rv[tid] = best; ri[tid] = bi;
    __syncthreads();
    for (int s = 128; s > 0; s >>= 1) {
      if (tid < s) {
        if (rv[tid+s] > rv[tid] || (rv[tid+s] == rv[tid] && ri[tid+s] < ri[tid])) {
          rv[tid] = rv[tid+s]; ri[tid] = ri[tid+s];
        }
      }
      __syncthreads();
    }
    if (tid == 0) { Mtop[bh * U_ + t] = ri[0]; vals[ri[0]] = -__builtin_inff(); }
    __syncthreads();
  }
}

// ---------------- attention: 3-kernel k-split -----------------------------
// score: grid (64*KS_) x 256thr; thread owns k; P (packed bf16 pairs, 18
// words/k) -> global Pg. Masked rows produce exactly 0 (exp(-inf)).
template<int UBASE, int UCNT>
__device__ __forceinline__ void score_group_g(
    const float* __restrict__ kp, const float* qs, const int* rowsL,
    uint32_t* __restrict__ prow, const int k, const int masked)
{
  float s[UCNT];
#pragma unroll
  for (int ug = 0; ug < UCNT; ++ug) s[ug] = 0.f;
#pragma unroll
  for (int dc = 0; dc < 64; dc += 16) {
    const float4 k0 = *(const float4*)(kp + dc);
    const float4 k1 = *(const float4*)(kp + dc + 4);
    const float4 k2 = *(const float4*)(kp + dc + 8);
    const float4 k3 = *(const float4*)(kp + dc + 12);
#pragma unroll
    for (int ug = 0; ug < UCNT; ++ug) {
      const float4* qp = (const float4*)&qs[(UBASE + ug) * 64 + dc];
      const float4 q0 = qp[0], q1 = qp[1], q2 = qp[2], q3 = qp[3];
      float acc = s[ug];
      acc = fmaf(q0.x, k0.x, acc); acc = fmaf(q0.y, k0.y, acc);
      acc = fmaf(q0.z, k0.z, acc); acc = fmaf(q0.w, k0.w, acc);
      acc = fmaf(q1.x, k1.x, acc); acc = fmaf(q1.y, k1.y, acc);
      acc = fmaf(q1.z, k1.z, acc); acc = fmaf(q1.w, k1.w, acc);
      acc = fmaf(q2.x, k2.x, acc); acc = fmaf(q2.y, k2.y, acc);
      acc = fmaf(q2.z, k2.z, acc); acc = fmaf(q2.w, k2.w, acc);
      acc = fmaf(q3.x, k3.x, acc); acc = fmaf(q3.y, k3.y, acc);
      acc = fmaf(q3.w == q3.w ? q3.w : 0.f, k3.w, acc); // (kept simple below)
      s[ug] = acc;
    }
  }
  // NOTE: the line above must be plain fma; rewritten cleanly:
  (void)0;
#pragma unroll
  for (int ug = 0; ug < UCNT; ++ug) {
    float v = s[ug] * 0.125f;
    if (masked && k > rowsL[UBASE + ug]) v = -__builtin_inff();
    s[ug] = expf(v);
  }
#pragma unroll
  for (int j = 0; j < UCNT / 2; ++j)
    prow[UBASE / 2 + j] = bf16rne(s[2 * j]) | (bf16rne(s[2 * j + 1]) << 16);
  if (UCNT & 1)
    prow[UBASE / 2 + UCNT / 2] = bf16rne(s[UCNT - 1]);
}

// Clean implementation (the template above had a stray edit; use this one).
template<int UBASE, int UCNT>
__device__ __forceinline__ void score_group_clean(
    const float* __restrict__ kp, const float* qs, const int* rowsL,
    uint32_t* __restrict__ prow, const int k, const int masked)
{
  float s[UCNT];
#pragma unroll
  for (int ug = 0; ug < UCNT; ++ug) s[ug] = 0.f;
#pragma unroll
  for (int dc = 0; dc < 64; dc += 16) {
    const float4 k0 = *(const float4*)(kp + dc);
    const float4 k1 = *(const float4*)(kp + dc + 4);
    const float4 k2 = *(const float4*)(kp + dc + 8);
    const float4 k3 = *(const float4*)(kp + dc + 12);
#pragma unroll
    for (int ug = 0; ug < UCNT; ++ug) {
      const float4* qp = (const float4*)&qs[(UBASE + ug) * 64 + dc];
      const float4 q0 = qp[0], q1 = qp[1], q2 = qp[2], q3 = qp[3];
      float acc = s[ug];
      acc = fmaf(q0.x, k0.x, acc); acc = fmaf(q0.y, k0.y, acc);
      acc = fmaf(q0.z, k0.z, acc); acc = fmaf(q0.w, k0.w, acc);
      acc = fmaf(q1.x, k1.x, acc); acc = fmaf(q1.y, k1.y, acc);
      acc = fmaf(q1.z, k1.z, acc); acc = fmaf(q1.w, k1.w, acc);
      acc = fmaf(q2.x, k2.x, acc); acc = fmaf(q2.y, k2.y, acc);
      acc = fmaf(q2.z, k2.z, acc); acc = fmaf(q2.w, k2.w, acc);
      acc = fmaf(q3.x, k3.x, acc); acc = fmaf(q3.y, k3.y, acc);
      acc = fmaf(q3.z, k3.z, acc); acc = fmaf(q3.w, k3.w, acc);
      s[ug] = acc;
    }
  }
#pragma unroll
  for (int ug = 0; ug < UCNT; ++ug) {
    float v = s[ug] * 0.125f;
    if (masked && k > rowsL[UBASE + ug]) v = -__builtin_inff();
    s[ug] = expf(v);
  }
#pragma unroll
  for (int j = 0; j < UCNT / 2; ++j)
    prow[UBASE / 2 + j] = bf16rne(s[2 * j]) | (bf16rne(s[2 * j + 1]) << 16);
  if (UCNT & 1)
    prow[UBASE / 2 + UCNT / 2] = bf16rne(s[UCNT - 1]);
}

__global__ __launch_bounds__(256) void attn_score(
    const float* __restrict__ Q, const float* __restrict__ K,
    const int* __restrict__ Mtop, uint32_t* __restrict__ Pg, int masked)
{
  __shared__ float qs[U_ * DH_];
  __shared__ int   rowsL[U_ + 1];
  const int bh = blockIdx.x >> 2, ks = blockIdx.x & 3;
  const int h = bh & (H_ - 1), b = bh >> 4;
  const int tid = threadIdx.x;
  const size_t kvbase = (size_t)(b * L_) * DM_ + h * DH_;

  if (tid < U_) rowsL[tid] = Mtop[bh * U_ + tid];
  __syncthreads();
  for (int i = tid; i < U_ * DH_; i += 256)
    qs[i] = Q[kvbase + (size_t)rowsL[i >> 6] * DM_ + (i & 63)];
  __syncthreads();

  const int k = ks * 256 + tid;
  const float* kp = K + kvbase + (size_t)k * DM_;
  uint32_t* prow = Pg + (size_t)bh * (L_ * 18) + (size_t)k * 18;
  score_group_clean<0, 12>(kp, qs, rowsL, prow, k, masked);
  score_group_clean<12, 12>(kp, qs, rowsL, prow, k, masked);
  score_group_clean<24, 11>(kp, qs, rowsL, prow, k, masked);
}

// pv: grid (64*KS_) x 256thr (4 waves). Wave wid owns u = wid+4j (j<9).
// Word index (wid>>1)+2j, hi-half iff wid&1 (wave-uniform) -> broadcast LDS
// reads. Partial O and denominators over this block's 256-k range.
__global__ __launch_bounds__(256) void attn_pv(
    const float* __restrict__ V, const uint32_t* __restrict__ Pg,
    float* __restrict__ Opart, float* __restrict__ Dpart)
{
  __shared__ uint32_t Pl[256 * 18];    // 18 KB
  const int bh = blockIdx.x >> 2, ks = blockIdx.x & 3;
  const int h = bh & (H_ - 1), b = bh >> 4;
  const int tid = threadIdx.x, lane = tid & 63, wid = tid >> 6;
  const size_t kvbase = (size_t)(b * L_) * DM_ + h * DH_;

  const uint32_t* ps = Pg + (size_t)bh * (L_ * 18) + (size_t)(ks * 256) * 18;
  for (int i = tid; i < 256 * 18; i += 256) Pl[i] = ps[i];
  __syncthreads();

  float acc[9], dd[9];
#pragma unroll
  for (int j = 0; j < 9; ++j) { acc[j] = 0.f; dd[j] = 0.f; }

  const float* vp = V + kvbase + (size_t)(ks * 256) * DM_ + lane;
  const int widh = wid >> 1;
  const int hi   = wid & 1;
#pragma unroll 4
  for (int kk = 0; kk < 256; ++kk) {
    const float v0 = vp[(size_t)kk * DM_];
    const uint32_t* pr = &Pl[kk * 18];
#pragma unroll
    for (int j = 0; j < 9; ++j) {
      if (wid + 4 * j < U_) {
        const uint32_t w = pr[widh + 2 * j];
        const float p = hi ? bitsf32(w & 0xFFFF0000u) : bitsf32(w << 16);
        acc[j] = fmaf(p, v0, acc[j]);
        dd[j] += p;
      }
    }
  }
  const int pb = (ks * 64 + bh) * U_;
#pragma unroll
  for (int j = 0; j < 9; ++j) {
    const int u = wid + 4 * j;
    if (u < U_) {
      Opart[(size_t)(pb + u) * 64 + lane] = acc[j];
      if (lane == 0) Dpart[pb + u] = dd[j];
    }
  }
}

// reduce: grid 2240 x 64thr. O = sum_ks Opart / sum_ks Dpart.
__global__ void attn_reduce(const float* __restrict__ Opart,
                            const float* __restrict__ Dpart,
                            float* __restrict__ ctx_rows)
{
  const int bhu = blockIdx.x;            // bh*U_ + u
  const int bh = bhu / U_, u = bhu % U_;
  const int lane = threadIdx.x;
  float o = 0.f, dd = 0.f;
#pragma unroll
  for (int ks = 0; ks < KS_; ++ks) {
    o  += Opart[(size_t)((ks * 64 + bh) * U_ + u) * 64 + lane];
    dd += Dpart[(ks * 64 + bh) * U_ + u];
  }
  ctx_rows[(size_t)bhu * 64 + lane] = o / dd;
}

// ---------------- cumsum / vmean / fill / scatter -------------------------
__global__ __launch_bounds__(256) void cumsum_kernel(
    const float* __restrict__ V, float* __restrict__ C)
{
  const int bh = blockIdx.x;
  const int h = bh & (H_ - 1), b = bh >> 4;
  const int d = threadIdx.x & 63, qq = threadIdx.x >> 6;
  __shared__ float chs[4][DH_];
  const size_t base = (size_t)b * L_ * DM_ + h * DH_ + d;
  float acc = 0.f;
  const int l0 = qq * 256;
  for (int l = l0; l < l0 + 256; ++l) acc += V[base + (size_t)l * DM_];
  chs[qq][d] = acc;
  __syncthreads();
  float off = 0.f;
  for (int j = 0; j < qq; ++j) off += chs[j][d];
  acc = off;
  for (int l = l0; l < l0 + 256; ++l) {
    acc += V[base + (size_t)l * DM_];
    C[base + (size_t)l * DM_] = acc;
  }
}

__global__ __launch_bounds__(256) void vmean_kernel(
    const float* __restrict__ V, float* __restrict__ vm)
{
  const int bh = blockIdx.x;
  const int h = bh & (H_ - 1), b = bh >> 4;
  const int d = threadIdx.x & 63, qq = threadIdx.x >> 6;
  __shared__ float chs[4][DH_];
  const size_t base = (size_t)b * L_ * DM_ + h * DH_ + d;
  float acc = 0.f;
  for (int l = qq * 256; l < qq * 256 + 256; ++l) acc += V[base + (size_t)l * DM_];
  chs[qq][d] = acc;
  __syncthreads();
  if (qq == 0)
    vm[bh * DH_ + d] = (chs[0][d] + chs[1][d] + chs[2][d] + chs[3][d]) * (1.0f / 1024.0f);
}

__global__ void fill_kernel(const float* __restrict__ vm, float* __restrict__ C)
{
  const size_t i = (size_t)blockIdx.x * 256 + threadIdx.x;
  const int d = (int)(i & 63);
  const int h = (int)((i >> 6) & (H_ - 1));
  const int b = (int)(i >> 20);
  C[i] = vm[(b * H_ + h) * DH_ + d];
}

__global__ void scatter_kernel(const float* __restrict__ ctx_rows,
                               const int* __restrict__ Mtop, float* __restrict__ C)
{
  const int bhu = blockIdx.x;
  const int u  = bhu % U_;
  const int bh = bhu / U_;
  const int h = bh & (H_ - 1), b = bh >> 4;
  const int row = Mtop[bh * U_ + u];
  C[(size_t)(b * L_ + row) * DM_ + h * DH_ + threadIdx.x] =
      ctx_rows[(size_t)bhu * DH_ + threadIdx.x];
}

// ---------------- LayerNorm(xa + xb), optional limb outputs ---------------
__global__ __launch_bounds__(256) void ln_kernel(
    const float* __restrict__ xa, const float* __restrict__ xb,
    const float* __restrict__ g, const float* __restrict__ bt,
    float* __restrict__ out, short* __restrict__ oh,
    short* __restrict__ om, short* __restrict__ ol)
{
  const int row = blockIdx.x;
  const int tid = threadIdx.x;
  __shared__ float v[DM_];
  __shared__ float red[256];
  float s = 0.f;
  for (int i = tid; i < DM_; i += 256) {
    const float t = xa[(size_t)row * DM_ + i] + xb[(size_t)row * DM_ + i];
    v[i] = t; s += t;
  }
  red[tid] = s; __syncthreads();
  for (int st = 128; st > 0; st >>= 1) { if (tid < st) red[tid] += red[tid+st]; __syncthreads(); }
  const float mean = red[0] * (1.0f / DM_);
  __syncthreads();
  float s2 = 0.f;
  for (int i = tid; i < DM_; i += 256) { const float dd = v[i] - mean; s2 += dd * dd; }
  red[tid] = s2; __syncthreads();
  for (int st = 128; st > 0; st >>= 1) { if (tid < st) red[tid] += red[tid+st]; __syncthreads(); }
  const float rstd = rsqrtf(red[0] * (1.0f / DM_) + 1e-5f);
  __syncthreads();
  for (int i = tid; i < DM_; i += 256) {
    const size_t idx = (size_t)row * DM_ + i;
    const float o = (v[i] - mean) * rstd * g[i] + bt[i];
    out[idx] = o;
    if (oh) {
      const uint32_t h = bf16rne(o);
      oh[idx] = (short)h;
      if (om) {
        const float r = o - bf16tof(h);
        const uint32_t m = bf16rne(r);
        om[idx] = (short)m;
        ol[idx] = (short)bf16rne(r - bf16tof(m));
      }
    }
  }
}

// ---------------- host orchestration --------------------------------------
extern "C" void kernel_launch(void* const* d_in, const int* in_sizes, int n_in,
                              void* d_out, int out_size, void* d_ws, size_t ws_size,
                              hipStream_t stream)
{
  (void)in_sizes; (void)n_in; (void)out_size; (void)ws_size;
  const float* x    = (const float*)d_in[0];
  const float* enc  = (const float*)d_in[1];
  const float* saWq = (const float*)d_in[2];  const float* sabq = (const float*)d_in[3];
  const float* saWk = (const float*)d_in[4];  const float* sabk = (const float*)d_in[5];
  const float* saWv = (const float*)d_in[6];  const float* sabv = (const float*)d_in[7];
  const float* saWo = (const float*)d_in[8];  const float* sabo = (const float*)d_in[9];
  const float* caWq = (const float*)d_in[10]; const float* cabq = (const float*)d_in[11];
  const float* caWk = (const float*)d_in[12]; const float* cabk = (const float*)d_in[13];
  const float* caWv = (const float*)d_in[14]; const float* cabv = (const float*)d_in[15];
  const float* caWo = (const float*)d_in[16]; const float* cabo = (const float*)d_in[17];
  const float* fW1  = (const float*)d_in[18]; const float* fb1  = (const float*)d_in[19];
  const float* fW2  = (const float*)d_in[20]; const float* fb2  = (const float*)d_in[21];
  const float* l1g  = (const float*)d_in[22]; const float* l1b  = (const float*)d_in[23];
  const float* l2g  = (const float*)d_in[24]; const float* l2b  = (const float*)d_in[25];
  const float* l3g  = (const float*)d_in[26]; const float* l3b  = (const float*)d_in[27];

  float* ws = (float*)d_ws;
  const size_t SL = (size_t)MROWS_ * DM_;       // 4M floats
  float* bufQ = ws;
  float* bufK = ws + SL;
  float* bufV = ws + 2 * SL;
  float* bufC = ws + 3 * SL;
  float* xcur = ws + 4 * SL;
  float* tmp  = ws + 5 * SL;
  float* smallp = ws + 6 * SL;
  int*   idxb = (int*)smallp;
  float* Mbuf = smallp + 36864;
  int*   Mtop = (int*)(smallp + 36864 + 65536);
  float* ctxr = smallp + 36864 + 65536 + 2304;
  float* vm   = ctxr + 143360;

  // attention scratch overlaid on bufC (dead until cumsum/fill):
  uint32_t* Pg    = (uint32_t*)bufC;                 // 64*1024*18 = 1,179,648 u32
  float*    Opart = bufC + 1179648;                  // KS_*64*35*64 = 573,440 f32
  float*    Dpart = Opart + (size_t)KS_ * 64 * U_ * 64;  // KS_*64*35 = 8,960 f32

  const size_t M1 = 1024u * 1024u;              // shorts per 1024^2 limb
  short* wreg = (short*)(ws + 6 * SL + 262144); // 8M shorts (16 MB)
  short* areg = wreg + 8 * M1;                  // 24M shorts (48 MB)
  short* Wqh = wreg;          short* Wqm = wreg + 1*M1; short* Wql = wreg + 2*M1;
  short* Wkh = wreg + 3*M1;   short* Wkm = wreg + 4*M1; short* Wkl = wreg + 5*M1;
  short* Wvh = wreg + 6*M1;   short* Woh = wreg + 7*M1;
  short* f1h = wreg;          short* f2h = wreg + 4*M1;
  short* xh = areg;           short* xm = areg + 4*M1;  short* xl = areg + 8*M1;
  short* eh = areg + 12*M1;   short* em = areg + 16*M1; short* el = areg + 20*M1;
  short* bCh = areg + 12*M1;
  short* hidh = (short*)bufQ;

  // --- JAX partitionable-threefry key ladder (verified round 3) ---
  uint32_t k1a, k1b, k2a, k2b;
  tf2x32(0u, 42u, 0u, 0u, k1a, k1b);
  tf2x32(0u, 42u, 0u, 1u, k2a, k2b);
  uint32_t kb1a, kb1b, kb2a, kb2b;
  tf2x32(k1a, k1b, 0u, 1u, kb1a, kb1b);
  tf2x32(k2a, k2b, 0u, 1u, kb2a, kb2b);

  const dim3 thr(256);
  const int gIdx = (IDXN_ + 255) / 256;
  const int n8 = (int)(SL / 8);
  const dim3 gT(16, 16);

  // ============ self attention (masked) ============
  tsplit_kernel<3><<<gT, thr, 0, stream>>>(saWq, Wqh, Wqm, Wql, DM_, DM_);
  tsplit_kernel<3><<<gT, thr, 0, stream>>>(saWk, Wkh, Wkm, Wkl, DM_, DM_);
  tsplit_kernel<1><<<gT, thr, 0, stream>>>(saWv, Wvh, nullptr, nullptr, DM_, DM_);
  tsplit_kernel<1><<<gT, thr, 0, stream>>>(saWo, Woh, nullptr, nullptr, DM_, DM_);
  rsplit_kernel<3><<<n8 / 256, thr, 0, stream>>>(x, xh, xm, xl, n8);
  {
    Jobs J = {};
    J.j[0] = { {{xh,Wqh},{xh,Wqm},{xm,Wqh},{xm,Wqm},{xh,Wql},{xl,Wqh}}, 6, sabq, bufQ, nullptr, 0 };
    J.j[1] = { {{xh,Wkh},{xh,Wkm},{xm,Wkh},{xm,Wkm},{xh,Wkl},{xl,Wkh}}, 6, sabk, bufK, nullptr, 0 };
    J.j[2] = { {{xh,Wvh},{nullptr,nullptr},{nullptr,nullptr},{nullptr,nullptr},{nullptr,nullptr},{nullptr,nullptr}}, 1, sabv, bufV, nullptr, 0 };
    gemm_seg<<<dim3(8, 32, 3), thr, 0, stream>>>(J, DM_, DM_);
  }
  idx_kernel<<<gIdx, thr, 0, stream>>>(kb1a, kb1b, idxb);
  qks_m_kernel<<<(B_ * H_ * L_) / 4, thr, 0, stream>>>(bufQ, bufK, idxb, Mbuf);
  topk_kernel<<<B_ * H_, thr, 0, stream>>>(Mbuf, Mtop);
  attn_score<<<B_ * H_ * KS_, thr, 0, stream>>>(bufQ, bufK, Mtop, Pg, 1);
  attn_pv<<<B_ * H_ * KS_, thr, 0, stream>>>(bufV, Pg, Opart, Dpart);
  attn_reduce<<<B_ * H_ * U_, dim3(64), 0, stream>>>(Opart, Dpart, ctxr);
  cumsum_kernel<<<B_ * H_, thr, 0, stream>>>(bufV, bufC);
  scatter_kernel<<<B_ * H_ * U_, dim3(64), 0, stream>>>(ctxr, Mtop, bufC);
  rsplit_kernel<1><<<n8 / 256, thr, 0, stream>>>(bufC, bCh, nullptr, nullptr, n8);
  {
    Jobs J = {};
    J.j[0] = { {{bCh,Woh},{nullptr,nullptr},{nullptr,nullptr},{nullptr,nullptr},{nullptr,nullptr},{nullptr,nullptr}}, 1, sabo, tmp, nullptr, 0 };
    gemm_seg<<<dim3(8, 32, 1), thr, 0, stream>>>(J, DM_, DM_);
  }
  ln_kernel<<<MROWS_, thr, 0, stream>>>(x, tmp, l1g, l1b, xcur, xh, xm, xl);

  // ============ cross attention (unmasked) ============
  tsplit_kernel<3><<<gT, thr, 0, stream>>>(caWq, Wqh, Wqm, Wql, DM_, DM_);
  tsplit_kernel<3><<<gT, thr, 0, stream>>>(caWk, Wkh, Wkm, Wkl, DM_, DM_);
  tsplit_kernel<1><<<gT, thr, 0, stream>>>(caWv, Wvh, nullptr, nullptr, DM_, DM_);
  tsplit_kernel<1><<<gT, thr, 0, stream>>>(caWo, Woh, nullptr, nullptr, DM_, DM_);
  rsplit_kernel<3><<<n8 / 256, thr, 0, stream>>>(enc, eh, em, el, n8);
  {
    Jobs J = {};
    J.j[0] = { {{xh,Wqh},{xh,Wqm},{xm,Wqh},{xm,Wqm},{xh,Wql},{xl,Wqh}}, 6, cabq, bufQ, nullptr, 0 };
    J.j[1] = { {{eh,Wkh},{eh,Wkm},{em,Wkh},{em,Wkm},{eh,Wkl},{el,Wkh}}, 6, cabk, bufK, nullptr, 0 };
    J.j[2] = { {{eh,Wvh},{nullptr,nullptr},{nullptr,nullptr},{nullptr,nullptr},{nullptr,nullptr},{nullptr,nullptr}}, 1, cabv, bufV, nullptr, 0 };
    gemm_seg<<<dim3(8, 32, 3), thr, 0, stream>>>(J, DM_, DM_);
  }
  idx_kernel<<<gIdx, thr, 0, stream>>>(kb2a, kb2b, idxb);
  qks_m_kernel<<<(B_ * H_ * L_) / 4, thr, 0, stream>>>(bufQ, bufK, idxb, Mbuf);
  topk_kernel<<<B_ * H_, thr, 0, stream>>>(Mbuf, Mtop);
  attn_score<<<B_ * H_ * KS_, thr, 0, stream>>>(bufQ, bufK, Mtop, Pg, 0);
  attn_pv<<<B_ * H_ * KS_, thr, 0, stream>>>(bufV, Pg, Opart, Dpart);
  attn_reduce<<<B_ * H_ * U_, dim3(64), 0, stream>>>(Opart, Dpart, ctxr);
  vmean_kernel<<<B_ * H_, thr, 0, stream>>>(bufV, vm);
  fill_kernel<<<(int)(SL / 256), thr, 0, stream>>>(vm, bufC);
  scatter_kernel<<<B_ * H_ * U_, dim3(64), 0, stream>>>(ctxr, Mtop, bufC);
  rsplit_kernel<1><<<n8 / 256, thr, 0, stream>>>(bufC, bCh, nullptr, nullptr, n8);
  {
    Jobs J = {};
    J.j[0] = { {{bCh,Woh},{nullptr,nullptr},{nullptr,nullptr},{nullptr,nullptr},{nullptr,nullptr},{nullptr,nullptr}}, 1, cabo, tmp, nullptr, 0 };
    gemm_seg<<<dim3(8, 32, 1), thr, 0, stream>>>(J, DM_, DM_);
  }
  ln_kernel<<<MROWS_, thr, 0, stream>>>(xcur, tmp, l2g, l2b, xcur, xh, nullptr, nullptr);

  // ============ FFN ============
  tsplit_kernel<1><<<dim3(64, 16), thr, 0, stream>>>(fW1, f1h, nullptr, nullptr, DM_, FF_);
  tsplit_kernel<1><<<dim3(16, 64), thr, 0, stream>>>(fW2, f2h, nullptr, nullptr, FF_, DM_);
  {
    Jobs J = {};
    J.j[0] = { {{xh,f1h},{nullptr,nullptr},{nullptr,nullptr},{nullptr,nullptr},{nullptr,nullptr},{nullptr,nullptr}}, 1, fb1, nullptr, hidh, 1 };
    gemm_seg<<<dim3(32, 32, 1), thr, 0, stream>>>(J, DM_, FF_);
  }
  {
    Jobs J = {};
    J.j[0] = { {{hidh,f2h},{nullptr,nullptr},{nullptr,nullptr},{nullptr,nullptr},{nullptr,nullptr},{nullptr,nullptr}}, 1, fb2, tmp, nullptr, 0 };
    gemm_seg<<<dim3(8, 32, 1), thr, 0, stream>>>(J, FF_, DM_);
  }
  ln_kernel<<<MROWS_, thr, 0, stream>>>(xcur, tmp, l3g, l3b, (float*)d_out,
                                        nullptr, nullptr, nullptr);
}

// Round 16
// 1174.736 us; speedup vs baseline: 2.9781x; 1.0777x over previous
//
#include <hip/hip_runtime.h>
#include <cstdint>
#include <cstddef>

// Informer ProbSparse decoder layer.
// GEMMs: split-once bf16 limbs + FUSED multi-limb bf16 GEMM (global_load_lds,
// per-K-step staging of all limbs; 6 pairings share staged tiles). XOR chunk
// swizzle (src-side, rule #21) kills the 8-way ds_read bank conflict; XCD
// swizzle for L2 locality. Q/K: 6 pairings (~f32); V/O/FFN: 1 (rne bf16).
// Attention: 3-kernel k-split (round-13 verified).
#define B_     4
#define L_     1024
#define DM_    1024
#define H_     16
#define DH_    64
#define U_     35
#define FF_    4096
#define MROWS_ 4096
#define IDXN_  35840
#define KS_    4

typedef __attribute__((ext_vector_type(8))) short bf16x8;
typedef __attribute__((ext_vector_type(4))) float f32x4;

// ---------------- Threefry-2x32-20 (exact JAX semantics) ----------------
__host__ __device__ inline void tf2x32(uint32_t k0, uint32_t k1,
                                       uint32_t x0, uint32_t x1,
                                       uint32_t& y0, uint32_t& y1) {
  const uint32_t ks2 = k0 ^ k1 ^ 0x1BD11BDAu;
  uint32_t v0 = x0 + k0, v1 = x1 + k1;
#define ROTL_(x,d) (((x)<<(d))|((x)>>(32-(d))))
#define RND_(r) { v0 += v1; v1 = ROTL_(v1,(r)); v1 ^= v0; }
  RND_(13) RND_(15) RND_(26) RND_(6)   v0 += k1;  v1 += ks2 + 1u;
  RND_(17) RND_(29) RND_(16) RND_(24)  v0 += ks2; v1 += k0  + 2u;
  RND_(13) RND_(15) RND_(26) RND_(6)   v0 += k0;  v1 += k1  + 3u;
  RND_(17) RND_(29) RND_(16) RND_(24)  v0 += k1;  v1 += ks2 + 4u;
  RND_(13) RND_(15) RND_(26) RND_(6)   v0 += ks2; v1 += k0  + 5u;
#undef RND_
#undef ROTL_
  y0 = v0; y1 = v1;
}

__global__ void idx_kernel(uint32_t k0, uint32_t k1, int* __restrict__ idx) {
  const int i = blockIdx.x * 256 + threadIdx.x;
  if (i >= IDXN_) return;
  uint32_t y0, y1;
  tf2x32(k0, k1, 0u, (uint32_t)i, y0, y1);
  idx[i] = (int)((y0 ^ y1) & 1023u);
}

// ---------------- bf16 helpers --------------------------------------------
__device__ __forceinline__ uint32_t f32bits(float x) {
  union { float f; uint32_t u; } c; c.f = x; return c.u;
}
__device__ __forceinline__ float bitsf32(uint32_t u) {
  union { uint32_t u; float f; } c; c.u = u; return c.f;
}
__device__ __forceinline__ uint32_t bf16rne(float x) {
  const uint32_t u = f32bits(x);
  return (u + 0x7FFFu + ((u >> 16) & 1u)) >> 16;
}
__device__ __forceinline__ float bf16tof(uint32_t h) { return bitsf32(h << 16); }

__device__ __forceinline__ void split3(float x, uint32_t& h, uint32_t& m, uint32_t& l) {
  h = bf16rne(x); const float r  = x - bf16tof(h);
  m = bf16rne(r); const float r2 = r - bf16tof(m);
  l = bf16rne(r2);
}

// ---------------- async global -> LDS (16B per lane) ----------------------
__device__ __forceinline__ void gload16(const void* g, void* l) {
  __builtin_amdgcn_global_load_lds(
      (const __attribute__((address_space(1))) void*)g,
      (__attribute__((address_space(3))) void*)l, 16, 0, 0);
}

// ---------------- transpose-split: W (KxN f32) -> W^T limbs (NxK bf16) ----
template<int LIMBS>
__global__ __launch_bounds__(256) void tsplit_kernel(
    const float* __restrict__ W, short* __restrict__ Th,
    short* __restrict__ Tm, short* __restrict__ Tl, int K, int N)
{
  __shared__ float tile[64][65];
  const int n0 = blockIdx.x * 64, k0 = blockIdx.y * 64;
  const int t = threadIdx.x;
  const int r = t >> 2, c0 = (t & 3) * 16;
  const float* src = W + (size_t)(k0 + r) * N + n0 + c0;
  const float4 v0 = *(const float4*)src;
  const float4 v1 = *(const float4*)(src + 4);
  const float4 v2 = *(const float4*)(src + 8);
  const float4 v3 = *(const float4*)(src + 12);
  float* tr = &tile[r][c0];
  tr[0]=v0.x; tr[1]=v0.y; tr[2]=v0.z; tr[3]=v0.w;
  tr[4]=v1.x; tr[5]=v1.y; tr[6]=v1.z; tr[7]=v1.w;
  tr[8]=v2.x; tr[9]=v2.y; tr[10]=v2.z; tr[11]=v2.w;
  tr[12]=v3.x; tr[13]=v3.y; tr[14]=v3.z; tr[15]=v3.w;
  __syncthreads();
  uint32_t ph[8], pm[8], pl[8];
#pragma unroll
  for (int j = 0; j < 16; j += 2) {
    uint32_t h0,m0,l0,h1,m1,l1;
    split3(tile[c0 + j][r], h0, m0, l0);
    split3(tile[c0 + j + 1][r], h1, m1, l1);
    ph[j>>1] = h0 | (h1 << 16);
    pm[j>>1] = m0 | (m1 << 16);
    pl[j>>1] = l0 | (l1 << 16);
  }
  const size_t ob = (size_t)(n0 + r) * K + k0 + c0;
  *(uint4*)(Th + ob)     = make_uint4(ph[0], ph[1], ph[2], ph[3]);
  *(uint4*)(Th + ob + 8) = make_uint4(ph[4], ph[5], ph[6], ph[7]);
  if (LIMBS == 3) {
    *(uint4*)(Tm + ob)     = make_uint4(pm[0], pm[1], pm[2], pm[3]);
    *(uint4*)(Tm + ob + 8) = make_uint4(pm[4], pm[5], pm[6], pm[7]);
    *(uint4*)(Tl + ob)     = make_uint4(pl[0], pl[1], pl[2], pl[3]);
    *(uint4*)(Tl + ob + 8) = make_uint4(pl[4], pl[5], pl[6], pl[7]);
  }
}

// ---------------- row split: X (f32) -> limbs (bf16), elementwise ---------
template<int LIMBS>
__global__ void rsplit_kernel(const float* __restrict__ X, short* __restrict__ Th,
                              short* __restrict__ Tm, short* __restrict__ Tl, int n8)
{
  const int i = blockIdx.x * 256 + threadIdx.x;
  if (i >= n8) return;
  const float4 a = ((const float4*)X)[2*i], b = ((const float4*)X)[2*i+1];
  const float v[8] = {a.x,a.y,a.z,a.w,b.x,b.y,b.z,b.w};
  uint32_t ph[4], pm[4], pl[4];
#pragma unroll
  for (int j = 0; j < 4; ++j) {
    uint32_t h0,m0,l0,h1,m1,l1;
    split3(v[2*j], h0, m0, l0);
    split3(v[2*j+1], h1, m1, l1);
    ph[j] = h0 | (h1 << 16); pm[j] = m0 | (m1 << 16); pl[j] = l0 | (l1 << 16);
  }
  ((uint4*)Th)[i] = make_uint4(ph[0], ph[1], ph[2], ph[3]);
  if (LIMBS == 3) {
    ((uint4*)Tm)[i] = make_uint4(pm[0], pm[1], pm[2], pm[3]);
    ((uint4*)Tl)[i] = make_uint4(pl[0], pl[1], pl[2], pl[3]);
  }
}

// ---------------- fused multi-limb bf16 GEMM ------------------------------
// C = sum over pairings A_a (MxK) @ B_b^T (NxK) + bias.
// NL=3: pairings (0,0)(0,1)(1,0)(1,1)(0,2)(2,0) — the 6-term limb product.
// NL=1: single pairing. 128x128 tile, BK=32, 4 waves, global_load_lds w16.
// LDS tiles [128][32] bf16 with chunk swizzle c ^= (r+(r>>2))&3 applied to
// the per-lane GLOBAL source (LDS dest linear, rule #21) and to ds_read.
struct FJob {
  const short* A[3];
  const short* B[3];
  const float* bias;
  float* C;       // nullable
  short* Ch;      // nullable: rne-bf16 of output
  int relu;
};
struct FJobs { FJob j[3]; };

template<int NL>
__global__ __launch_bounds__(256, 2) void gemm_fused(FJobs jobs, int K, int N)
{
  __shared__ short As[NL][4096] __attribute__((aligned(16)));
  __shared__ short Bs[NL][4096] __attribute__((aligned(16)));
  const int z = blockIdx.z;
  // XCD-aware bijective swizzle (nwg multiple of 8 in all our grids)
  const int nwg  = gridDim.x * gridDim.y;
  const int flat = blockIdx.y * gridDim.x + blockIdx.x;
  const int swz  = (flat & 7) * (nwg >> 3) + (flat >> 3);
  const int bn = (swz % gridDim.x) * 128;
  const int bm = (swz / gridDim.x) * 128;

  const int t = threadIdx.x, lane = t & 63;
  const int wid = t >> 6, wr = wid >> 1, wc = wid & 1;
  const int l15 = lane & 15, kg = lane >> 4;
  const int srow = t >> 2;                                   // 0..63
  const int sc   = ((t & 3) ^ ((srow + (srow >> 2)) & 3)) * 8; // swizzled src chunk (shorts); g(r)==g(r+64)

  int aoff[4], boff[4];   // ds_read offsets (shorts), swizzled
#pragma unroll
  for (int m = 0; m < 4; ++m) {
    const int ra = wr * 64 + m * 16 + l15;
    aoff[m] = ra * 32 + ((kg ^ ((ra + (ra >> 2)) & 3)) << 3);
    const int rb = wc * 64 + m * 16 + l15;
    boff[m] = rb * 32 + ((kg ^ ((rb + (rb >> 2)) & 3)) << 3);
  }

  f32x4 acc[4][4];
#pragma unroll
  for (int m = 0; m < 4; ++m)
#pragma unroll
    for (int n = 0; n < 4; ++n) acc[m][n] = (f32x4){0.f,0.f,0.f,0.f};

  const size_t aofs0 = (size_t)(bm + srow) * K + sc;
  const size_t bofs0 = (size_t)(bn + srow) * K + sc;
  const size_t half  = (size_t)64 * K;

  for (int kk = 0; kk < K; kk += 32) {
    __syncthreads();                        // LDS reuse guard
#pragma unroll
    for (int l = 0; l < NL; ++l) {
      gload16(jobs.j[z].A[l] + aofs0 + kk,        &As[l][t * 8]);
      gload16(jobs.j[z].A[l] + aofs0 + half + kk, &As[l][2048 + t * 8]);
      gload16(jobs.j[z].B[l] + bofs0 + kk,        &Bs[l][t * 8]);
      gload16(jobs.j[z].B[l] + bofs0 + half + kk, &Bs[l][2048 + t * 8]);
    }
    __syncthreads();                        // drains vmcnt before reads
    if (NL == 1) {
      bf16x8 a[4], b[4];
#pragma unroll
      for (int m = 0; m < 4; ++m) a[m] = *(const bf16x8*)&As[0][aoff[m]];
#pragma unroll
      for (int n = 0; n < 4; ++n) b[n] = *(const bf16x8*)&Bs[0][boff[n]];
#pragma unroll
      for (int m = 0; m < 4; ++m)
#pragma unroll
        for (int n = 0; n < 4; ++n)
          acc[m][n] = __builtin_amdgcn_mfma_f32_16x16x32_bf16(a[m], b[n], acc[m][n], 0, 0, 0);
    } else {
      bf16x8 a0[4], a1[4], a2[4], b[4];
#pragma unroll
      for (int m = 0; m < 4; ++m) {
        a0[m] = *(const bf16x8*)&As[0][aoff[m]];
        a1[m] = *(const bf16x8*)&As[1][aoff[m]];
        a2[m] = *(const bf16x8*)&As[2][aoff[m]];
      }
      // B limb h: pairs (h,h),(m,h),(l,h)
#pragma unroll
      for (int n = 0; n < 4; ++n) b[n] = *(const bf16x8*)&Bs[0][boff[n]];
#pragma unroll
      for (int m = 0; m < 4; ++m)
#pragma unroll
        for (int n = 0; n < 4; ++n) {
          acc[m][n] = __builtin_amdgcn_mfma_f32_16x16x32_bf16(a0[m], b[n], acc[m][n], 0, 0, 0);
          acc[m][n] = __builtin_amdgcn_mfma_f32_16x16x32_bf16(a1[m], b[n], acc[m][n], 0, 0, 0);
          acc[m][n] = __builtin_amdgcn_mfma_f32_16x16x32_bf16(a2[m], b[n], acc[m][n], 0, 0, 0);
        }
      // B limb m: pairs (h,m),(m,m)
#pragma unroll
      for (int n = 0; n < 4; ++n) b[n] = *(const bf16x8*)&Bs[1][boff[n]];
#pragma unroll
      for (int m = 0; m < 4; ++m)
#pragma unroll
        for (int n = 0; n < 4; ++n) {
          acc[m][n] = __builtin_amdgcn_mfma_f32_16x16x32_bf16(a0[m], b[n], acc[m][n], 0, 0, 0);
          acc[m][n] = __builtin_amdgcn_mfma_f32_16x16x32_bf16(a1[m], b[n], acc[m][n], 0, 0, 0);
        }
      // B limb l: pair (h,l)
#pragma unroll
      for (int n = 0; n < 4; ++n) b[n] = *(const bf16x8*)&Bs[2][boff[n]];
#pragma unroll
      for (int m = 0; m < 4; ++m)
#pragma unroll
        for (int n = 0; n < 4; ++n)
          acc[m][n] = __builtin_amdgcn_mfma_f32_16x16x32_bf16(a0[m], b[n], acc[m][n], 0, 0, 0);
    }
  }

  const float* bias = jobs.j[z].bias;
  float* C  = jobs.j[z].C;
  short* Ch = jobs.j[z].Ch;
  const int relu = jobs.j[z].relu;
  float bv[4];
#pragma unroll
  for (int n = 0; n < 4; ++n) bv[n] = bias[bn + wc*64 + n*16 + l15];
#pragma unroll
  for (int m = 0; m < 4; ++m) {
    const int row0 = bm + wr*64 + m*16 + kg*4;
#pragma unroll
    for (int n = 0; n < 4; ++n) {
      const int col = bn + wc*64 + n*16 + l15;
#pragma unroll
      for (int q = 0; q < 4; ++q) {
        float o = acc[m][n][q] + bv[n];
        if (relu) o = fmaxf(o, 0.f);
        const size_t off = (size_t)(row0 + q) * N + col;
        if (C)  C[off]  = o;
        if (Ch) Ch[off] = (short)bf16rne(o);
      }
    }
  }
}

// ---------------- sampled QK^T -> M scores (round-11 verified) ------------
__global__ __launch_bounds__(256) void qks_m_kernel(
    const float* __restrict__ Q, const float* __restrict__ K,
    const int* __restrict__ idx, float* __restrict__ Mout)
{
  const int gw   = blockIdx.x * 4 + (threadIdx.x >> 6);
  const int lane = threadIdx.x & 63;
  const int l  = gw & (L_ - 1);
  const int bh = gw >> 10;
  const int h  = bh & (H_ - 1);
  const int b  = bh >> 4;
  const size_t base = (size_t)(b * L_) * DM_ + h * DH_ + lane;
  const float q = Q[base + (size_t)l * DM_];
  const int* ip = idx + l * U_;

  float kv[U_];
#pragma unroll
  for (int s = 0; s < U_; ++s) {
    const int ks = __builtin_amdgcn_readfirstlane(ip[s]);
    kv[s] = K[base + (size_t)ks * DM_];
  }
  float ksum = 0.f;
#pragma unroll
  for (int s = 0; s < U_; ++s) ksum += kv[s];

  float sm = q * ksum;
#pragma unroll
  for (int off = 32; off > 0; off >>= 1) sm += __shfl_xor(sm, off, 64);

  float mx = -__builtin_inff();
#pragma unroll
  for (int s = 0; s < U_; ++s) {
    float p = q * kv[s];
#pragma unroll
    for (int off = 32; off > 0; off >>= 1) p += __shfl_xor(p, off, 64);
    mx = fmaxf(mx, p);
  }
  if (lane == 0) Mout[gw] = mx - sm * (1.0f / 1024.0f);
}

// ---------------- top-35 indices per (b,h) --------------------------------
__global__ __launch_bounds__(256) void topk_kernel(
    const float* __restrict__ M, int* __restrict__ Mtop)
{
  const int bh  = blockIdx.x;
  const int tid = threadIdx.x;
  __shared__ float vals[L_];
  __shared__ float rv[256];
  __shared__ int   ri[256];
  for (int i = tid; i < L_; i += 256) vals[i] = M[(size_t)bh * L_ + i];
  __syncthreads();
  for (int t = 0; t < U_; ++t) {
    float best = -__builtin_inff();
    int   bi   = L_;
    for (int i = tid; i < L_; i += 256) {
      const float v = vals[i];
      if (v > best) { best = v; bi = i; }
    }
    rv[tid] = best; ri[tid] = bi;
    __syncthreads();
    for (int s = 128; s > 0; s >>= 1) {
      if (tid < s) {
        if (rv[tid+s] > rv[tid] || (rv[tid+s] == rv[tid] && ri[tid+s] < ri[tid])) {
          rv[tid] = rv[tid+s]; ri[tid] = ri[tid+s];
        }
      }
      __syncthreads();
    }
    if (tid == 0) { Mtop[bh * U_ + t] = ri[0]; vals[ri[0]] = -__builtin_inff(); }
    __syncthreads();
  }
}

// ---------------- attention: 3-kernel k-split (round-13 verified) ---------
template<int UBASE, int UCNT>
__device__ __forceinline__ void score_group(
    const float* __restrict__ kp, const float* qs, const int* rowsL,
    uint32_t* __restrict__ prow, const int k, const int masked)
{
  float s[UCNT];
#pragma unroll
  for (int ug = 0; ug < UCNT; ++ug) s[ug] = 0.f;
#pragma unroll
  for (int dc = 0; dc < 64; dc += 16) {
    const float4 k0 = *(const float4*)(kp + dc);
    const float4 k1 = *(const float4*)(kp + dc + 4);
    const float4 k2 = *(const float4*)(kp + dc + 8);
    const float4 k3 = *(const float4*)(kp + dc + 12);
#pragma unroll
    for (int ug = 0; ug < UCNT; ++ug) {
      const float4* qp = (const float4*)&qs[(UBASE + ug) * 64 + dc];
      const float4 q0 = qp[0], q1 = qp[1], q2 = qp[2], q3 = qp[3];
      float acc = s[ug];
      acc = fmaf(q0.x, k0.x, acc); acc = fmaf(q0.y, k0.y, acc);
      acc = fmaf(q0.z, k0.z, acc); acc = fmaf(q0.w, k0.w, acc);
      acc = fmaf(q1.x, k1.x, acc); acc = fmaf(q1.y, k1.y, acc);
      acc = fmaf(q1.z, k1.z, acc); acc = fmaf(q1.w, k1.w, acc);
      acc = fmaf(q2.x, k2.x, acc); acc = fmaf(q2.y, k2.y, acc);
      acc = fmaf(q2.z, k2.z, acc); acc = fmaf(q2.w, k2.w, acc);
      acc = fmaf(q3.x, k3.x, acc); acc = fmaf(q3.y, k3.y, acc);
      acc = fmaf(q3.z, k3.z, acc); acc = fmaf(q3.w, k3.w, acc);
      s[ug] = acc;
    }
  }
#pragma unroll
  for (int ug = 0; ug < UCNT; ++ug) {
    float v = s[ug] * 0.125f;
    if (masked && k > rowsL[UBASE + ug]) v = -__builtin_inff();
    s[ug] = expf(v);
  }
#pragma unroll
  for (int j = 0; j < UCNT / 2; ++j)
    prow[UBASE / 2 + j] = bf16rne(s[2 * j]) | (bf16rne(s[2 * j + 1]) << 16);
  if (UCNT & 1)
    prow[UBASE / 2 + UCNT / 2] = bf16rne(s[UCNT - 1]);
}

__global__ __launch_bounds__(256) void attn_score(
    const float* __restrict__ Q, const float* __restrict__ K,
    const int* __restrict__ Mtop, uint32_t* __restrict__ Pg, int masked)
{
  __shared__ float qs[U_ * DH_];
  __shared__ int   rowsL[U_ + 1];
  const int bh = blockIdx.x >> 2, ks = blockIdx.x & 3;
  const int h = bh & (H_ - 1), b = bh >> 4;
  const int tid = threadIdx.x;
  const size_t kvbase = (size_t)(b * L_) * DM_ + h * DH_;

  if (tid < U_) rowsL[tid] = Mtop[bh * U_ + tid];
  __syncthreads();
  for (int i = tid; i < U_ * DH_; i += 256)
    qs[i] = Q[kvbase + (size_t)rowsL[i >> 6] * DM_ + (i & 63)];
  __syncthreads();

  const int k = ks * 256 + tid;
  const float* kp = K + kvbase + (size_t)k * DM_;
  uint32_t* prow = Pg + (size_t)bh * (L_ * 18) + (size_t)k * 18;
  score_group<0, 12>(kp, qs, rowsL, prow, k, masked);
  score_group<12, 12>(kp, qs, rowsL, prow, k, masked);
  score_group<24, 11>(kp, qs, rowsL, prow, k, masked);
}

__global__ __launch_bounds__(256) void attn_pv(
    const float* __restrict__ V, const uint32_t* __restrict__ Pg,
    float* __restrict__ Opart, float* __restrict__ Dpart)
{
  __shared__ uint32_t Pl[256 * 18];
  const int bh = blockIdx.x >> 2, ks = blockIdx.x & 3;
  const int h = bh & (H_ - 1), b = bh >> 4;
  const int tid = threadIdx.x, lane = tid & 63, wid = tid >> 6;
  const size_t kvbase = (size_t)(b * L_) * DM_ + h * DH_;

  const uint32_t* ps = Pg + (size_t)bh * (L_ * 18) + (size_t)(ks * 256) * 18;
  for (int i = tid; i < 256 * 18; i += 256) Pl[i] = ps[i];
  __syncthreads();

  float acc[9], dd[9];
#pragma unroll
  for (int j = 0; j < 9; ++j) { acc[j] = 0.f; dd[j] = 0.f; }

  const float* vp = V + kvbase + (size_t)(ks * 256) * DM_ + lane;
  const int widh = wid >> 1;
  const int hi   = wid & 1;
#pragma unroll 4
  for (int kk = 0; kk < 256; ++kk) {
    const float v0 = vp[(size_t)kk * DM_];
    const uint32_t* pr = &Pl[kk * 18];
#pragma unroll
    for (int j = 0; j < 9; ++j) {
      if (wid + 4 * j < U_) {
        const uint32_t w = pr[widh + 2 * j];
        const float p = hi ? bitsf32(w & 0xFFFF0000u) : bitsf32(w << 16);
        acc[j] = fmaf(p, v0, acc[j]);
        dd[j] += p;
      }
    }
  }
  const int pb = (ks * 64 + bh) * U_;
#pragma unroll
  for (int j = 0; j < 9; ++j) {
    const int u = wid + 4 * j;
    if (u < U_) {
      Opart[(size_t)(pb + u) * 64 + lane] = acc[j];
      if (lane == 0) Dpart[pb + u] = dd[j];
    }
  }
}

__global__ void attn_reduce(const float* __restrict__ Opart,
                            const float* __restrict__ Dpart,
                            float* __restrict__ ctx_rows)
{
  const int bhu = blockIdx.x;
  const int bh = bhu / U_, u = bhu % U_;
  const int lane = threadIdx.x;
  float o = 0.f, dd = 0.f;
#pragma unroll
  for (int ks = 0; ks < KS_; ++ks) {
    o  += Opart[(size_t)((ks * 64 + bh) * U_ + u) * 64 + lane];
    dd += Dpart[(ks * 64 + bh) * U_ + u];
  }
  ctx_rows[(size_t)bhu * 64 + lane] = o / dd;
}

// ---------------- cumsum / vmean / fill / scatter -------------------------
__global__ __launch_bounds__(256) void cumsum_kernel(
    const float* __restrict__ V, float* __restrict__ C)
{
  const int bh = blockIdx.x;
  const int h = bh & (H_ - 1), b = bh >> 4;
  const int d = threadIdx.x & 63, qq = threadIdx.x >> 6;
  __shared__ float chs[4][DH_];
  const size_t base = (size_t)b * L_ * DM_ + h * DH_ + d;
  float acc = 0.f;
  const int l0 = qq * 256;
  for (int l = l0; l < l0 + 256; ++l) acc += V[base + (size_t)l * DM_];
  chs[qq][d] = acc;
  __syncthreads();
  float off = 0.f;
  for (int j = 0; j < qq; ++j) off += chs[j][d];
  acc = off;
  for (int l = l0; l < l0 + 256; ++l) {
    acc += V[base + (size_t)l * DM_];
    C[base + (size_t)l * DM_] = acc;
  }
}

__global__ __launch_bounds__(256) void vmean_kernel(
    const float* __restrict__ V, float* __restrict__ vm)
{
  const int bh = blockIdx.x;
  const int h = bh & (H_ - 1), b = bh >> 4;
  const int d = threadIdx.x & 63, qq = threadIdx.x >> 6;
  __shared__ float chs[4][DH_];
  const size_t base = (size_t)b * L_ * DM_ + h * DH_ + d;
  float acc = 0.f;
  for (int l = qq * 256; l < qq * 256 + 256; ++l) acc += V[base + (size_t)l * DM_];
  chs[qq][d] = acc;
  __syncthreads();
  if (qq == 0)
    vm[bh * DH_ + d] = (chs[0][d] + chs[1][d] + chs[2][d] + chs[3][d]) * (1.0f / 1024.0f);
}

__global__ void fill_kernel(const float* __restrict__ vm, float* __restrict__ C)
{
  const size_t i = (size_t)blockIdx.x * 256 + threadIdx.x;
  const int d = (int)(i & 63);
  const int h = (int)((i >> 6) & (H_ - 1));
  const int b = (int)(i >> 20);
  C[i] = vm[(b * H_ + h) * DH_ + d];
}

__global__ void scatter_kernel(const float* __restrict__ ctx_rows,
                               const int* __restrict__ Mtop, float* __restrict__ C)
{
  const int bhu = blockIdx.x;
  const int u  = bhu % U_;
  const int bh = bhu / U_;
  const int h = bh & (H_ - 1), b = bh >> 4;
  const int row = Mtop[bh * U_ + u];
  C[(size_t)(b * L_ + row) * DM_ + h * DH_ + threadIdx.x] =
      ctx_rows[(size_t)bhu * DH_ + threadIdx.x];
}

// ---------------- LayerNorm(xa + xb), optional limb outputs ---------------
__global__ __launch_bounds__(256) void ln_kernel(
    const float* __restrict__ xa, const float* __restrict__ xb,
    const float* __restrict__ g, const float* __restrict__ bt,
    float* __restrict__ out, short* __restrict__ oh,
    short* __restrict__ om, short* __restrict__ ol)
{
  const int row = blockIdx.x;
  const int tid = threadIdx.x;
  __shared__ float v[DM_];
  __shared__ float red[256];
  float s = 0.f;
  for (int i = tid; i < DM_; i += 256) {
    const float t = xa[(size_t)row * DM_ + i] + xb[(size_t)row * DM_ + i];
    v[i] = t; s += t;
  }
  red[tid] = s; __syncthreads();
  for (int st = 128; st > 0; st >>= 1) { if (tid < st) red[tid] += red[tid+st]; __syncthreads(); }
  const float mean = red[0] * (1.0f / DM_);
  __syncthreads();
  float s2 = 0.f;
  for (int i = tid; i < DM_; i += 256) { const float dd = v[i] - mean; s2 += dd * dd; }
  red[tid] = s2; __syncthreads();
  for (int st = 128; st > 0; st >>= 1) { if (tid < st) red[tid] += red[tid+st]; __syncthreads(); }
  const float rstd = rsqrtf(red[0] * (1.0f / DM_) + 1e-5f);
  __syncthreads();
  for (int i = tid; i < DM_; i += 256) {
    const size_t idx = (size_t)row * DM_ + i;
    const float o = (v[i] - mean) * rstd * g[i] + bt[i];
    out[idx] = o;
    if (oh) {
      const uint32_t h = bf16rne(o);
      oh[idx] = (short)h;
      if (om) {
        const float r = o - bf16tof(h);
        const uint32_t m = bf16rne(r);
        om[idx] = (short)m;
        ol[idx] = (short)bf16rne(r - bf16tof(m));
      }
    }
  }
}

// ---------------- host orchestration --------------------------------------
extern "C" void kernel_launch(void* const* d_in, const int* in_sizes, int n_in,
                              void* d_out, int out_size, void* d_ws, size_t ws_size,
                              hipStream_t stream)
{
  (void)in_sizes; (void)n_in; (void)out_size; (void)ws_size;
  const float* x    = (const float*)d_in[0];
  const float* enc  = (const float*)d_in[1];
  const float* saWq = (const float*)d_in[2];  const float* sabq = (const float*)d_in[3];
  const float* saWk = (const float*)d_in[4];  const float* sabk = (const float*)d_in[5];
  const float* saWv = (const float*)d_in[6];  const float* sabv = (const float*)d_in[7];
  const float* saWo = (const float*)d_in[8];  const float* sabo = (const float*)d_in[9];
  const float* caWq = (const float*)d_in[10]; const float* cabq = (const float*)d_in[11];
  const float* caWk = (const float*)d_in[12]; const float* cabk = (const float*)d_in[13];
  const float* caWv = (const float*)d_in[14]; const float* cabv = (const float*)d_in[15];
  const float* caWo = (const float*)d_in[16]; const float* cabo = (const float*)d_in[17];
  const float* fW1  = (const float*)d_in[18]; const float* fb1  = (const float*)d_in[19];
  const float* fW2  = (const float*)d_in[20]; const float* fb2  = (const float*)d_in[21];
  const float* l1g  = (const float*)d_in[22]; const float* l1b  = (const float*)d_in[23];
  const float* l2g  = (const float*)d_in[24]; const float* l2b  = (const float*)d_in[25];
  const float* l3g  = (const float*)d_in[26]; const float* l3b  = (const float*)d_in[27];

  float* ws = (float*)d_ws;
  const size_t SL = (size_t)MROWS_ * DM_;       // 4M floats
  float* bufQ = ws;
  float* bufK = ws + SL;
  float* bufV = ws + 2 * SL;
  float* bufC = ws + 3 * SL;
  float* xcur = ws + 4 * SL;
  float* tmp  = ws + 5 * SL;
  float* smallp = ws + 6 * SL;
  int*   idxb = (int*)smallp;
  float* Mbuf = smallp + 36864;
  int*   Mtop = (int*)(smallp + 36864 + 65536);
  float* ctxr = smallp + 36864 + 65536 + 2304;
  float* vm   = ctxr + 143360;

  // attention scratch overlaid on bufC (dead until cumsum/fill):
  uint32_t* Pg    = (uint32_t*)bufC;
  float*    Opart = bufC + 1179648;
  float*    Dpart = Opart + (size_t)KS_ * 64 * U_ * 64;

  const size_t M1 = 1024u * 1024u;
  short* wreg = (short*)(ws + 6 * SL + 262144);
  short* areg = wreg + 8 * M1;
  short* Wqh = wreg;          short* Wqm = wreg + 1*M1; short* Wql = wreg + 2*M1;
  short* Wkh = wreg + 3*M1;   short* Wkm = wreg + 4*M1; short* Wkl = wreg + 5*M1;
  short* Wvh = wreg + 6*M1;   short* Woh = wreg + 7*M1;
  short* f1h = wreg;          short* f2h = wreg + 4*M1;
  short* xh = areg;           short* xm = areg + 4*M1;  short* xl = areg + 8*M1;
  short* eh = areg + 12*M1;   short* em = areg + 16*M1; short* el = areg + 20*M1;
  short* bCh = areg + 12*M1;
  short* hidh = (short*)bufQ;

  // --- JAX partitionable-threefry key ladder (verified round 3) ---
  uint32_t k1a, k1b, k2a, k2b;
  tf2x32(0u, 42u, 0u, 0u, k1a, k1b);
  tf2x32(0u, 42u, 0u, 1u, k2a, k2b);
  uint32_t kb1a, kb1b, kb2a, kb2b;
  tf2x32(k1a, k1b, 0u, 1u, kb1a, kb1b);
  tf2x32(k2a, k2b, 0u, 1u, kb2a, kb2b);

  const dim3 thr(256);
  const int gIdx = (IDXN_ + 255) / 256;
  const int n8 = (int)(SL / 8);
  const dim3 gT(16, 16);

  // ============ self attention (masked) ============
  tsplit_kernel<3><<<gT, thr, 0, stream>>>(saWq, Wqh, Wqm, Wql, DM_, DM_);
  tsplit_kernel<3><<<gT, thr, 0, stream>>>(saWk, Wkh, Wkm, Wkl, DM_, DM_);
  tsplit_kernel<1><<<gT, thr, 0, stream>>>(saWv, Wvh, nullptr, nullptr, DM_, DM_);
  tsplit_kernel<1><<<gT, thr, 0, stream>>>(saWo, Woh, nullptr, nullptr, DM_, DM_);
  rsplit_kernel<3><<<n8 / 256, thr, 0, stream>>>(x, xh, xm, xl, n8);
  {
    FJobs J = {};
    J.j[0] = { {xh, xm, xl}, {Wqh, Wqm, Wql}, sabq, bufQ, nullptr, 0 };
    J.j[1] = { {xh, xm, xl}, {Wkh, Wkm, Wkl}, sabk, bufK, nullptr, 0 };
    gemm_fused<3><<<dim3(8, 32, 2), thr, 0, stream>>>(J, DM_, DM_);
  }
  {
    FJobs J = {};
    J.j[0] = { {xh, nullptr, nullptr}, {Wvh, nullptr, nullptr}, sabv, bufV, nullptr, 0 };
    gemm_fused<1><<<dim3(8, 32, 1), thr, 0, stream>>>(J, DM_, DM_);
  }
  idx_kernel<<<gIdx, thr, 0, stream>>>(kb1a, kb1b, idxb);
  qks_m_kernel<<<(B_ * H_ * L_) / 4, thr, 0, stream>>>(bufQ, bufK, idxb, Mbuf);
  topk_kernel<<<B_ * H_, thr, 0, stream>>>(Mbuf, Mtop);
  attn_score<<<B_ * H_ * KS_, thr, 0, stream>>>(bufQ, bufK, Mtop, Pg, 1);
  attn_pv<<<B_ * H_ * KS_, thr, 0, stream>>>(bufV, Pg, Opart, Dpart);
  attn_reduce<<<B_ * H_ * U_, dim3(64), 0, stream>>>(Opart, Dpart, ctxr);
  cumsum_kernel<<<B_ * H_, thr, 0, stream>>>(bufV, bufC);
  scatter_kernel<<<B_ * H_ * U_, dim3(64), 0, stream>>>(ctxr, Mtop, bufC);
  rsplit_kernel<1><<<n8 / 256, thr, 0, stream>>>(bufC, bCh, nullptr, nullptr, n8);
  {
    FJobs J = {};
    J.j[0] = { {bCh, nullptr, nullptr}, {Woh, nullptr, nullptr}, sabo, tmp, nullptr, 0 };
    gemm_fused<1><<<dim3(8, 32, 1), thr, 0, stream>>>(J, DM_, DM_);
  }
  ln_kernel<<<MROWS_, thr, 0, stream>>>(x, tmp, l1g, l1b, xcur, xh, xm, xl);

  // ============ cross attention (unmasked) ============
  tsplit_kernel<3><<<gT, thr, 0, stream>>>(caWq, Wqh, Wqm, Wql, DM_, DM_);
  tsplit_kernel<3><<<gT, thr, 0, stream>>>(caWk, Wkh, Wkm, Wkl, DM_, DM_);
  tsplit_kernel<1><<<gT, thr, 0, stream>>>(caWv, Wvh, nullptr, nullptr, DM_, DM_);
  tsplit_kernel<1><<<gT, thr, 0, stream>>>(caWo, Woh, nullptr, nullptr, DM_, DM_);
  rsplit_kernel<3><<<n8 / 256, thr, 0, stream>>>(enc, eh, em, el, n8);
  {
    FJobs J = {};
    J.j[0] = { {xh, xm, xl}, {Wqh, Wqm, Wql}, cabq, bufQ, nullptr, 0 };
    J.j[1] = { {eh, em, el}, {Wkh, Wkm, Wkl}, cabk, bufK, nullptr, 0 };
    gemm_fused<3><<<dim3(8, 32, 2), thr, 0, stream>>>(J, DM_, DM_);
  }
  {
    FJobs J = {};
    J.j[0] = { {eh, nullptr, nullptr}, {Wvh, nullptr, nullptr}, cabv, bufV, nullptr, 0 };
    gemm_fused<1><<<dim3(8, 32, 1), thr, 0, stream>>>(J, DM_, DM_);
  }
  idx_kernel<<<gIdx, thr, 0, stream>>>(kb2a, kb2b, idxb);
  qks_m_kernel<<<(B_ * H_ * L_) / 4, thr, 0, stream>>>(bufQ, bufK, idxb, Mbuf);
  topk_kernel<<<B_ * H_, thr, 0, stream>>>(Mbuf, Mtop);
  attn_score<<<B_ * H_ * KS_, thr, 0, stream>>>(bufQ, bufK, Mtop, Pg, 0);
  attn_pv<<<B_ * H_ * KS_, thr, 0, stream>>>(bufV, Pg, Opart, Dpart);
  attn_reduce<<<B_ * H_ * U_, dim3(64), 0, stream>>>(Opart, Dpart, ctxr);
  vmean_kernel<<<B_ * H_, thr, 0, stream>>>(bufV, vm);
  fill_kernel<<<(int)(SL / 256), thr, 0, stream>>>(vm, bufC);
  scatter_kernel<<<B_ * H_ * U_, dim3(64), 0, stream>>>(ctxr, Mtop, bufC);
  rsplit_kernel<1><<<n8 / 256, thr, 0, stream>>>(bufC, bCh, nullptr, nullptr, n8);
  {
    FJobs J = {};
    J.j[0] = { {bCh, nullptr, nullptr}, {Woh, nullptr, nullptr}, cabo, tmp, nullptr, 0 };
    gemm_fused<1><<<dim3(8, 32, 1), thr, 0, stream>>>(J, DM_, DM_);
  }
  ln_kernel<<<MROWS_, thr, 0, stream>>>(xcur, tmp, l2g, l2b, xcur, xh, nullptr, nullptr);

  // ============ FFN ============
  tsplit_kernel<1><<<dim3(64, 16), thr, 0, stream>>>(fW1, f1h, nullptr, nullptr, DM_, FF_);
  tsplit_kernel<1><<<dim3(16, 64), thr, 0, stream>>>(fW2, f2h, nullptr, nullptr, FF_, DM_);
  {
    FJobs J = {};
    J.j[0] = { {xh, nullptr, nullptr}, {f1h, nullptr, nullptr}, fb1, nullptr, hidh, 1 };
    gemm_fused<1><<<dim3(32, 32, 1), thr, 0, stream>>>(J, DM_, FF_);
  }
  {
    FJobs J = {};
    J.j[0] = { {hidh, nullptr, nullptr}, {f2h, nullptr, nullptr}, fb2, tmp, nullptr, 0 };
    gemm_fused<1><<<dim3(8, 32, 1), thr, 0, stream>>>(J, FF_, DM_);
  }
  ln_kernel<<<MROWS_, thr, 0, stream>>>(xcur, tmp, l3g, l3b, (float*)d_out,
                                        nullptr, nullptr, nullptr);
}

// Round 17
// 1173.838 us; speedup vs baseline: 2.9804x; 1.0008x over previous
//
#include <hip/hip_runtime.h>
#include <cstdint>
#include <cstddef>

// Informer ProbSparse decoder layer.
// GEMMs: split-once bf16 limbs + FUSED multi-limb bf16 GEMM (global_load_lds,
// per-K-step staging of all limbs; 6 pairings share staged tiles). XOR chunk
// swizzle (src-side, rule #21) kills the 8-way ds_read bank conflict; XCD
// swizzle for L2 locality. Q/K: 6 pairings (~f32); V/O/FFN: 1 (rne bf16).
// Attention: 3-kernel k-split. qks_m: XCD-affinity block remap (round-17).
#define B_     4
#define L_     1024
#define DM_    1024
#define H_     16
#define DH_    64
#define U_     35
#define FF_    4096
#define MROWS_ 4096
#define IDXN_  35840
#define KS_    4

typedef __attribute__((ext_vector_type(8))) short bf16x8;
typedef __attribute__((ext_vector_type(4))) float f32x4;

// ---------------- Threefry-2x32-20 (exact JAX semantics) ----------------
__host__ __device__ inline void tf2x32(uint32_t k0, uint32_t k1,
                                       uint32_t x0, uint32_t x1,
                                       uint32_t& y0, uint32_t& y1) {
  const uint32_t ks2 = k0 ^ k1 ^ 0x1BD11BDAu;
  uint32_t v0 = x0 + k0, v1 = x1 + k1;
#define ROTL_(x,d) (((x)<<(d))|((x)>>(32-(d))))
#define RND_(r) { v0 += v1; v1 = ROTL_(v1,(r)); v1 ^= v0; }
  RND_(13) RND_(15) RND_(26) RND_(6)   v0 += k1;  v1 += ks2 + 1u;
  RND_(17) RND_(29) RND_(16) RND_(24)  v0 += ks2; v1 += k0  + 2u;
  RND_(13) RND_(15) RND_(26) RND_(6)   v0 += k0;  v1 += k1  + 3u;
  RND_(17) RND_(29) RND_(16) RND_(24)  v0 += k1;  v1 += ks2 + 4u;
  RND_(13) RND_(15) RND_(26) RND_(6)   v0 += ks2; v1 += k0  + 5u;
#undef RND_
#undef ROTL_
  y0 = v0; y1 = v1;
}

__global__ void idx_kernel(uint32_t k0, uint32_t k1, int* __restrict__ idx) {
  const int i = blockIdx.x * 256 + threadIdx.x;
  if (i >= IDXN_) return;
  uint32_t y0, y1;
  tf2x32(k0, k1, 0u, (uint32_t)i, y0, y1);
  idx[i] = (int)((y0 ^ y1) & 1023u);
}

// ---------------- bf16 helpers --------------------------------------------
__device__ __forceinline__ uint32_t f32bits(float x) {
  union { float f; uint32_t u; } c; c.f = x; return c.u;
}
__device__ __forceinline__ float bitsf32(uint32_t u) {
  union { uint32_t u; float f; } c; c.u = u; return c.f;
}
__device__ __forceinline__ uint32_t bf16rne(float x) {
  const uint32_t u = f32bits(x);
  return (u + 0x7FFFu + ((u >> 16) & 1u)) >> 16;
}
__device__ __forceinline__ float bf16tof(uint32_t h) { return bitsf32(h << 16); }

__device__ __forceinline__ void split3(float x, uint32_t& h, uint32_t& m, uint32_t& l) {
  h = bf16rne(x); const float r  = x - bf16tof(h);
  m = bf16rne(r); const float r2 = r - bf16tof(m);
  l = bf16rne(r2);
}

// ---------------- async global -> LDS (16B per lane) ----------------------
__device__ __forceinline__ void gload16(const void* g, void* l) {
  __builtin_amdgcn_global_load_lds(
      (const __attribute__((address_space(1))) void*)g,
      (__attribute__((address_space(3))) void*)l, 16, 0, 0);
}

// ---------------- transpose-split: W (KxN f32) -> W^T limbs (NxK bf16) ----
template<int LIMBS>
__global__ __launch_bounds__(256) void tsplit_kernel(
    const float* __restrict__ W, short* __restrict__ Th,
    short* __restrict__ Tm, short* __restrict__ Tl, int K, int N)
{
  __shared__ float tile[64][65];
  const int n0 = blockIdx.x * 64, k0 = blockIdx.y * 64;
  const int t = threadIdx.x;
  const int r = t >> 2, c0 = (t & 3) * 16;
  const float* src = W + (size_t)(k0 + r) * N + n0 + c0;
  const float4 v0 = *(const float4*)src;
  const float4 v1 = *(const float4*)(src + 4);
  const float4 v2 = *(const float4*)(src + 8);
  const float4 v3 = *(const float4*)(src + 12);
  float* tr = &tile[r][c0];
  tr[0]=v0.x; tr[1]=v0.y; tr[2]=v0.z; tr[3]=v0.w;
  tr[4]=v1.x; tr[5]=v1.y; tr[6]=v1.z; tr[7]=v1.w;
  tr[8]=v2.x; tr[9]=v2.y; tr[10]=v2.z; tr[11]=v2.w;
  tr[12]=v3.x; tr[13]=v3.y; tr[14]=v3.z; tr[15]=v3.w;
  __syncthreads();
  uint32_t ph[8], pm[8], pl[8];
#pragma unroll
  for (int j = 0; j < 16; j += 2) {
    uint32_t h0,m0,l0,h1,m1,l1;
    split3(tile[c0 + j][r], h0, m0, l0);
    split3(tile[c0 + j + 1][r], h1, m1, l1);
    ph[j>>1] = h0 | (h1 << 16);
    pm[j>>1] = m0 | (m1 << 16);
    pl[j>>1] = l0 | (l1 << 16);
  }
  const size_t ob = (size_t)(n0 + r) * K + k0 + c0;
  *(uint4*)(Th + ob)     = make_uint4(ph[0], ph[1], ph[2], ph[3]);
  *(uint4*)(Th + ob + 8) = make_uint4(ph[4], ph[5], ph[6], ph[7]);
  if (LIMBS == 3) {
    *(uint4*)(Tm + ob)     = make_uint4(pm[0], pm[1], pm[2], pm[3]);
    *(uint4*)(Tm + ob + 8) = make_uint4(pm[4], pm[5], pm[6], pm[7]);
    *(uint4*)(Tl + ob)     = make_uint4(pl[0], pl[1], pl[2], pl[3]);
    *(uint4*)(Tl + ob + 8) = make_uint4(pl[4], pl[5], pl[6], pl[7]);
  }
}

// ---------------- row split: X (f32) -> limbs (bf16), elementwise ---------
template<int LIMBS>
__global__ void rsplit_kernel(const float* __restrict__ X, short* __restrict__ Th,
                              short* __restrict__ Tm, short* __restrict__ Tl, int n8)
{
  const int i = blockIdx.x * 256 + threadIdx.x;
  if (i >= n8) return;
  const float4 a = ((const float4*)X)[2*i], b = ((const float4*)X)[2*i+1];
  const float v[8] = {a.x,a.y,a.z,a.w,b.x,b.y,b.z,b.w};
  uint32_t ph[4], pm[4], pl[4];
#pragma unroll
  for (int j = 0; j < 4; ++j) {
    uint32_t h0,m0,l0,h1,m1,l1;
    split3(v[2*j], h0, m0, l0);
    split3(v[2*j+1], h1, m1, l1);
    ph[j] = h0 | (h1 << 16); pm[j] = m0 | (m1 << 16); pl[j] = l0 | (l1 << 16);
  }
  ((uint4*)Th)[i] = make_uint4(ph[0], ph[1], ph[2], ph[3]);
  if (LIMBS == 3) {
    ((uint4*)Tm)[i] = make_uint4(pm[0], pm[1], pm[2], pm[3]);
    ((uint4*)Tl)[i] = make_uint4(pl[0], pl[1], pl[2], pl[3]);
  }
}

// ---------------- fused multi-limb bf16 GEMM (round-16 verified) ----------
struct FJob {
  const short* A[3];
  const short* B[3];
  const float* bias;
  float* C;       // nullable
  short* Ch;      // nullable: rne-bf16 of output
  int relu;
};
struct FJobs { FJob j[3]; };

template<int NL>
__global__ __launch_bounds__(256, 2) void gemm_fused(FJobs jobs, int K, int N)
{
  __shared__ short As[NL][4096] __attribute__((aligned(16)));
  __shared__ short Bs[NL][4096] __attribute__((aligned(16)));
  const int z = blockIdx.z;
  const int nwg  = gridDim.x * gridDim.y;
  const int flat = blockIdx.y * gridDim.x + blockIdx.x;
  const int swz  = (flat & 7) * (nwg >> 3) + (flat >> 3);
  const int bn = (swz % gridDim.x) * 128;
  const int bm = (swz / gridDim.x) * 128;

  const int t = threadIdx.x, lane = t & 63;
  const int wid = t >> 6, wr = wid >> 1, wc = wid & 1;
  const int l15 = lane & 15, kg = lane >> 4;
  const int srow = t >> 2;
  const int sc   = ((t & 3) ^ ((srow + (srow >> 2)) & 3)) * 8;

  int aoff[4], boff[4];
#pragma unroll
  for (int m = 0; m < 4; ++m) {
    const int ra = wr * 64 + m * 16 + l15;
    aoff[m] = ra * 32 + ((kg ^ ((ra + (ra >> 2)) & 3)) << 3);
    const int rb = wc * 64 + m * 16 + l15;
    boff[m] = rb * 32 + ((kg ^ ((rb + (rb >> 2)) & 3)) << 3);
  }

  f32x4 acc[4][4];
#pragma unroll
  for (int m = 0; m < 4; ++m)
#pragma unroll
    for (int n = 0; n < 4; ++n) acc[m][n] = (f32x4){0.f,0.f,0.f,0.f};

  const size_t aofs0 = (size_t)(bm + srow) * K + sc;
  const size_t bofs0 = (size_t)(bn + srow) * K + sc;
  const size_t half  = (size_t)64 * K;

  for (int kk = 0; kk < K; kk += 32) {
    __syncthreads();
#pragma unroll
    for (int l = 0; l < NL; ++l) {
      gload16(jobs.j[z].A[l] + aofs0 + kk,        &As[l][t * 8]);
      gload16(jobs.j[z].A[l] + aofs0 + half + kk, &As[l][2048 + t * 8]);
      gload16(jobs.j[z].B[l] + bofs0 + kk,        &Bs[l][t * 8]);
      gload16(jobs.j[z].B[l] + bofs0 + half + kk, &Bs[l][2048 + t * 8]);
    }
    __syncthreads();
    if (NL == 1) {
      bf16x8 a[4], b[4];
#pragma unroll
      for (int m = 0; m < 4; ++m) a[m] = *(const bf16x8*)&As[0][aoff[m]];
#pragma unroll
      for (int n = 0; n < 4; ++n) b[n] = *(const bf16x8*)&Bs[0][boff[n]];
#pragma unroll
      for (int m = 0; m < 4; ++m)
#pragma unroll
        for (int n = 0; n < 4; ++n)
          acc[m][n] = __builtin_amdgcn_mfma_f32_16x16x32_bf16(a[m], b[n], acc[m][n], 0, 0, 0);
    } else {
      bf16x8 a0[4], a1[4], a2[4], b[4];
#pragma unroll
      for (int m = 0; m < 4; ++m) {
        a0[m] = *(const bf16x8*)&As[0][aoff[m]];
        a1[m] = *(const bf16x8*)&As[1][aoff[m]];
        a2[m] = *(const bf16x8*)&As[2][aoff[m]];
      }
#pragma unroll
      for (int n = 0; n < 4; ++n) b[n] = *(const bf16x8*)&Bs[0][boff[n]];
#pragma unroll
      for (int m = 0; m < 4; ++m)
#pragma unroll
        for (int n = 0; n < 4; ++n) {
          acc[m][n] = __builtin_amdgcn_mfma_f32_16x16x32_bf16(a0[m], b[n], acc[m][n], 0, 0, 0);
          acc[m][n] = __builtin_amdgcn_mfma_f32_16x16x32_bf16(a1[m], b[n], acc[m][n], 0, 0, 0);
          acc[m][n] = __builtin_amdgcn_mfma_f32_16x16x32_bf16(a2[m], b[n], acc[m][n], 0, 0, 0);
        }
#pragma unroll
      for (int n = 0; n < 4; ++n) b[n] = *(const bf16x8*)&Bs[1][boff[n]];
#pragma unroll
      for (int m = 0; m < 4; ++m)
#pragma unroll
        for (int n = 0; n < 4; ++n) {
          acc[m][n] = __builtin_amdgcn_mfma_f32_16x16x32_bf16(a0[m], b[n], acc[m][n], 0, 0, 0);
          acc[m][n] = __builtin_amdgcn_mfma_f32_16x16x32_bf16(a1[m], b[n], acc[m][n], 0, 0, 0);
        }
#pragma unroll
      for (int n = 0; n < 4; ++n) b[n] = *(const bf16x8*)&Bs[2][boff[n]];
#pragma unroll
      for (int m = 0; m < 4; ++m)
#pragma unroll
        for (int n = 0; n < 4; ++n)
          acc[m][n] = __builtin_amdgcn_mfma_f32_16x16x32_bf16(a0[m], b[n], acc[m][n], 0, 0, 0);
    }
  }

  const float* bias = jobs.j[z].bias;
  float* C  = jobs.j[z].C;
  short* Ch = jobs.j[z].Ch;
  const int relu = jobs.j[z].relu;
  float bv[4];
#pragma unroll
  for (int n = 0; n < 4; ++n) bv[n] = bias[bn + wc*64 + n*16 + l15];
#pragma unroll
  for (int m = 0; m < 4; ++m) {
    const int row0 = bm + wr*64 + m*16 + kg*4;
#pragma unroll
    for (int n = 0; n < 4; ++n) {
      const int col = bn + wc*64 + n*16 + l15;
#pragma unroll
      for (int q = 0; q < 4; ++q) {
        float o = acc[m][n][q] + bv[n];
        if (relu) o = fmaxf(o, 0.f);
        const size_t off = (size_t)(row0 + q) * N + col;
        if (C)  C[off]  = o;
        if (Ch) Ch[off] = (short)bf16rne(o);
      }
    }
  }
}

// ---------------- sampled QK^T -> M scores --------------------------------
// Round-16 post-mortem: 155us, FETCH 73MB @485GB/s -> HBM-fetch-bound.
// Cause: blocks of one (b,h) round-robin across all 8 XCDs; each XCD's
// private L2 re-fetches the (b,h) K-slice from HBM (no cross-XCD sharing).
// Fix: bijective remap pinning all 256 blocks of group g to XCD g%8
// (dispatch maps block i -> XCD i%8): g=(p&7)+(p>>11)*8, j=(p&2047)>>3.
// Per XCD: 8 groups x (256KB K + 256KB Q) = 4MB ~= its L2.
__global__ __launch_bounds__(256) void qks_m_kernel(
    const float* __restrict__ Q, const float* __restrict__ K,
    const int* __restrict__ idx, float* __restrict__ Mout)
{
  const int p = blockIdx.x;                       // 0..16383
  const int g = (p & 7) + ((p >> 11) << 3);       // bh group -> XCD g%8
  const int j = (p & 2047) >> 3;                  // block within group, 0..255
  const int l = j * 4 + (threadIdx.x >> 6);
  const int lane = threadIdx.x & 63;
  const int h  = g & (H_ - 1);
  const int b  = g >> 4;
  const size_t base = (size_t)(b * L_) * DM_ + h * DH_ + lane;
  const float q = Q[base + (size_t)l * DM_];
  const int* ip = idx + l * U_;

  float kv[U_];
#pragma unroll
  for (int s = 0; s < U_; ++s) {
    const int ks = __builtin_amdgcn_readfirstlane(ip[s]);
    kv[s] = K[base + (size_t)ks * DM_];
  }
  float ksum = 0.f;
#pragma unroll
  for (int s = 0; s < U_; ++s) ksum += kv[s];

  float sm = q * ksum;
#pragma unroll
  for (int off = 32; off > 0; off >>= 1) sm += __shfl_xor(sm, off, 64);

  float mx = -__builtin_inff();
#pragma unroll
  for (int s = 0; s < U_; ++s) {
    float p2 = q * kv[s];
#pragma unroll
    for (int off = 32; off > 0; off >>= 1) p2 += __shfl_xor(p2, off, 64);
    mx = fmaxf(mx, p2);
  }
  if (lane == 0) Mout[g * L_ + l] = mx - sm * (1.0f / 1024.0f);
}

// ---------------- top-35 indices per (b,h) --------------------------------
__global__ __launch_bounds__(256) void topk_kernel(
    const float* __restrict__ M, int* __restrict__ Mtop)
{
  const int bh  = blockIdx.x;
  const int tid = threadIdx.x;
  __shared__ float vals[L_];
  __shared__ float rv[256];
  __shared__ int   ri[256];
  for (int i = tid; i < L_; i += 256) vals[i] = M[(size_t)bh * L_ + i];
  __syncthreads();
  for (int t = 0; t < U_; ++t) {
    float best = -__builtin_inff();
    int   bi   = L_;
    for (int i = tid; i < L_; i += 256) {
      const float v = vals[i];
      if (v > best) { best = v; bi = i; }
    }
    rv[tid] = best; ri[tid] = bi;
    __syncthreads();
    for (int s = 128; s > 0; s >>= 1) {
      if (tid < s) {
        if (rv[tid+s] > rv[tid] || (rv[tid+s] == rv[tid] && ri[tid+s] < ri[tid])) {
          rv[tid] = rv[tid+s]; ri[tid] = ri[tid+s];
        }
      }
      __syncthreads();
    }
    if (tid == 0) { Mtop[bh * U_ + t] = ri[0]; vals[ri[0]] = -__builtin_inff(); }
    __syncthreads();
  }
}

// ---------------- attention: 3-kernel k-split (round-13 verified) ---------
template<int UBASE, int UCNT>
__device__ __forceinline__ void score_group(
    const float* __restrict__ kp, const float* qs, const int* rowsL,
    uint32_t* __restrict__ prow, const int k, const int masked)
{
  float s[UCNT];
#pragma unroll
  for (int ug = 0; ug < UCNT; ++ug) s[ug] = 0.f;
#pragma unroll
  for (int dc = 0; dc < 64; dc += 16) {
    const float4 k0 = *(const float4*)(kp + dc);
    const float4 k1 = *(const float4*)(kp + dc + 4);
    const float4 k2 = *(const float4*)(kp + dc + 8);
    const float4 k3 = *(const float4*)(kp + dc + 12);
#pragma unroll
    for (int ug = 0; ug < UCNT; ++ug) {
      const float4* qp = (const float4*)&qs[(UBASE + ug) * 64 + dc];
      const float4 q0 = qp[0], q1 = qp[1], q2 = qp[2], q3 = qp[3];
      float acc = s[ug];
      acc = fmaf(q0.x, k0.x, acc); acc = fmaf(q0.y, k0.y, acc);
      acc = fmaf(q0.z, k0.z, acc); acc = fmaf(q0.w, k0.w, acc);
      acc = fmaf(q1.x, k1.x, acc); acc = fmaf(q1.y, k1.y, acc);
      acc = fmaf(q1.z, k1.z, acc); acc = fmaf(q1.w, k1.w, acc);
      acc = fmaf(q2.x, k2.x, acc); acc = fmaf(q2.y, k2.y, acc);
      acc = fmaf(q2.z, k2.z, acc); acc = fmaf(q2.w, k2.w, acc);
      acc = fmaf(q3.x, k3.x, acc); acc = fmaf(q3.y, k3.y, acc);
      acc = fmaf(q3.z, k3.z, acc); acc = fmaf(q3.w, k3.w, acc);
      s[ug] = acc;
    }
  }
#pragma unroll
  for (int ug = 0; ug < UCNT; ++ug) {
    float v = s[ug] * 0.125f;
    if (masked && k > rowsL[UBASE + ug]) v = -__builtin_inff();
    s[ug] = expf(v);
  }
#pragma unroll
  for (int j = 0; j < UCNT / 2; ++j)
    prow[UBASE / 2 + j] = bf16rne(s[2 * j]) | (bf16rne(s[2 * j + 1]) << 16);
  if (UCNT & 1)
    prow[UBASE / 2 + UCNT / 2] = bf16rne(s[UCNT - 1]);
}

__global__ __launch_bounds__(256) void attn_score(
    const float* __restrict__ Q, const float* __restrict__ K,
    const int* __restrict__ Mtop, uint32_t* __restrict__ Pg, int masked)
{
  __shared__ float qs[U_ * DH_];
  __shared__ int   rowsL[U_ + 1];
  const int bh = blockIdx.x >> 2, ks = blockIdx.x & 3;
  const int h = bh & (H_ - 1), b = bh >> 4;
  const int tid = threadIdx.x;
  const size_t kvbase = (size_t)(b * L_) * DM_ + h * DH_;

  if (tid < U_) rowsL[tid] = Mtop[bh * U_ + tid];
  __syncthreads();
  for (int i = tid; i < U_ * DH_; i += 256)
    qs[i] = Q[kvbase + (size_t)rowsL[i >> 6] * DM_ + (i & 63)];
  __syncthreads();

  const int k = ks * 256 + tid;
  const float* kp = K + kvbase + (size_t)k * DM_;
  uint32_t* prow = Pg + (size_t)bh * (L_ * 18) + (size_t)k * 18;
  score_group<0, 12>(kp, qs, rowsL, prow, k, masked);
  score_group<12, 12>(kp, qs, rowsL, prow, k, masked);
  score_group<24, 11>(kp, qs, rowsL, prow, k, masked);
}

__global__ __launch_bounds__(256) void attn_pv(
    const float* __restrict__ V, const uint32_t* __restrict__ Pg,
    float* __restrict__ Opart, float* __restrict__ Dpart)
{
  __shared__ uint32_t Pl[256 * 18];
  const int bh = blockIdx.x >> 2, ks = blockIdx.x & 3;
  const int h = bh & (H_ - 1), b = bh >> 4;
  const int tid = threadIdx.x, lane = tid & 63, wid = tid >> 6;
  const size_t kvbase = (size_t)(b * L_) * DM_ + h * DH_;

  const uint32_t* ps = Pg + (size_t)bh * (L_ * 18) + (size_t)(ks * 256) * 18;
  for (int i = tid; i < 256 * 18; i += 256) Pl[i] = ps[i];
  __syncthreads();

  float acc[9], dd[9];
#pragma unroll
  for (int j = 0; j < 9; ++j) { acc[j] = 0.f; dd[j] = 0.f; }

  const float* vp = V + kvbase + (size_t)(ks * 256) * DM_ + lane;
  const int widh = wid >> 1;
  const int hi   = wid & 1;
#pragma unroll 4
  for (int kk = 0; kk < 256; ++kk) {
    const float v0 = vp[(size_t)kk * DM_];
    const uint32_t* pr = &Pl[kk * 18];
#pragma unroll
    for (int j = 0; j < 9; ++j) {
      if (wid + 4 * j < U_) {
        const uint32_t w = pr[widh + 2 * j];
        const float p = hi ? bitsf32(w & 0xFFFF0000u) : bitsf32(w << 16);
        acc[j] = fmaf(p, v0, acc[j]);
        dd[j] += p;
      }
    }
  }
  const int pb = (ks * 64 + bh) * U_;
#pragma unroll
  for (int j = 0; j < 9; ++j) {
    const int u = wid + 4 * j;
    if (u < U_) {
      Opart[(size_t)(pb + u) * 64 + lane] = acc[j];
      if (lane == 0) Dpart[pb + u] = dd[j];
    }
  }
}

__global__ void attn_reduce(const float* __restrict__ Opart,
                            const float* __restrict__ Dpart,
                            float* __restrict__ ctx_rows)
{
  const int bhu = blockIdx.x;
  const int bh = bhu / U_, u = bhu % U_;
  const int lane = threadIdx.x;
  float o = 0.f, dd = 0.f;
#pragma unroll
  for (int ks = 0; ks < KS_; ++ks) {
    o  += Opart[(size_t)((ks * 64 + bh) * U_ + u) * 64 + lane];
    dd += Dpart[(ks * 64 + bh) * U_ + u];
  }
  ctx_rows[(size_t)bhu * 64 + lane] = o / dd;
}

// ---------------- cumsum / vmean / fill / scatter -------------------------
__global__ __launch_bounds__(256) void cumsum_kernel(
    const float* __restrict__ V, float* __restrict__ C)
{
  const int bh = blockIdx.x;
  const int h = bh & (H_ - 1), b = bh >> 4;
  const int d = threadIdx.x & 63, qq = threadIdx.x >> 6;
  __shared__ float chs[4][DH_];
  const size_t base = (size_t)b * L_ * DM_ + h * DH_ + d;
  float acc = 0.f;
  const int l0 = qq * 256;
  for (int l = l0; l < l0 + 256; ++l) acc += V[base + (size_t)l * DM_];
  chs[qq][d] = acc;
  __syncthreads();
  float off = 0.f;
  for (int j = 0; j < qq; ++j) off += chs[j][d];
  acc = off;
  for (int l = l0; l < l0 + 256; ++l) {
    acc += V[base + (size_t)l * DM_];
    C[base + (size_t)l * DM_] = acc;
  }
}

__global__ __launch_bounds__(256) void vmean_kernel(
    const float* __restrict__ V, float* __restrict__ vm)
{
  const int bh = blockIdx.x;
  const int h = bh & (H_ - 1), b = bh >> 4;
  const int d = threadIdx.x & 63, qq = threadIdx.x >> 6;
  __shared__ float chs[4][DH_];
  const size_t base = (size_t)b * L_ * DM_ + h * DH_ + d;
  float acc = 0.f;
  for (int l = qq * 256; l < qq * 256 + 256; ++l) acc += V[base + (size_t)l * DM_];
  chs[qq][d] = acc;
  __syncthreads();
  if (qq == 0)
    vm[bh * DH_ + d] = (chs[0][d] + chs[1][d] + chs[2][d] + chs[3][d]) * (1.0f / 1024.0f);
}

__global__ void fill_kernel(const float* __restrict__ vm, float* __restrict__ C)
{
  const size_t i = (size_t)blockIdx.x * 256 + threadIdx.x;
  const int d = (int)(i & 63);
  const int h = (int)((i >> 6) & (H_ - 1));
  const int b = (int)(i >> 20);
  C[i] = vm[(b * H_ + h) * DH_ + d];
}

__global__ void scatter_kernel(const float* __restrict__ ctx_rows,
                               const int* __restrict__ Mtop, float* __restrict__ C)
{
  const int bhu = blockIdx.x;
  const int u  = bhu % U_;
  const int bh = bhu / U_;
  const int h = bh & (H_ - 1), b = bh >> 4;
  const int row = Mtop[bh * U_ + u];
  C[(size_t)(b * L_ + row) * DM_ + h * DH_ + threadIdx.x] =
      ctx_rows[(size_t)bhu * DH_ + threadIdx.x];
}

// ---------------- LayerNorm(xa + xb), optional limb outputs ---------------
__global__ __launch_bounds__(256) void ln_kernel(
    const float* __restrict__ xa, const float* __restrict__ xb,
    const float* __restrict__ g, const float* __restrict__ bt,
    float* __restrict__ out, short* __restrict__ oh,
    short* __restrict__ om, short* __restrict__ ol)
{
  const int row = blockIdx.x;
  const int tid = threadIdx.x;
  __shared__ float v[DM_];
  __shared__ float red[256];
  float s = 0.f;
  for (int i = tid; i < DM_; i += 256) {
    const float t = xa[(size_t)row * DM_ + i] + xb[(size_t)row * DM_ + i];
    v[i] = t; s += t;
  }
  red[tid] = s; __syncthreads();
  for (int st = 128; st > 0; st >>= 1) { if (tid < st) red[tid] += red[tid+st]; __syncthreads(); }
  const float mean = red[0] * (1.0f / DM_);
  __syncthreads();
  float s2 = 0.f;
  for (int i = tid; i < DM_; i += 256) { const float dd = v[i] - mean; s2 += dd * dd; }
  red[tid] = s2; __syncthreads();
  for (int st = 128; st > 0; st >>= 1) { if (tid < st) red[tid] += red[tid+st]; __syncthreads(); }
  const float rstd = rsqrtf(red[0] * (1.0f / DM_) + 1e-5f);
  __syncthreads();
  for (int i = tid; i < DM_; i += 256) {
    const size_t idx = (size_t)row * DM_ + i;
    const float o = (v[i] - mean) * rstd * g[i] + bt[i];
    out[idx] = o;
    if (oh) {
      const uint32_t h = bf16rne(o);
      oh[idx] = (short)h;
      if (om) {
        const float r = o - bf16tof(h);
        const uint32_t m = bf16rne(r);
        om[idx] = (short)m;
        ol[idx] = (short)bf16rne(r - bf16tof(m));
      }
    }
  }
}

// ---------------- host orchestration --------------------------------------
extern "C" void kernel_launch(void* const* d_in, const int* in_sizes, int n_in,
                              void* d_out, int out_size, void* d_ws, size_t ws_size,
                              hipStream_t stream)
{
  (void)in_sizes; (void)n_in; (void)out_size; (void)ws_size;
  const float* x    = (const float*)d_in[0];
  const float* enc  = (const float*)d_in[1];
  const float* saWq = (const float*)d_in[2];  const float* sabq = (const float*)d_in[3];
  const float* saWk = (const float*)d_in[4];  const float* sabk = (const float*)d_in[5];
  const float* saWv = (const float*)d_in[6];  const float* sabv = (const float*)d_in[7];
  const float* saWo = (const float*)d_in[8];  const float* sabo = (const float*)d_in[9];
  const float* caWq = (const float*)d_in[10]; const float* cabq = (const float*)d_in[11];
  const float* caWk = (const float*)d_in[12]; const float* cabk = (const float*)d_in[13];
  const float* caWv = (const float*)d_in[14]; const float* cabv = (const float*)d_in[15];
  const float* caWo = (const float*)d_in[16]; const float* cabo = (const float*)d_in[17];
  const float* fW1  = (const float*)d_in[18]; const float* fb1  = (const float*)d_in[19];
  const float* fW2  = (const float*)d_in[20]; const float* fb2  = (const float*)d_in[21];
  const float* l1g  = (const float*)d_in[22]; const float* l1b  = (const float*)d_in[23];
  const float* l2g  = (const float*)d_in[24]; const float* l2b  = (const float*)d_in[25];
  const float* l3g  = (const float*)d_in[26]; const float* l3b  = (const float*)d_in[27];

  float* ws = (float*)d_ws;
  const size_t SL = (size_t)MROWS_ * DM_;       // 4M floats
  float* bufQ = ws;
  float* bufK = ws + SL;
  float* bufV = ws + 2 * SL;
  float* bufC = ws + 3 * SL;
  float* xcur = ws + 4 * SL;
  float* tmp  = ws + 5 * SL;
  float* smallp = ws + 6 * SL;
  int*   idxb = (int*)smallp;
  float* Mbuf = smallp + 36864;
  int*   Mtop = (int*)(smallp + 36864 + 65536);
  float* ctxr = smallp + 36864 + 65536 + 2304;
  float* vm   = ctxr + 143360;

  // attention scratch overlaid on bufC (dead until cumsum/fill):
  uint32_t* Pg    = (uint32_t*)bufC;
  float*    Opart = bufC + 1179648;
  float*    Dpart = Opart + (size_t)KS_ * 64 * U_ * 64;

  const size_t M1 = 1024u * 1024u;
  short* wreg = (short*)(ws + 6 * SL + 262144);
  short* areg = wreg + 8 * M1;
  short* Wqh = wreg;          short* Wqm = wreg + 1*M1; short* Wql = wreg + 2*M1;
  short* Wkh = wreg + 3*M1;   short* Wkm = wreg + 4*M1; short* Wkl = wreg + 5*M1;
  short* Wvh = wreg + 6*M1;   short* Woh = wreg + 7*M1;
  short* f1h = wreg;          short* f2h = wreg + 4*M1;
  short* xh = areg;           short* xm = areg + 4*M1;  short* xl = areg + 8*M1;
  short* eh = areg + 12*M1;   short* em = areg + 16*M1; short* el = areg + 20*M1;
  short* bCh = areg + 12*M1;
  short* hidh = (short*)bufQ;

  // --- JAX partitionable-threefry key ladder (verified round 3) ---
  uint32_t k1a, k1b, k2a, k2b;
  tf2x32(0u, 42u, 0u, 0u, k1a, k1b);
  tf2x32(0u, 42u, 0u, 1u, k2a, k2b);
  uint32_t kb1a, kb1b, kb2a, kb2b;
  tf2x32(k1a, k1b, 0u, 1u, kb1a, kb1b);
  tf2x32(k2a, k2b, 0u, 1u, kb2a, kb2b);

  const dim3 thr(256);
  const int gIdx = (IDXN_ + 255) / 256;
  const int n8 = (int)(SL / 8);
  const dim3 gT(16, 16);

  // ============ self attention (masked) ============
  tsplit_kernel<3><<<gT, thr, 0, stream>>>(saWq, Wqh, Wqm, Wql, DM_, DM_);
  tsplit_kernel<3><<<gT, thr, 0, stream>>>(saWk, Wkh, Wkm, Wkl, DM_, DM_);
  tsplit_kernel<1><<<gT, thr, 0, stream>>>(saWv, Wvh, nullptr, nullptr, DM_, DM_);
  tsplit_kernel<1><<<gT, thr, 0, stream>>>(saWo, Woh, nullptr, nullptr, DM_, DM_);
  rsplit_kernel<3><<<n8 / 256, thr, 0, stream>>>(x, xh, xm, xl, n8);
  {
    FJobs J = {};
    J.j[0] = { {xh, xm, xl}, {Wqh, Wqm, Wql}, sabq, bufQ, nullptr, 0 };
    J.j[1] = { {xh, xm, xl}, {Wkh, Wkm, Wkl}, sabk, bufK, nullptr, 0 };
    gemm_fused<3><<<dim3(8, 32, 2), thr, 0, stream>>>(J, DM_, DM_);
  }
  {
    FJobs J = {};
    J.j[0] = { {xh, nullptr, nullptr}, {Wvh, nullptr, nullptr}, sabv, bufV, nullptr, 0 };
    gemm_fused<1><<<dim3(8, 32, 1), thr, 0, stream>>>(J, DM_, DM_);
  }
  idx_kernel<<<gIdx, thr, 0, stream>>>(kb1a, kb1b, idxb);
  qks_m_kernel<<<(B_ * H_ * L_) / 4, thr, 0, stream>>>(bufQ, bufK, idxb, Mbuf);
  topk_kernel<<<B_ * H_, thr, 0, stream>>>(Mbuf, Mtop);
  attn_score<<<B_ * H_ * KS_, thr, 0, stream>>>(bufQ, bufK, Mtop, Pg, 1);
  attn_pv<<<B_ * H_ * KS_, thr, 0, stream>>>(bufV, Pg, Opart, Dpart);
  attn_reduce<<<B_ * H_ * U_, dim3(64), 0, stream>>>(Opart, Dpart, ctxr);
  cumsum_kernel<<<B_ * H_, thr, 0, stream>>>(bufV, bufC);
  scatter_kernel<<<B_ * H_ * U_, dim3(64), 0, stream>>>(ctxr, Mtop, bufC);
  rsplit_kernel<1><<<n8 / 256, thr, 0, stream>>>(bufC, bCh, nullptr, nullptr, n8);
  {
    FJobs J = {};
    J.j[0] = { {bCh, nullptr, nullptr}, {Woh, nullptr, nullptr}, sabo, tmp, nullptr, 0 };
    gemm_fused<1><<<dim3(8, 32, 1), thr, 0, stream>>>(J, DM_, DM_);
  }
  ln_kernel<<<MROWS_, thr, 0, stream>>>(x, tmp, l1g, l1b, xcur, xh, xm, xl);

  // ============ cross attention (unmasked) ============
  tsplit_kernel<3><<<gT, thr, 0, stream>>>(caWq, Wqh, Wqm, Wql, DM_, DM_);
  tsplit_kernel<3><<<gT, thr, 0, stream>>>(caWk, Wkh, Wkm, Wkl, DM_, DM_);
  tsplit_kernel<1><<<gT, thr, 0, stream>>>(caWv, Wvh, nullptr, nullptr, DM_, DM_);
  tsplit_kernel<1><<<gT, thr, 0, stream>>>(caWo, Woh, nullptr, nullptr, DM_, DM_);
  rsplit_kernel<3><<<n8 / 256, thr, 0, stream>>>(enc, eh, em, el, n8);
  {
    FJobs J = {};
    J.j[0] = { {xh, xm, xl}, {Wqh, Wqm, Wql}, cabq, bufQ, nullptr, 0 };
    J.j[1] = { {eh, em, el}, {Wkh, Wkm, Wkl}, cabk, bufK, nullptr, 0 };
    gemm_fused<3><<<dim3(8, 32, 2), thr, 0, stream>>>(J, DM_, DM_);
  }
  {
    FJobs J = {};
    J.j[0] = { {eh, nullptr, nullptr}, {Wvh, nullptr, nullptr}, cabv, bufV, nullptr, 0 };
    gemm_fused<1><<<dim3(8, 32, 1), thr, 0, stream>>>(J, DM_, DM_);
  }
  idx_kernel<<<gIdx, thr, 0, stream>>>(kb2a, kb2b, idxb);
  qks_m_kernel<<<(B_ * H_ * L_) / 4, thr, 0, stream>>>(bufQ, bufK, idxb, Mbuf);
  topk_kernel<<<B_ * H_, thr, 0, stream>>>(Mbuf, Mtop);
  attn_score<<<B_ * H_ * KS_, thr, 0, stream>>>(bufQ, bufK, Mtop, Pg, 0);
  attn_pv<<<B_ * H_ * KS_, thr, 0, stream>>>(bufV, Pg, Opart, Dpart);
  attn_reduce<<<B_ * H_ * U_, dim3(64), 0, stream>>>(Opart, Dpart, ctxr);
  vmean_kernel<<<B_ * H_, thr, 0, stream>>>(bufV, vm);
  fill_kernel<<<(int)(SL / 256), thr, 0, stream>>>(vm, bufC);
  scatter_kernel<<<B_ * H_ * U_, dim3(64), 0, stream>>>(ctxr, Mtop, bufC);
  rsplit_kernel<1><<<n8 / 256, thr, 0, stream>>>(bufC, bCh, nullptr, nullptr, n8);
  {
    FJobs J = {};
    J.j[0] = { {bCh, nullptr, nullptr}, {Woh, nullptr, nullptr}, cabo, tmp, nullptr, 0 };
    gemm_fused<1><<<dim3(8, 32, 1), thr, 0, stream>>>(J, DM_, DM_);
  }
  ln_kernel<<<MROWS_, thr, 0, stream>>>(xcur, tmp, l2g, l2b, xcur, xh, nullptr, nullptr);

  // ============ FFN ============
  tsplit_kernel<1><<<dim3(64, 16), thr, 0, stream>>>(fW1, f1h, nullptr, nullptr, DM_, FF_);
  tsplit_kernel<1><<<dim3(16, 64), thr, 0, stream>>>(fW2, f2h, nullptr, nullptr, FF_, DM_);
  {
    FJobs J = {};
    J.j[0] = { {xh, nullptr, nullptr}, {f1h, nullptr, nullptr}, fb1, nullptr, hidh, 1 };
    gemm_fused<1><<<dim3(32, 32, 1), thr, 0, stream>>>(J, DM_, FF_);
  }
  {
    FJobs J = {};
    J.j[0] = { {hidh, nullptr, nullptr}, {f2h, nullptr, nullptr}, fb2, tmp, nullptr, 0 };
    gemm_fused<1><<<dim3(8, 32, 1), thr, 0, stream>>>(J, FF_, DM_);
  }
  ln_kernel<<<MROWS_, thr, 0, stream>>>(xcur, tmp, l3g, l3b, (float*)d_out,
                                        nullptr, nullptr, nullptr);
}